// Round 6
// baseline (798.590 us; speedup 1.0000x reference)
//
#include <hip/hip_runtime.h>

typedef _Float16 half8 __attribute__((ext_vector_type(8)));
typedef _Float16 half4 __attribute__((ext_vector_type(4)));
typedef float floatx4 __attribute__((ext_vector_type(4)));

__device__ __forceinline__ float leaky(float v) { return v >= 0.f ? v : 0.2f * v; }

// ---------------- CSR build ----------------
__global__ void hist_kernel(const int* __restrict__ dst, int E, int* __restrict__ cnt) {
    int e = blockIdx.x * blockDim.x + threadIdx.x;
    if (e < E) atomicAdd(&cnt[dst[e]], 1);
}

__global__ __launch_bounds__(1024) void scan_kernel(const int* __restrict__ cnt,
                                                    int* __restrict__ row_ptr,
                                                    int* __restrict__ cursor, int N) {
    __shared__ int part[1024];
    int tid = threadIdx.x;
    int per = (N + 1023) >> 10;
    int s0 = tid * per, s1 = min(s0 + per, N);
    int s = 0;
    for (int i = s0; i < s1; i++) s += cnt[i] + 1;  // +1 = self loop
    part[tid] = s;
    __syncthreads();
    for (int off = 1; off < 1024; off <<= 1) {
        int v = (tid >= off) ? part[tid - off] : 0;
        __syncthreads();
        part[tid] += v;
        __syncthreads();
    }
    int base = (tid == 0) ? 0 : part[tid - 1];
    for (int i = s0; i < s1; i++) {
        row_ptr[i] = base; cursor[i] = base;
        base += cnt[i] + 1;
    }
    if (tid == 0) row_ptr[N] = part[1023];
}

__global__ void scatter_kernel(const int* __restrict__ src, const int* __restrict__ dst,
                               int E, int N, int* __restrict__ cursor, int* __restrict__ csr_src) {
    int e = blockIdx.x * blockDim.x + threadIdx.x;
    if (e >= E + N) return;
    int s, d;
    if (e < E) { s = src[e]; d = dst[e]; }
    else       { s = e - E;  d = s; }
    int pos = atomicAdd(&cursor[d], 1);
    csr_src[pos] = s;
}

// ---------------- weight prep: fp32 [K,N] -> f16 hi/lo planes frag order [K/8][N][8] ----------------
__global__ void prep_weight_kernel(const float* __restrict__ W,
                                   _Float16* __restrict__ Wh, _Float16* __restrict__ Wl,
                                   int K, int N) {
    int idx = blockIdx.x * blockDim.x + threadIdx.x;
    if (idx >= K * N) return;
    int k = idx / N, n = idx % N;
    float v = W[idx];
    _Float16 hi = (_Float16)v;
    _Float16 lo = (_Float16)(v - (float)hi);
    size_t o = ((size_t)(k >> 3) * N + n) * 8 + (k & 7);
    Wh[o] = hi; Wl[o] = lo;
}

// ---------------- activation prep: fp32 [M,K] row-major -> hi/lo planes [K/8][Mpad][8] ----------------
__global__ void prep_act_kernel(const float* __restrict__ X,
                                _Float16* __restrict__ Ph, _Float16* __restrict__ Pl,
                                int M, int Mpad, int Kg, int K) {
    int idx = blockIdx.x * blockDim.x + threadIdx.x;
    if (idx >= Mpad * Kg) return;
    int row = idx / Kg, kg = idx - row * Kg;
    float vs[8] = {0.f, 0.f, 0.f, 0.f, 0.f, 0.f, 0.f, 0.f};
    if (row < M) {
        const float4* p = (const float4*)(X + (size_t)row * K + kg * 8);
        float4 a = p[0], b = p[1];
        vs[0] = a.x; vs[1] = a.y; vs[2] = a.z; vs[3] = a.w;
        vs[4] = b.x; vs[5] = b.y; vs[6] = b.z; vs[7] = b.w;
    }
    half8 hh, hl;
#pragma unroll
    for (int j = 0; j < 8; j++) {
        _Float16 hi = (_Float16)vs[j];
        hh[j] = hi;
        hl[j] = (_Float16)(vs[j] - (float)hi);
    }
    size_t o = ((size_t)kg * Mpad + row) * 8;
    *reinterpret_cast<half8*>(Ph + o) = hh;
    *reinterpret_cast<half8*>(Pl + o) = hl;
}

// ---------------- MFMA GEMM, no LDS: A and B pre-split f16 hi/lo in frag order ----------------
// A planes: [K/8][Mpad][8], B planes: [K/8][Nn][8]. Wave owns 32 rows (2x16), CT col-tiles.
// A frag: A[m=lane&15][k=quad*8+j]; C/D: col=lane&15, row=quad*4+reg.
template <int CT, bool RELU, bool BIAS>
__global__ __launch_bounds__(256) void gemm_frag_kernel(
        const _Float16* __restrict__ Ah, const _Float16* __restrict__ Al,
        const _Float16* __restrict__ Bh, const _Float16* __restrict__ Bl,
        const float* __restrict__ bias, float* __restrict__ C,
        int Mpad, int M, int K, int Nn) {
    int tid = threadIdx.x;
    int wv = tid >> 6, lane = tid & 63;
    int m16 = lane & 15, quad = lane >> 4;
    int row0 = blockIdx.x * 128 + wv * 32;
    int col0 = blockIdx.y * (CT * 16);

    floatx4 acc[2][CT];
#pragma unroll
    for (int t = 0; t < 2; t++)
#pragma unroll
        for (int c = 0; c < CT; c++)
#pragma unroll
            for (int i = 0; i < 4; i++) acc[t][c][i] = 0.f;

    size_t aoff = ((size_t)quad * Mpad + row0 + m16) * 8;
    size_t boff = ((size_t)quad * Nn + col0 + m16) * 8;
    const size_t aStep = (size_t)Mpad * 32;  // 4 kgrps
    const size_t bStep = (size_t)Nn * 32;

    for (int kt = 0; kt < K; kt += 32) {
        half8 ah0 = *reinterpret_cast<const half8*>(Ah + aoff);
        half8 ah1 = *reinterpret_cast<const half8*>(Ah + aoff + 128);
        half8 al0 = *reinterpret_cast<const half8*>(Al + aoff);
        half8 al1 = *reinterpret_cast<const half8*>(Al + aoff + 128);
#pragma unroll
        for (int c = 0; c < CT; c++) {
            half8 bh = *reinterpret_cast<const half8*>(Bh + boff + c * 128);
            half8 bl = *reinterpret_cast<const half8*>(Bl + boff + c * 128);
            acc[0][c] = __builtin_amdgcn_mfma_f32_16x16x32_f16(ah0, bh, acc[0][c], 0, 0, 0);
            acc[1][c] = __builtin_amdgcn_mfma_f32_16x16x32_f16(ah1, bh, acc[1][c], 0, 0, 0);
            acc[0][c] = __builtin_amdgcn_mfma_f32_16x16x32_f16(ah0, bl, acc[0][c], 0, 0, 0);
            acc[1][c] = __builtin_amdgcn_mfma_f32_16x16x32_f16(ah1, bl, acc[1][c], 0, 0, 0);
            acc[0][c] = __builtin_amdgcn_mfma_f32_16x16x32_f16(al0, bh, acc[0][c], 0, 0, 0);
            acc[1][c] = __builtin_amdgcn_mfma_f32_16x16x32_f16(al1, bh, acc[1][c], 0, 0, 0);
        }
        aoff += aStep; boff += bStep;
    }

#pragma unroll
    for (int t = 0; t < 2; t++) {
#pragma unroll
        for (int c = 0; c < CT; c++) {
            int col = col0 + c * 16 + m16;
            float bv = BIAS ? bias[col] : 0.f;
#pragma unroll
            for (int i = 0; i < 4; i++) {
                int r = row0 + t * 16 + quad * 4 + i;
                if (r < M) {
                    float v = acc[t][c][i] + bv;
                    if (RELU) v = fmaxf(v, 0.f);
                    C[(size_t)r * Nn + col] = v;
                }
            }
        }
    }
}

// ---------------- alpha_s/alpha_d per node ----------------
template <int H>
__global__ __launch_bounds__(256) void alphas_kernel(const float* __restrict__ h,
                                                     const float* __restrict__ a_src,
                                                     const float* __restrict__ a_dst,
                                                     float* __restrict__ alpha_s,
                                                     float* __restrict__ alpha_d, int N) {
    int lane = threadIdx.x & 63;
    int node = blockIdx.x * (blockDim.x >> 6) + (threadIdx.x >> 6);
    if (node >= N) return;
    if (H == 4) {
        int head = lane >> 4;
        int c4 = (lane & 15) * 4;
        const float* hp = h + (size_t)node * 256 + head * 64 + c4;
        float s = 0.f, d = 0.f;
#pragma unroll
        for (int j = 0; j < 4; j++) {
            float hv = hp[j];
            s += hv * a_src[head * 64 + c4 + j];
            d += hv * a_dst[head * 64 + c4 + j];
        }
#pragma unroll
        for (int off = 1; off < 16; off <<= 1) {
            s += __shfl_xor(s, off);
            d += __shfl_xor(d, off);
        }
        if ((lane & 15) == 0) {
            alpha_s[node * 4 + head] = s;
            alpha_d[node * 4 + head] = d;
        }
    } else {
        float hv = h[(size_t)node * 64 + lane];
        float s = hv * a_src[lane];
        float d = hv * a_dst[lane];
#pragma unroll
        for (int off = 1; off < 64; off <<= 1) {
            s += __shfl_xor(s, off);
            d += __shfl_xor(d, off);
        }
        if (lane == 0) { alpha_s[node] = s; alpha_d[node] = d; }
    }
}

// ---------------- aggregation H=4: gathers fp32 h, writes f16 hi/lo planes for next GEMM ----------------
__global__ __launch_bounds__(256) void aggregate4_kernel(const float* __restrict__ hsrc,
                                                         const float* __restrict__ alpha_s,
                                                         const float* __restrict__ alpha_d,
                                                         const int* __restrict__ row_ptr,
                                                         const int* __restrict__ csr_src,
                                                         const float* __restrict__ bias,
                                                         _Float16* __restrict__ outH,
                                                         _Float16* __restrict__ outL,
                                                         int N, int Mpad) {
    __shared__ float wlds[4][64][4];
    __shared__ int   slds[4][64];
    int wv = threadIdx.x >> 6, lane = threadIdx.x & 63;
    int node = blockIdx.x * 4 + wv;
    if (node >= N) return;
    int rs = row_ptr[node], re = row_ptr[node + 1];
    int head = lane >> 4, c4 = (lane & 15) * 4;
    float4 ad4 = *(const float4*)(alpha_d + (size_t)node * 4);

    float m0 = -1e30f, m1 = -1e30f, m2 = -1e30f, m3 = -1e30f;
    for (int base = rs; base < re; base += 64) {
        int i = base + lane;
        if (i < re) {
            int s = csr_src[i];
            float4 as = *(const float4*)(alpha_s + (size_t)s * 4);
            m0 = fmaxf(m0, leaky(as.x + ad4.x));
            m1 = fmaxf(m1, leaky(as.y + ad4.y));
            m2 = fmaxf(m2, leaky(as.z + ad4.z));
            m3 = fmaxf(m3, leaky(as.w + ad4.w));
        }
    }
#pragma unroll
    for (int off = 32; off >= 1; off >>= 1) {
        m0 = fmaxf(m0, __shfl_xor(m0, off));
        m1 = fmaxf(m1, __shfl_xor(m1, off));
        m2 = fmaxf(m2, __shfl_xor(m2, off));
        m3 = fmaxf(m3, __shfl_xor(m3, off));
    }

    float den0 = 0.f, den1 = 0.f, den2 = 0.f, den3 = 0.f;
    float a0 = 0.f, a1 = 0.f, a2 = 0.f, a3 = 0.f;
    float* wp = &wlds[wv][0][0];
    int*   sp = &slds[wv][0];
    for (int base = rs; base < re; base += 64) {
        int i = base + lane;
        float w0 = 0.f, w1 = 0.f, w2 = 0.f, w3 = 0.f;
        int s = 0;
        if (i < re) {
            s = csr_src[i];
            float4 as = *(const float4*)(alpha_s + (size_t)s * 4);
            w0 = __expf(leaky(as.x + ad4.x) - m0);
            w1 = __expf(leaky(as.y + ad4.y) - m1);
            w2 = __expf(leaky(as.z + ad4.z) - m2);
            w3 = __expf(leaky(as.w + ad4.w) - m3);
        }
        den0 += w0; den1 += w1; den2 += w2; den3 += w3;
        sp[lane] = s;
        *(float4*)(wp + lane * 4) = make_float4(w0, w1, w2, w3);
        int cnt = min(64, re - base);
#pragma unroll 4
        for (int j = 0; j < cnt; j++) {
            int s2 = sp[j];
            float w = wp[j * 4 + head];
            const float* hp = hsrc + (size_t)s2 * 256 + (head << 6) + c4;
            a0 += w * hp[0]; a1 += w * hp[1]; a2 += w * hp[2]; a3 += w * hp[3];
        }
    }
#pragma unroll
    for (int off = 32; off >= 1; off >>= 1) {
        den0 += __shfl_xor(den0, off);
        den1 += __shfl_xor(den1, off);
        den2 += __shfl_xor(den2, off);
        den3 += __shfl_xor(den3, off);
    }
    float den = (head & 2) ? ((head & 1) ? den3 : den2) : ((head & 1) ? den1 : den0);
    float inv = 1.f / (den + 1e-16f);
    int cbase = (head << 6) + c4;
    float v0 = a0 * inv + bias[cbase + 0];
    float v1 = a1 * inv + bias[cbase + 1];
    float v2 = a2 * inv + bias[cbase + 2];
    float v3 = a3 * inv + bias[cbase + 3];
    v0 = fmaxf(v0, 0.f); v1 = fmaxf(v1, 0.f);
    v2 = fmaxf(v2, 0.f); v3 = fmaxf(v3, 0.f);
    // f16 hi/lo split write in frag-plane layout [ch/8][Mpad][8]
    half4 hv, lv;
    _Float16 h;
    h = (_Float16)v0; hv[0] = h; lv[0] = (_Float16)(v0 - (float)h);
    h = (_Float16)v1; hv[1] = h; lv[1] = (_Float16)(v1 - (float)h);
    h = (_Float16)v2; hv[2] = h; lv[2] = (_Float16)(v2 - (float)h);
    h = (_Float16)v3; hv[3] = h; lv[3] = (_Float16)(v3 - (float)h);
    size_t o = ((size_t)(cbase >> 3) * Mpad + node) * 8 + (cbase & 7);
    *reinterpret_cast<half4*>(outH + o) = hv;
    *reinterpret_cast<half4*>(outL + o) = lv;
}

// ---------------- aggregation, H=1 (fp32 out) ----------------
template <bool RELU>
__global__ __launch_bounds__(256) void aggregate1_kernel(const float* __restrict__ hsrc,
                                                         const float* __restrict__ alpha_s,
                                                         const float* __restrict__ alpha_d,
                                                         const int* __restrict__ row_ptr,
                                                         const int* __restrict__ csr_src,
                                                         const float* __restrict__ bias,
                                                         float* __restrict__ out, int N) {
    __shared__ float wlds[4][64];
    __shared__ int   slds[4][64];
    int wv = threadIdx.x >> 6, lane = threadIdx.x & 63;
    int node = blockIdx.x * 4 + wv;
    if (node >= N) return;
    int rs = row_ptr[node], re = row_ptr[node + 1];
    float ad = alpha_d[node];

    float m = -1e30f;
    for (int base = rs; base < re; base += 64) {
        int i = base + lane;
        if (i < re) {
            int s = csr_src[i];
            m = fmaxf(m, leaky(alpha_s[s] + ad));
        }
    }
#pragma unroll
    for (int off = 32; off >= 1; off >>= 1) m = fmaxf(m, __shfl_xor(m, off));

    float den = 0.f, acc = 0.f;
    float* wp = &wlds[wv][0];
    int*   sp = &slds[wv][0];
    for (int base = rs; base < re; base += 64) {
        int i = base + lane;
        float w = 0.f;
        int s = 0;
        if (i < re) {
            s = csr_src[i];
            w = __expf(leaky(alpha_s[s] + ad) - m);
        }
        den += w;
        sp[lane] = s;
        wp[lane] = w;
        int cnt = min(64, re - base);
#pragma unroll 4
        for (int j = 0; j < cnt; j++) {
            int s2 = sp[j];
            acc += wp[j] * hsrc[(size_t)s2 * 64 + lane];
        }
    }
#pragma unroll
    for (int off = 32; off >= 1; off >>= 1) den += __shfl_xor(den, off);
    float v = acc / (den + 1e-16f) + bias[lane];
    if (RELU) v = fmaxf(v, 0.f);
    out[(size_t)node * 64 + lane] = v;
}

// ---------------- head MLP ----------------
__global__ __launch_bounds__(256) void mlp_head_kernel(const float* __restrict__ hin,
                                                       const float* __restrict__ Wo1,
                                                       const float* __restrict__ bo1,
                                                       const float* __restrict__ Wo2,
                                                       const float* __restrict__ bo2,
                                                       float* __restrict__ out, int N) {
    __shared__ float w1[64 * 32];
    __shared__ float w2[32];
    __shared__ float b1s[32];
    int tid = threadIdx.x;
#pragma unroll
    for (int i = 0; i < 8; i++) w1[tid + i * 256] = Wo1[tid + i * 256];
    if (tid < 32) { w2[tid] = Wo2[tid]; b1s[tid] = bo1[tid]; }
    __syncthreads();
    int n = blockIdx.x * blockDim.x + tid;
    if (n >= N) return;
    float hrow[64];
    const float* pr = hin + (size_t)n * 64;
#pragma unroll
    for (int i = 0; i < 64; i++) hrow[i] = pr[i];
    float sum = 0.f;
    for (int j = 0; j < 32; j++) {
        float a = b1s[j];
#pragma unroll
        for (int k = 0; k < 64; k++) a += hrow[k] * w1[k * 32 + j];
        a = fmaxf(a, 0.f);
        sum += a * w2[j];
    }
    out[n] = sum + bo2[0];
}

// ---------------- launch ----------------
extern "C" void kernel_launch(void* const* d_in, const int* in_sizes, int n_in,
                              void* d_out, int out_size, void* d_ws, size_t ws_size,
                              hipStream_t stream) {
    const float* x     = (const float*)d_in[0];
    const float* W_emb = (const float*)d_in[1];
    const float* b_emb = (const float*)d_in[2];
    const float* W0    = (const float*)d_in[3];
    const float* as0   = (const float*)d_in[4];
    const float* ad0   = (const float*)d_in[5];
    const float* b0    = (const float*)d_in[6];
    const float* W1    = (const float*)d_in[7];
    const float* as1   = (const float*)d_in[8];
    const float* ad1   = (const float*)d_in[9];
    const float* b1    = (const float*)d_in[10];
    const float* W2    = (const float*)d_in[11];
    const float* as2   = (const float*)d_in[12];
    const float* ad2   = (const float*)d_in[13];
    const float* b2    = (const float*)d_in[14];
    const float* Wo1   = (const float*)d_in[15];
    const float* bo1   = (const float*)d_in[16];
    const float* Wo2   = (const float*)d_in[17];
    const float* bo2   = (const float*)d_in[18];
    const int* eidx    = (const int*)d_in[19];

    const int N = in_sizes[0] / 128;
    const int E = in_sizes[19] / 2;
    const int* esrc = eidx;
    const int* edst = eidx + E;
    const int gmB  = (N + 127) / 128;
    const int Mpad = gmB * 128;

    char* w = (char*)d_ws;
    auto alloc = [&](size_t bytes) {
        char* p = w;
        w += (bytes + 255) & ~(size_t)255;
        return (void*)p;
    };
    float* bufB    = (float*)alloc((size_t)Mpad * 256 * 4);   // GEMM fp32 outputs
    float* bufA    = (float*)alloc((size_t)Mpad * 64 * 4);    // emb out / agg1 out
    _Float16* PHh  = (_Float16*)alloc((size_t)Mpad * 256 * 2); // act planes (reused)
    _Float16* PHl  = (_Float16*)alloc((size_t)Mpad * 256 * 2);
    float* aS      = (float*)alloc((size_t)N * 4 * 4);
    float* aD      = (float*)alloc((size_t)N * 4 * 4);
    int*   row_ptr = (int*)alloc((size_t)(N + 1) * 4);
    int*   cursor  = (int*)alloc((size_t)N * 4);
    int*   cnt     = (int*)alloc((size_t)N * 4);
    int*   csr     = (int*)alloc((size_t)(E + N) * 4);
    _Float16* WeH  = (_Float16*)alloc(128 * 64 * 2);
    _Float16* WeL  = (_Float16*)alloc(128 * 64 * 2);
    _Float16* W0H  = (_Float16*)alloc(64 * 256 * 2);
    _Float16* W0L  = (_Float16*)alloc(64 * 256 * 2);
    _Float16* W1H  = (_Float16*)alloc(256 * 256 * 2);
    _Float16* W1L  = (_Float16*)alloc(256 * 256 * 2);
    _Float16* W2H  = (_Float16*)alloc(256 * 64 * 2);
    _Float16* W2L  = (_Float16*)alloc(256 * 64 * 2);

    // CSR build
    hipMemsetAsync(cnt, 0, (size_t)N * 4, stream);
    hist_kernel<<<(E + 255) / 256, 256, 0, stream>>>(edst, E, cnt);
    scan_kernel<<<1, 1024, 0, stream>>>(cnt, row_ptr, cursor, N);
    scatter_kernel<<<(E + N + 255) / 256, 256, 0, stream>>>(esrc, edst, E, N, cursor, csr);

    // weight planes
    prep_weight_kernel<<<(128 * 64 + 255) / 256, 256, 0, stream>>>(W_emb, WeH, WeL, 128, 64);
    prep_weight_kernel<<<(64 * 256 + 255) / 256, 256, 0, stream>>>(W0, W0H, W0L, 64, 256);
    prep_weight_kernel<<<(256 * 256 + 255) / 256, 256, 0, stream>>>(W1, W1H, W1L, 256, 256);
    prep_weight_kernel<<<(256 * 64 + 255) / 256, 256, 0, stream>>>(W2, W2H, W2L, 256, 64);

    int gn4 = (N + 3) / 4;

    // embedding: planes(x) -> h0 = relu(x@W_emb + b_emb) [N,64] fp32
    prep_act_kernel<<<((size_t)Mpad * 16 + 255) / 256, 256, 0, stream>>>(x, PHh, PHl, N, Mpad, 16, 128);
    gemm_frag_kernel<4, true, true><<<dim3(gmB, 1), 256, 0, stream>>>(PHh, PHl, WeH, WeL, b_emb, bufA, Mpad, N, 128, 64);

    // GAT layer 0: planes(h0) -> GEMM -> alphas -> aggregate (writes planes)
    prep_act_kernel<<<((size_t)Mpad * 8 + 255) / 256, 256, 0, stream>>>(bufA, PHh, PHl, N, Mpad, 8, 64);
    gemm_frag_kernel<8, false, false><<<dim3(gmB, 2), 256, 0, stream>>>(PHh, PHl, W0H, W0L, nullptr, bufB, Mpad, N, 64, 256);
    alphas_kernel<4><<<gn4, 256, 0, stream>>>(bufB, as0, ad0, aS, aD, N);
    aggregate4_kernel<<<gn4, 256, 0, stream>>>(bufB, aS, aD, row_ptr, csr, b0, PHh, PHl, N, Mpad);

    // GAT layer 1
    gemm_frag_kernel<8, false, false><<<dim3(gmB, 2), 256, 0, stream>>>(PHh, PHl, W1H, W1L, nullptr, bufB, Mpad, N, 256, 256);
    alphas_kernel<4><<<gn4, 256, 0, stream>>>(bufB, as1, ad1, aS, aD, N);
    aggregate4_kernel<<<gn4, 256, 0, stream>>>(bufB, aS, aD, row_ptr, csr, b1, PHh, PHl, N, Mpad);

    // GAT layer 2 (1 head, no relu)
    gemm_frag_kernel<4, false, false><<<dim3(gmB, 1), 256, 0, stream>>>(PHh, PHl, W2H, W2L, nullptr, bufB, Mpad, N, 256, 64);
    alphas_kernel<1><<<gn4, 256, 0, stream>>>(bufB, as2, ad2, aS, aD, N);
    aggregate1_kernel<false><<<gn4, 256, 0, stream>>>(bufB, aS, aD, row_ptr, csr, b2, bufA, N);

    // head MLP -> out [N,1] fp32
    mlp_head_kernel<<<(N + 255) / 256, 256, 0, stream>>>(bufA, Wo1, bo1, Wo2, bo2, (float*)d_out, N);
}

// Round 7
// 643.672 us; speedup vs baseline: 1.2407x; 1.2407x over previous
//
#include <hip/hip_runtime.h>

typedef _Float16 h8_t __attribute__((ext_vector_type(8)));
typedef _Float16 h4_t __attribute__((ext_vector_type(4)));
typedef float floatx4 __attribute__((ext_vector_type(4)));

__device__ __forceinline__ float leaky(float v) { return v >= 0.f ? v : 0.2f * v; }

// ---------------- CSR build ----------------
__global__ void hist_kernel(const int* __restrict__ dst, int E, int* __restrict__ cnt) {
    int e = blockIdx.x * blockDim.x + threadIdx.x;
    if (e < E) atomicAdd(&cnt[dst[e]], 1);
}

__global__ __launch_bounds__(1024) void scan_kernel(const int* __restrict__ cnt,
                                                    int* __restrict__ row_ptr,
                                                    int* __restrict__ cursor, int N) {
    __shared__ int part[1024];
    int tid = threadIdx.x;
    int per = (N + 1023) >> 10;
    int s0 = tid * per, s1 = min(s0 + per, N);
    int s = 0;
    for (int i = s0; i < s1; i++) s += cnt[i] + 1;  // +1 = self loop
    part[tid] = s;
    __syncthreads();
    for (int off = 1; off < 1024; off <<= 1) {
        int v = (tid >= off) ? part[tid - off] : 0;
        __syncthreads();
        part[tid] += v;
        __syncthreads();
    }
    int base = (tid == 0) ? 0 : part[tid - 1];
    for (int i = s0; i < s1; i++) {
        row_ptr[i] = base; cursor[i] = base;
        base += cnt[i] + 1;
    }
    if (tid == 0) row_ptr[N] = part[1023];
}

__global__ void scatter_kernel(const int* __restrict__ src, const int* __restrict__ dst,
                               int E, int N, int* __restrict__ cursor, int* __restrict__ csr_src) {
    int e = blockIdx.x * blockDim.x + threadIdx.x;
    if (e >= E + N) return;
    int s, d;
    if (e < E) { s = src[e]; d = dst[e]; }
    else       { s = e - E;  d = s; }
    int pos = atomicAdd(&cursor[d], 1);
    csr_src[pos] = s;
}

// ---------------- weight prep: fp32 [K,N] -> f16 hi/lo planes frag order [K/8][N][8] ----------------
__global__ void prep_weight_kernel(const float* __restrict__ W,
                                   _Float16* __restrict__ Wh, _Float16* __restrict__ Wl,
                                   int K, int N) {
    int idx = blockIdx.x * blockDim.x + threadIdx.x;
    if (idx >= K * N) return;
    int k = idx / N, n = idx % N;
    float v = W[idx];
    _Float16 hi = (_Float16)v;
    _Float16 lo = (_Float16)(v - (float)hi);
    size_t o = ((size_t)(k >> 3) * N + n) * 8 + (k & 7);
    Wh[o] = hi; Wl[o] = lo;
}

// ---------------- activation prep: fp32 [M,K] -> hi/lo planes [K/8][Mpad][8] ----------------
__global__ void prep_act_kernel(const float* __restrict__ X,
                                _Float16* __restrict__ Ph, _Float16* __restrict__ Pl,
                                int M, int Mpad, int Kg, int K) {
    int idx = blockIdx.x * blockDim.x + threadIdx.x;
    if (idx >= Mpad * Kg) return;
    int row = idx / Kg, kg = idx - row * Kg;
    float vs[8] = {0.f, 0.f, 0.f, 0.f, 0.f, 0.f, 0.f, 0.f};
    if (row < M) {
        const float4* p = (const float4*)(X + (size_t)row * K + kg * 8);
        float4 a = p[0], b = p[1];
        vs[0] = a.x; vs[1] = a.y; vs[2] = a.z; vs[3] = a.w;
        vs[4] = b.x; vs[5] = b.y; vs[6] = b.z; vs[7] = b.w;
    }
    h8_t hh, hl;
#pragma unroll
    for (int j = 0; j < 8; j++) {
        _Float16 hi = (_Float16)vs[j];
        hh[j] = hi;
        hl[j] = (_Float16)(vs[j] - (float)hi);
    }
    size_t o = ((size_t)kg * Mpad + row) * 8;
    *reinterpret_cast<h8_t*>(Ph + o) = hh;
    *reinterpret_cast<h8_t*>(Pl + o) = hl;
}

// ---------------- embedding GEMM: planes(x) @ W_emb + bias, relu -> hi/lo planes [64/8][Mpad][8] ----------------
__global__ __launch_bounds__(256) void gemm_emb_kernel(
        const _Float16* __restrict__ Ah, const _Float16* __restrict__ Al,
        const _Float16* __restrict__ Bh, const _Float16* __restrict__ Bl,
        const float* __restrict__ bias,
        _Float16* __restrict__ Ph, _Float16* __restrict__ Pl,
        int Mpad, int M, int K) {
    const int Nn = 64;
    int tid = threadIdx.x;
    int wv = tid >> 6, lane = tid & 63;
    int m16 = lane & 15, quad = lane >> 4;
    int row0 = blockIdx.x * 128 + wv * 32;

    floatx4 acc[2][4];
#pragma unroll
    for (int t = 0; t < 2; t++)
#pragma unroll
        for (int c = 0; c < 4; c++)
#pragma unroll
            for (int i = 0; i < 4; i++) acc[t][c][i] = 0.f;

    size_t aoff = ((size_t)quad * Mpad + row0 + m16) * 8;
    size_t boff = ((size_t)quad * Nn + m16) * 8;
    const size_t aStep = (size_t)Mpad * 32;
    const size_t bStep = (size_t)Nn * 32;

    for (int kt = 0; kt < K; kt += 32) {
        h8_t ah0 = *reinterpret_cast<const h8_t*>(Ah + aoff);
        h8_t ah1 = *reinterpret_cast<const h8_t*>(Ah + aoff + 128);
        h8_t al0 = *reinterpret_cast<const h8_t*>(Al + aoff);
        h8_t al1 = *reinterpret_cast<const h8_t*>(Al + aoff + 128);
#pragma unroll
        for (int c = 0; c < 4; c++) {
            h8_t bh = *reinterpret_cast<const h8_t*>(Bh + boff + c * 128);
            h8_t bl = *reinterpret_cast<const h8_t*>(Bl + boff + c * 128);
            acc[0][c] = __builtin_amdgcn_mfma_f32_16x16x32_f16(ah0, bh, acc[0][c], 0, 0, 0);
            acc[1][c] = __builtin_amdgcn_mfma_f32_16x16x32_f16(ah1, bh, acc[1][c], 0, 0, 0);
            acc[0][c] = __builtin_amdgcn_mfma_f32_16x16x32_f16(ah0, bl, acc[0][c], 0, 0, 0);
            acc[1][c] = __builtin_amdgcn_mfma_f32_16x16x32_f16(ah1, bl, acc[1][c], 0, 0, 0);
            acc[0][c] = __builtin_amdgcn_mfma_f32_16x16x32_f16(al0, bh, acc[0][c], 0, 0, 0);
            acc[1][c] = __builtin_amdgcn_mfma_f32_16x16x32_f16(al1, bh, acc[1][c], 0, 0, 0);
        }
        aoff += aStep; boff += bStep;
    }

#pragma unroll
    for (int t = 0; t < 2; t++) {
#pragma unroll
        for (int c = 0; c < 4; c++) {
            int col = c * 16 + m16;
            float bv = bias[col];
            size_t obase = ((size_t)(col >> 3) * Mpad) * 8 + (col & 7);
#pragma unroll
            for (int i = 0; i < 4; i++) {
                int r = row0 + t * 16 + quad * 4 + i;
                float v = fmaxf(acc[t][c][i] + bv, 0.f);
                _Float16 hi = (_Float16)v;
                size_t o = obase + (size_t)r * 8;
                Ph[o] = hi;
                Pl[o] = (_Float16)(v - (float)hi);
            }
        }
    }
}

// ---------------- GAT GEMM (Nn=256): planes @ W -> h f16 row-major + fused alphas (2 heads/block) ----------------
__global__ __launch_bounds__(256) void gemm_gat_kernel(
        const _Float16* __restrict__ Ah, const _Float16* __restrict__ Al,
        const _Float16* __restrict__ Bh, const _Float16* __restrict__ Bl,
        const float* __restrict__ a_src, const float* __restrict__ a_dst,
        _Float16* __restrict__ hOut, float* __restrict__ aS, float* __restrict__ aD,
        int Mpad, int M, int K) {
    const int Nn = 256;
    int tid = threadIdx.x;
    int wv = tid >> 6, lane = tid & 63;
    int m16 = lane & 15, quad = lane >> 4;
    int row0 = blockIdx.x * 128 + wv * 32;
    int colBase = blockIdx.y * 128;

    floatx4 acc[2][8];
#pragma unroll
    for (int t = 0; t < 2; t++)
#pragma unroll
        for (int c = 0; c < 8; c++)
#pragma unroll
            for (int i = 0; i < 4; i++) acc[t][c][i] = 0.f;

    size_t aoff = ((size_t)quad * Mpad + row0 + m16) * 8;
    size_t boff = ((size_t)quad * Nn + colBase + m16) * 8;
    const size_t aStep = (size_t)Mpad * 32;
    const size_t bStep = (size_t)Nn * 32;

    for (int kt = 0; kt < K; kt += 32) {
        h8_t ah0 = *reinterpret_cast<const h8_t*>(Ah + aoff);
        h8_t ah1 = *reinterpret_cast<const h8_t*>(Ah + aoff + 128);
        h8_t al0 = *reinterpret_cast<const h8_t*>(Al + aoff);
        h8_t al1 = *reinterpret_cast<const h8_t*>(Al + aoff + 128);
#pragma unroll
        for (int c = 0; c < 8; c++) {
            h8_t bh = *reinterpret_cast<const h8_t*>(Bh + boff + c * 128);
            h8_t bl = *reinterpret_cast<const h8_t*>(Bl + boff + c * 128);
            acc[0][c] = __builtin_amdgcn_mfma_f32_16x16x32_f16(ah0, bh, acc[0][c], 0, 0, 0);
            acc[1][c] = __builtin_amdgcn_mfma_f32_16x16x32_f16(ah1, bh, acc[1][c], 0, 0, 0);
            acc[0][c] = __builtin_amdgcn_mfma_f32_16x16x32_f16(ah0, bl, acc[0][c], 0, 0, 0);
            acc[1][c] = __builtin_amdgcn_mfma_f32_16x16x32_f16(ah1, bl, acc[1][c], 0, 0, 0);
            acc[0][c] = __builtin_amdgcn_mfma_f32_16x16x32_f16(al0, bh, acc[0][c], 0, 0, 0);
            acc[1][c] = __builtin_amdgcn_mfma_f32_16x16x32_f16(al1, bh, acc[1][c], 0, 0, 0);
        }
        aoff += aStep; boff += bStep;
    }

    float asv[8], adv[8];
#pragma unroll
    for (int c = 0; c < 8; c++) {
        asv[c] = a_src[colBase + c * 16 + m16];
        adv[c] = a_dst[colBase + c * 16 + m16];
    }
    int hb = colBase >> 6;
#pragma unroll
    for (int t = 0; t < 2; t++) {
#pragma unroll
        for (int i = 0; i < 4; i++) {
            int r = row0 + t * 16 + quad * 4 + i;
            float s0 = 0.f, d0 = 0.f, s1 = 0.f, d1 = 0.f;
            size_t ob = (size_t)r * 256 + colBase + m16;
#pragma unroll
            for (int c = 0; c < 8; c++) {
                float v = acc[t][c][i];
                hOut[ob + c * 16] = (_Float16)v;
                if (c < 4) { s0 += v * asv[c]; d0 += v * adv[c]; }
                else       { s1 += v * asv[c]; d1 += v * adv[c]; }
            }
#pragma unroll
            for (int off = 1; off < 16; off <<= 1) {
                s0 += __shfl_xor(s0, off);
                d0 += __shfl_xor(d0, off);
                s1 += __shfl_xor(s1, off);
                d1 += __shfl_xor(d1, off);
            }
            if (m16 == 0 && r < M) {
                aS[r * 4 + hb] = s0;     aD[r * 4 + hb] = d0;
                aS[r * 4 + hb + 1] = s1; aD[r * 4 + hb + 1] = d1;
            }
        }
    }
}

// ---------------- layer-2 GEMM (Nn=64, 1 head): -> h f16 row-major + fused alphas ----------------
__global__ __launch_bounds__(256) void gemm_l2_kernel(
        const _Float16* __restrict__ Ah, const _Float16* __restrict__ Al,
        const _Float16* __restrict__ Bh, const _Float16* __restrict__ Bl,
        const float* __restrict__ a_src, const float* __restrict__ a_dst,
        _Float16* __restrict__ hOut, float* __restrict__ aS, float* __restrict__ aD,
        int Mpad, int M, int K) {
    const int Nn = 64;
    int tid = threadIdx.x;
    int wv = tid >> 6, lane = tid & 63;
    int m16 = lane & 15, quad = lane >> 4;
    int row0 = blockIdx.x * 128 + wv * 32;

    floatx4 acc[2][4];
#pragma unroll
    for (int t = 0; t < 2; t++)
#pragma unroll
        for (int c = 0; c < 4; c++)
#pragma unroll
            for (int i = 0; i < 4; i++) acc[t][c][i] = 0.f;

    size_t aoff = ((size_t)quad * Mpad + row0 + m16) * 8;
    size_t boff = ((size_t)quad * Nn + m16) * 8;
    const size_t aStep = (size_t)Mpad * 32;
    const size_t bStep = (size_t)Nn * 32;

    for (int kt = 0; kt < K; kt += 32) {
        h8_t ah0 = *reinterpret_cast<const h8_t*>(Ah + aoff);
        h8_t ah1 = *reinterpret_cast<const h8_t*>(Ah + aoff + 128);
        h8_t al0 = *reinterpret_cast<const h8_t*>(Al + aoff);
        h8_t al1 = *reinterpret_cast<const h8_t*>(Al + aoff + 128);
#pragma unroll
        for (int c = 0; c < 4; c++) {
            h8_t bh = *reinterpret_cast<const h8_t*>(Bh + boff + c * 128);
            h8_t bl = *reinterpret_cast<const h8_t*>(Bl + boff + c * 128);
            acc[0][c] = __builtin_amdgcn_mfma_f32_16x16x32_f16(ah0, bh, acc[0][c], 0, 0, 0);
            acc[1][c] = __builtin_amdgcn_mfma_f32_16x16x32_f16(ah1, bh, acc[1][c], 0, 0, 0);
            acc[0][c] = __builtin_amdgcn_mfma_f32_16x16x32_f16(ah0, bl, acc[0][c], 0, 0, 0);
            acc[1][c] = __builtin_amdgcn_mfma_f32_16x16x32_f16(ah1, bl, acc[1][c], 0, 0, 0);
            acc[0][c] = __builtin_amdgcn_mfma_f32_16x16x32_f16(al0, bh, acc[0][c], 0, 0, 0);
            acc[1][c] = __builtin_amdgcn_mfma_f32_16x16x32_f16(al1, bh, acc[1][c], 0, 0, 0);
        }
        aoff += aStep; boff += bStep;
    }

    float asv[4], adv[4];
#pragma unroll
    for (int c = 0; c < 4; c++) {
        asv[c] = a_src[c * 16 + m16];
        adv[c] = a_dst[c * 16 + m16];
    }
#pragma unroll
    for (int t = 0; t < 2; t++) {
#pragma unroll
        for (int i = 0; i < 4; i++) {
            int r = row0 + t * 16 + quad * 4 + i;
            float s0 = 0.f, d0 = 0.f;
            size_t ob = (size_t)r * 64 + m16;
#pragma unroll
            for (int c = 0; c < 4; c++) {
                float v = acc[t][c][i];
                hOut[ob + c * 16] = (_Float16)v;
                s0 += v * asv[c]; d0 += v * adv[c];
            }
#pragma unroll
            for (int off = 1; off < 16; off <<= 1) {
                s0 += __shfl_xor(s0, off);
                d0 += __shfl_xor(d0, off);
            }
            if (m16 == 0 && r < M) { aS[r] = s0; aD[r] = d0; }
        }
    }
}

// ---------------- aggregation H=4: gathers f16 h, writes hi/lo planes for next GEMM ----------------
__global__ __launch_bounds__(256) void aggregate4_kernel(const _Float16* __restrict__ hsrc,
                                                         const float* __restrict__ alpha_s,
                                                         const float* __restrict__ alpha_d,
                                                         const int* __restrict__ row_ptr,
                                                         const int* __restrict__ csr_src,
                                                         const float* __restrict__ bias,
                                                         _Float16* __restrict__ outH,
                                                         _Float16* __restrict__ outL,
                                                         int N, int Mpad) {
    __shared__ float wlds[4][64][4];
    __shared__ int   slds[4][64];
    int wv = threadIdx.x >> 6, lane = threadIdx.x & 63;
    int node = blockIdx.x * 4 + wv;
    if (node >= N) return;
    int rs = row_ptr[node], re = row_ptr[node + 1];
    int head = lane >> 4, c4 = (lane & 15) * 4;
    float4 ad4 = *(const float4*)(alpha_d + (size_t)node * 4);

    float m0 = -1e30f, m1 = -1e30f, m2 = -1e30f, m3 = -1e30f;
    for (int base = rs; base < re; base += 64) {
        int i = base + lane;
        if (i < re) {
            int s = csr_src[i];
            float4 as = *(const float4*)(alpha_s + (size_t)s * 4);
            m0 = fmaxf(m0, leaky(as.x + ad4.x));
            m1 = fmaxf(m1, leaky(as.y + ad4.y));
            m2 = fmaxf(m2, leaky(as.z + ad4.z));
            m3 = fmaxf(m3, leaky(as.w + ad4.w));
        }
    }
#pragma unroll
    for (int off = 32; off >= 1; off >>= 1) {
        m0 = fmaxf(m0, __shfl_xor(m0, off));
        m1 = fmaxf(m1, __shfl_xor(m1, off));
        m2 = fmaxf(m2, __shfl_xor(m2, off));
        m3 = fmaxf(m3, __shfl_xor(m3, off));
    }

    float den0 = 0.f, den1 = 0.f, den2 = 0.f, den3 = 0.f;
    float a0 = 0.f, a1 = 0.f, a2 = 0.f, a3 = 0.f;
    float* wp = &wlds[wv][0][0];
    int*   sp = &slds[wv][0];
    for (int base = rs; base < re; base += 64) {
        int i = base + lane;
        float w0 = 0.f, w1 = 0.f, w2 = 0.f, w3 = 0.f;
        int s = 0;
        if (i < re) {
            s = csr_src[i];
            float4 as = *(const float4*)(alpha_s + (size_t)s * 4);
            w0 = __expf(leaky(as.x + ad4.x) - m0);
            w1 = __expf(leaky(as.y + ad4.y) - m1);
            w2 = __expf(leaky(as.z + ad4.z) - m2);
            w3 = __expf(leaky(as.w + ad4.w) - m3);
        }
        den0 += w0; den1 += w1; den2 += w2; den3 += w3;
        sp[lane] = s;
        *(float4*)(wp + lane * 4) = make_float4(w0, w1, w2, w3);
        int cnt = min(64, re - base);
#pragma unroll 4
        for (int j = 0; j < cnt; j++) {
            int s2 = sp[j];
            float w = wp[j * 4 + head];
            h4_t hv = *reinterpret_cast<const h4_t*>(hsrc + (size_t)s2 * 256 + (head << 6) + c4);
            a0 += w * (float)hv[0]; a1 += w * (float)hv[1];
            a2 += w * (float)hv[2]; a3 += w * (float)hv[3];
        }
    }
#pragma unroll
    for (int off = 32; off >= 1; off >>= 1) {
        den0 += __shfl_xor(den0, off);
        den1 += __shfl_xor(den1, off);
        den2 += __shfl_xor(den2, off);
        den3 += __shfl_xor(den3, off);
    }
    float den = (head & 2) ? ((head & 1) ? den3 : den2) : ((head & 1) ? den1 : den0);
    float inv = 1.f / (den + 1e-16f);
    int cbase = (head << 6) + c4;
    float v0 = fmaxf(a0 * inv + bias[cbase + 0], 0.f);
    float v1 = fmaxf(a1 * inv + bias[cbase + 1], 0.f);
    float v2 = fmaxf(a2 * inv + bias[cbase + 2], 0.f);
    float v3 = fmaxf(a3 * inv + bias[cbase + 3], 0.f);
    h4_t hv, lv;
    _Float16 h;
    h = (_Float16)v0; hv[0] = h; lv[0] = (_Float16)(v0 - (float)h);
    h = (_Float16)v1; hv[1] = h; lv[1] = (_Float16)(v1 - (float)h);
    h = (_Float16)v2; hv[2] = h; lv[2] = (_Float16)(v2 - (float)h);
    h = (_Float16)v3; hv[3] = h; lv[3] = (_Float16)(v3 - (float)h);
    size_t o = ((size_t)(cbase >> 3) * Mpad + node) * 8 + (cbase & 7);
    *reinterpret_cast<h4_t*>(outH + o) = hv;
    *reinterpret_cast<h4_t*>(outL + o) = lv;
}

// ---------------- aggregation H=1: gathers f16, writes fp32 [N,64] ----------------
__global__ __launch_bounds__(256) void aggregate1_kernel(const _Float16* __restrict__ hsrc,
                                                         const float* __restrict__ alpha_s,
                                                         const float* __restrict__ alpha_d,
                                                         const int* __restrict__ row_ptr,
                                                         const int* __restrict__ csr_src,
                                                         const float* __restrict__ bias,
                                                         float* __restrict__ out, int N) {
    __shared__ float wlds[4][64];
    __shared__ int   slds[4][64];
    int wv = threadIdx.x >> 6, lane = threadIdx.x & 63;
    int node = blockIdx.x * 4 + wv;
    if (node >= N) return;
    int rs = row_ptr[node], re = row_ptr[node + 1];
    float ad = alpha_d[node];

    float m = -1e30f;
    for (int base = rs; base < re; base += 64) {
        int i = base + lane;
        if (i < re) {
            int s = csr_src[i];
            m = fmaxf(m, leaky(alpha_s[s] + ad));
        }
    }
#pragma unroll
    for (int off = 32; off >= 1; off >>= 1) m = fmaxf(m, __shfl_xor(m, off));

    float den = 0.f, acc = 0.f;
    float* wp = &wlds[wv][0];
    int*   sp = &slds[wv][0];
    for (int base = rs; base < re; base += 64) {
        int i = base + lane;
        float w = 0.f;
        int s = 0;
        if (i < re) {
            s = csr_src[i];
            w = __expf(leaky(alpha_s[s] + ad) - m);
        }
        den += w;
        sp[lane] = s;
        wp[lane] = w;
        int cnt = min(64, re - base);
#pragma unroll 4
        for (int j = 0; j < cnt; j++) {
            int s2 = sp[j];
            acc += wp[j] * (float)hsrc[(size_t)s2 * 64 + lane];
        }
    }
#pragma unroll
    for (int off = 32; off >= 1; off >>= 1) den += __shfl_xor(den, off);
    float v = acc / (den + 1e-16f) + bias[lane];
    out[(size_t)node * 64 + lane] = v;
}

// ---------------- head MLP ----------------
__global__ __launch_bounds__(256) void mlp_head_kernel(const float* __restrict__ hin,
                                                       const float* __restrict__ Wo1,
                                                       const float* __restrict__ bo1,
                                                       const float* __restrict__ Wo2,
                                                       const float* __restrict__ bo2,
                                                       float* __restrict__ out, int N) {
    __shared__ float w1[64 * 32];
    __shared__ float w2[32];
    __shared__ float b1s[32];
    int tid = threadIdx.x;
#pragma unroll
    for (int i = 0; i < 8; i++) w1[tid + i * 256] = Wo1[tid + i * 256];
    if (tid < 32) { w2[tid] = Wo2[tid]; b1s[tid] = bo1[tid]; }
    __syncthreads();
    int n = blockIdx.x * blockDim.x + tid;
    if (n >= N) return;
    float hrow[64];
    const float* pr = hin + (size_t)n * 64;
#pragma unroll
    for (int i = 0; i < 64; i++) hrow[i] = pr[i];
    float sum = 0.f;
    for (int j = 0; j < 32; j++) {
        float a = b1s[j];
#pragma unroll
        for (int k = 0; k < 64; k++) a += hrow[k] * w1[k * 32 + j];
        a = fmaxf(a, 0.f);
        sum += a * w2[j];
    }
    out[n] = sum + bo2[0];
}

// ---------------- launch ----------------
extern "C" void kernel_launch(void* const* d_in, const int* in_sizes, int n_in,
                              void* d_out, int out_size, void* d_ws, size_t ws_size,
                              hipStream_t stream) {
    const float* x     = (const float*)d_in[0];
    const float* W_emb = (const float*)d_in[1];
    const float* b_emb = (const float*)d_in[2];
    const float* W0    = (const float*)d_in[3];
    const float* as0   = (const float*)d_in[4];
    const float* ad0   = (const float*)d_in[5];
    const float* b0    = (const float*)d_in[6];
    const float* W1    = (const float*)d_in[7];
    const float* as1   = (const float*)d_in[8];
    const float* ad1   = (const float*)d_in[9];
    const float* b1    = (const float*)d_in[10];
    const float* W2    = (const float*)d_in[11];
    const float* as2   = (const float*)d_in[12];
    const float* ad2   = (const float*)d_in[13];
    const float* b2    = (const float*)d_in[14];
    const float* Wo1   = (const float*)d_in[15];
    const float* bo1   = (const float*)d_in[16];
    const float* Wo2   = (const float*)d_in[17];
    const float* bo2   = (const float*)d_in[18];
    const int* eidx    = (const int*)d_in[19];

    const int N = in_sizes[0] / 128;
    const int E = in_sizes[19] / 2;
    const int* esrc = eidx;
    const int* edst = eidx + E;
    const int gmB  = (N + 127) / 128;
    const int Mpad = gmB * 128;

    char* w = (char*)d_ws;
    auto alloc = [&](size_t bytes) {
        char* p = w;
        w += (bytes + 255) & ~(size_t)255;
        return (void*)p;
    };
    _Float16* hOut = (_Float16*)alloc((size_t)Mpad * 256 * 2);  // f16 h (gather source)
    _Float16* PHh  = (_Float16*)alloc((size_t)Mpad * 256 * 2);  // A planes hi
    _Float16* PHl  = (_Float16*)alloc((size_t)Mpad * 256 * 2);  // A planes lo
    _Float16* XPh  = (_Float16*)alloc((size_t)Mpad * 128 * 2);  // x planes hi
    _Float16* XPl  = (_Float16*)alloc((size_t)Mpad * 128 * 2);
    float* bufA    = (float*)alloc((size_t)Mpad * 64 * 4);      // agg1 out (fp32)
    float* aS      = (float*)alloc((size_t)N * 4 * 4);
    float* aD      = (float*)alloc((size_t)N * 4 * 4);
    int*   row_ptr = (int*)alloc((size_t)(N + 1) * 4);
    int*   cursor  = (int*)alloc((size_t)N * 4);
    int*   cnt     = (int*)alloc((size_t)N * 4);
    int*   csr     = (int*)alloc((size_t)(E + N) * 4);
    _Float16* WeH  = (_Float16*)alloc(128 * 64 * 2);
    _Float16* WeL  = (_Float16*)alloc(128 * 64 * 2);
    _Float16* W0H  = (_Float16*)alloc(64 * 256 * 2);
    _Float16* W0L  = (_Float16*)alloc(64 * 256 * 2);
    _Float16* W1H  = (_Float16*)alloc(256 * 256 * 2);
    _Float16* W1L  = (_Float16*)alloc(256 * 256 * 2);
    _Float16* W2H  = (_Float16*)alloc(256 * 64 * 2);
    _Float16* W2L  = (_Float16*)alloc(256 * 64 * 2);

    // CSR build
    hipMemsetAsync(cnt, 0, (size_t)N * 4, stream);
    hist_kernel<<<(E + 255) / 256, 256, 0, stream>>>(edst, E, cnt);
    scan_kernel<<<1, 1024, 0, stream>>>(cnt, row_ptr, cursor, N);
    scatter_kernel<<<(E + N + 255) / 256, 256, 0, stream>>>(esrc, edst, E, N, cursor, csr);

    // weight planes
    prep_weight_kernel<<<(128 * 64 + 255) / 256, 256, 0, stream>>>(W_emb, WeH, WeL, 128, 64);
    prep_weight_kernel<<<(64 * 256 + 255) / 256, 256, 0, stream>>>(W0, W0H, W0L, 64, 256);
    prep_weight_kernel<<<(256 * 256 + 255) / 256, 256, 0, stream>>>(W1, W1H, W1L, 256, 256);
    prep_weight_kernel<<<(256 * 64 + 255) / 256, 256, 0, stream>>>(W2, W2H, W2L, 256, 64);

    int gn4 = (N + 3) / 4;

    // embedding: planes(x) -> relu(x@W_emb + b_emb) as hi/lo planes (K=64 for GEMM0)
    prep_act_kernel<<<((size_t)Mpad * 16 + 255) / 256, 256, 0, stream>>>(x, XPh, XPl, N, Mpad, 16, 128);
    gemm_emb_kernel<<<dim3(gmB, 1), 256, 0, stream>>>(XPh, XPl, WeH, WeL, b_emb, PHh, PHl, Mpad, N, 128);

    // GAT layer 0: GEMM (+fused alphas) -> aggregate (writes planes)
    gemm_gat_kernel<<<dim3(gmB, 2), 256, 0, stream>>>(PHh, PHl, W0H, W0L, as0, ad0, hOut, aS, aD, Mpad, N, 64);
    aggregate4_kernel<<<gn4, 256, 0, stream>>>(hOut, aS, aD, row_ptr, csr, b0, PHh, PHl, N, Mpad);

    // GAT layer 1
    gemm_gat_kernel<<<dim3(gmB, 2), 256, 0, stream>>>(PHh, PHl, W1H, W1L, as1, ad1, hOut, aS, aD, Mpad, N, 256);
    aggregate4_kernel<<<gn4, 256, 0, stream>>>(hOut, aS, aD, row_ptr, csr, b1, PHh, PHl, N, Mpad);

    // GAT layer 2 (1 head, no relu)
    gemm_l2_kernel<<<dim3(gmB, 1), 256, 0, stream>>>(PHh, PHl, W2H, W2L, as2, ad2, hOut, aS, aD, Mpad, N, 256);
    aggregate1_kernel<<<gn4, 256, 0, stream>>>(hOut, aS, aD, row_ptr, csr, b2, bufA, N);

    // head MLP -> out [N,1] fp32
    mlp_head_kernel<<<(N + 255) / 256, 256, 0, stream>>>(bufA, Wo1, bo1, Wo2, bo2, (float*)d_out, N);
}

// Round 8
// 551.741 us; speedup vs baseline: 1.4474x; 1.1666x over previous
//
#include <hip/hip_runtime.h>

typedef _Float16 h8_t __attribute__((ext_vector_type(8)));
typedef _Float16 h4_t __attribute__((ext_vector_type(4)));
typedef float floatx4 __attribute__((ext_vector_type(4)));

__device__ __forceinline__ float leaky(float v) { return v >= 0.f ? v : 0.2f * v; }

// ---------------- CSR build ----------------
__global__ void hist_kernel(const int* __restrict__ dst, int E, int* __restrict__ cnt) {
    int e = blockIdx.x * blockDim.x + threadIdx.x;
    if (e < E) atomicAdd(&cnt[dst[e]], 1);
}

// phase 1: per-block sums of (cnt[i]+1), 256 elems/block
__global__ __launch_bounds__(256) void blocksum_kernel(const int* __restrict__ cnt, int N,
                                                       int* __restrict__ bsum) {
    __shared__ int red[256];
    int tid = threadIdx.x;
    int idx = blockIdx.x * 256 + tid;
    red[tid] = idx < N ? cnt[idx] + 1 : 0;
    __syncthreads();
#pragma unroll
    for (int off = 128; off >= 1; off >>= 1) {
        if (tid < off) red[tid] += red[tid + off];
        __syncthreads();
    }
    if (tid == 0) bsum[blockIdx.x] = red[0];
}

// phase 2: single-block exclusive scan of block sums; writes grand total to *total
__global__ __launch_bounds__(256) void scanbsum_kernel(int* __restrict__ bsum, int nb,
                                                       int* __restrict__ total) {
    __shared__ int part[256];
    int tid = threadIdx.x;
    int per = (nb + 255) / 256;
    int s0 = tid * per, s1 = min(s0 + per, nb);
    int s = 0;
    for (int i = s0; i < s1; i++) s += bsum[i];
    part[tid] = s;
    __syncthreads();
    for (int off = 1; off < 256; off <<= 1) {
        int v = (tid >= off) ? part[tid - off] : 0;
        __syncthreads();
        part[tid] += v;
        __syncthreads();
    }
    int base = (tid == 0) ? 0 : part[tid - 1];
    for (int i = s0; i < s1; i++) {
        int v = bsum[i];
        bsum[i] = base;
        base += v;
    }
    if (tid == 255) *total = part[255];
}

// phase 3: intra-block exclusive scan + block offset -> row_ptr, cursor
__global__ __launch_bounds__(256) void rowptr_kernel(const int* __restrict__ cnt,
                                                     const int* __restrict__ bsum, int N,
                                                     int* __restrict__ row_ptr,
                                                     int* __restrict__ cursor) {
    __shared__ int lds[256];
    int tid = threadIdx.x;
    int idx = blockIdx.x * 256 + tid;
    int v = idx < N ? cnt[idx] + 1 : 0;
    lds[tid] = v;
    __syncthreads();
    for (int off = 1; off < 256; off <<= 1) {
        int t = (tid >= off) ? lds[tid - off] : 0;
        __syncthreads();
        lds[tid] += t;
        __syncthreads();
    }
    if (idx < N) {
        int p = bsum[blockIdx.x] + lds[tid] - v;
        row_ptr[idx] = p;
        cursor[idx] = p;
    }
}

__global__ void scatter_kernel(const int* __restrict__ src, const int* __restrict__ dst,
                               int E, int N, int* __restrict__ cursor, int* __restrict__ csr_src) {
    int e = blockIdx.x * blockDim.x + threadIdx.x;
    if (e >= E + N) return;
    int s, d;
    if (e < E) { s = src[e]; d = dst[e]; }
    else       { s = e - E;  d = s; }
    int pos = atomicAdd(&cursor[d], 1);
    csr_src[pos] = s;
}

// ---------------- weight prep: fp32 [K,N] -> f16 hi/lo planes frag order [K/8][N][8] ----------------
__global__ void prep_weight_kernel(const float* __restrict__ W,
                                   _Float16* __restrict__ Wh, _Float16* __restrict__ Wl,
                                   int K, int N) {
    int idx = blockIdx.x * blockDim.x + threadIdx.x;
    if (idx >= K * N) return;
    int k = idx / N, n = idx % N;
    float v = W[idx];
    _Float16 hi = (_Float16)v;
    _Float16 lo = (_Float16)(v - (float)hi);
    size_t o = ((size_t)(k >> 3) * N + n) * 8 + (k & 7);
    Wh[o] = hi; Wl[o] = lo;
}

// ---------------- activation prep: fp32 [M,K] -> hi/lo planes [K/8][Mpad][8] ----------------
__global__ void prep_act_kernel(const float* __restrict__ X,
                                _Float16* __restrict__ Ph, _Float16* __restrict__ Pl,
                                int M, int Mpad, int Kg, int K) {
    int idx = blockIdx.x * blockDim.x + threadIdx.x;
    if (idx >= Mpad * Kg) return;
    int row = idx / Kg, kg = idx - row * Kg;
    float vs[8] = {0.f, 0.f, 0.f, 0.f, 0.f, 0.f, 0.f, 0.f};
    if (row < M) {
        const float4* p = (const float4*)(X + (size_t)row * K + kg * 8);
        float4 a = p[0], b = p[1];
        vs[0] = a.x; vs[1] = a.y; vs[2] = a.z; vs[3] = a.w;
        vs[4] = b.x; vs[5] = b.y; vs[6] = b.z; vs[7] = b.w;
    }
    h8_t hh, hl;
#pragma unroll
    for (int j = 0; j < 8; j++) {
        _Float16 hi = (_Float16)vs[j];
        hh[j] = hi;
        hl[j] = (_Float16)(vs[j] - (float)hi);
    }
    size_t o = ((size_t)kg * Mpad + row) * 8;
    *reinterpret_cast<h8_t*>(Ph + o) = hh;
    *reinterpret_cast<h8_t*>(Pl + o) = hl;
}

// ---------------- embedding GEMM: planes(x) @ W_emb + bias, relu -> hi/lo planes [64/8][Mpad][8] ----------------
__global__ __launch_bounds__(256) void gemm_emb_kernel(
        const _Float16* __restrict__ Ah, const _Float16* __restrict__ Al,
        const _Float16* __restrict__ Bh, const _Float16* __restrict__ Bl,
        const float* __restrict__ bias,
        _Float16* __restrict__ Ph, _Float16* __restrict__ Pl,
        int Mpad, int M, int K) {
    const int Nn = 64;
    int tid = threadIdx.x;
    int wv = tid >> 6, lane = tid & 63;
    int m16 = lane & 15, quad = lane >> 4;
    int row0 = blockIdx.x * 128 + wv * 32;

    floatx4 acc[2][4];
#pragma unroll
    for (int t = 0; t < 2; t++)
#pragma unroll
        for (int c = 0; c < 4; c++)
#pragma unroll
            for (int i = 0; i < 4; i++) acc[t][c][i] = 0.f;

    size_t aoff = ((size_t)quad * Mpad + row0 + m16) * 8;
    size_t boff = ((size_t)quad * Nn + m16) * 8;
    const size_t aStep = (size_t)Mpad * 32;
    const size_t bStep = (size_t)Nn * 32;

    for (int kt = 0; kt < K; kt += 32) {
        h8_t ah0 = *reinterpret_cast<const h8_t*>(Ah + aoff);
        h8_t ah1 = *reinterpret_cast<const h8_t*>(Ah + aoff + 128);
        h8_t al0 = *reinterpret_cast<const h8_t*>(Al + aoff);
        h8_t al1 = *reinterpret_cast<const h8_t*>(Al + aoff + 128);
#pragma unroll
        for (int c = 0; c < 4; c++) {
            h8_t bh = *reinterpret_cast<const h8_t*>(Bh + boff + c * 128);
            h8_t bl = *reinterpret_cast<const h8_t*>(Bl + boff + c * 128);
            acc[0][c] = __builtin_amdgcn_mfma_f32_16x16x32_f16(ah0, bh, acc[0][c], 0, 0, 0);
            acc[1][c] = __builtin_amdgcn_mfma_f32_16x16x32_f16(ah1, bh, acc[1][c], 0, 0, 0);
            acc[0][c] = __builtin_amdgcn_mfma_f32_16x16x32_f16(ah0, bl, acc[0][c], 0, 0, 0);
            acc[1][c] = __builtin_amdgcn_mfma_f32_16x16x32_f16(ah1, bl, acc[1][c], 0, 0, 0);
            acc[0][c] = __builtin_amdgcn_mfma_f32_16x16x32_f16(al0, bh, acc[0][c], 0, 0, 0);
            acc[1][c] = __builtin_amdgcn_mfma_f32_16x16x32_f16(al1, bh, acc[1][c], 0, 0, 0);
        }
        aoff += aStep; boff += bStep;
    }

#pragma unroll
    for (int t = 0; t < 2; t++) {
#pragma unroll
        for (int c = 0; c < 4; c++) {
            int col = c * 16 + m16;
            float bv = bias[col];
            size_t obase = ((size_t)(col >> 3) * Mpad) * 8 + (col & 7);
#pragma unroll
            for (int i = 0; i < 4; i++) {
                int r = row0 + t * 16 + quad * 4 + i;
                float v = fmaxf(acc[t][c][i] + bv, 0.f);
                _Float16 hi = (_Float16)v;
                size_t o = obase + (size_t)r * 8;
                Ph[o] = hi;
                Pl[o] = (_Float16)(v - (float)hi);
            }
        }
    }
}

// ---------------- GAT GEMM (Nn=256): planes @ W -> h f16 row-major + fused alphas (2 heads/block) ----------------
__global__ __launch_bounds__(256) void gemm_gat_kernel(
        const _Float16* __restrict__ Ah, const _Float16* __restrict__ Al,
        const _Float16* __restrict__ Bh, const _Float16* __restrict__ Bl,
        const float* __restrict__ a_src, const float* __restrict__ a_dst,
        _Float16* __restrict__ hOut, float* __restrict__ aS, float* __restrict__ aD,
        int Mpad, int M, int K) {
    const int Nn = 256;
    int tid = threadIdx.x;
    int wv = tid >> 6, lane = tid & 63;
    int m16 = lane & 15, quad = lane >> 4;
    int row0 = blockIdx.x * 128 + wv * 32;
    int colBase = blockIdx.y * 128;

    floatx4 acc[2][8];
#pragma unroll
    for (int t = 0; t < 2; t++)
#pragma unroll
        for (int c = 0; c < 8; c++)
#pragma unroll
            for (int i = 0; i < 4; i++) acc[t][c][i] = 0.f;

    size_t aoff = ((size_t)quad * Mpad + row0 + m16) * 8;
    size_t boff = ((size_t)quad * Nn + colBase + m16) * 8;
    const size_t aStep = (size_t)Mpad * 32;
    const size_t bStep = (size_t)Nn * 32;

    for (int kt = 0; kt < K; kt += 32) {
        h8_t ah0 = *reinterpret_cast<const h8_t*>(Ah + aoff);
        h8_t ah1 = *reinterpret_cast<const h8_t*>(Ah + aoff + 128);
        h8_t al0 = *reinterpret_cast<const h8_t*>(Al + aoff);
        h8_t al1 = *reinterpret_cast<const h8_t*>(Al + aoff + 128);
#pragma unroll
        for (int c = 0; c < 8; c++) {
            h8_t bh = *reinterpret_cast<const h8_t*>(Bh + boff + c * 128);
            h8_t bl = *reinterpret_cast<const h8_t*>(Bl + boff + c * 128);
            acc[0][c] = __builtin_amdgcn_mfma_f32_16x16x32_f16(ah0, bh, acc[0][c], 0, 0, 0);
            acc[1][c] = __builtin_amdgcn_mfma_f32_16x16x32_f16(ah1, bh, acc[1][c], 0, 0, 0);
            acc[0][c] = __builtin_amdgcn_mfma_f32_16x16x32_f16(ah0, bl, acc[0][c], 0, 0, 0);
            acc[1][c] = __builtin_amdgcn_mfma_f32_16x16x32_f16(ah1, bl, acc[1][c], 0, 0, 0);
            acc[0][c] = __builtin_amdgcn_mfma_f32_16x16x32_f16(al0, bh, acc[0][c], 0, 0, 0);
            acc[1][c] = __builtin_amdgcn_mfma_f32_16x16x32_f16(al1, bh, acc[1][c], 0, 0, 0);
        }
        aoff += aStep; boff += bStep;
    }

    float asv[8], adv[8];
#pragma unroll
    for (int c = 0; c < 8; c++) {
        asv[c] = a_src[colBase + c * 16 + m16];
        adv[c] = a_dst[colBase + c * 16 + m16];
    }
    int hb = colBase >> 6;
#pragma unroll
    for (int t = 0; t < 2; t++) {
#pragma unroll
        for (int i = 0; i < 4; i++) {
            int r = row0 + t * 16 + quad * 4 + i;
            float s0 = 0.f, d0 = 0.f, s1 = 0.f, d1 = 0.f;
            size_t ob = (size_t)r * 256 + colBase + m16;
#pragma unroll
            for (int c = 0; c < 8; c++) {
                float v = acc[t][c][i];
                hOut[ob + c * 16] = (_Float16)v;
                if (c < 4) { s0 += v * asv[c]; d0 += v * adv[c]; }
                else       { s1 += v * asv[c]; d1 += v * adv[c]; }
            }
#pragma unroll
            for (int off = 1; off < 16; off <<= 1) {
                s0 += __shfl_xor(s0, off);
                d0 += __shfl_xor(d0, off);
                s1 += __shfl_xor(s1, off);
                d1 += __shfl_xor(d1, off);
            }
            if (m16 == 0 && r < M) {
                aS[r * 4 + hb] = s0;     aD[r * 4 + hb] = d0;
                aS[r * 4 + hb + 1] = s1; aD[r * 4 + hb + 1] = d1;
            }
        }
    }
}

// ---------------- layer-2 GEMM (Nn=64, 1 head): -> h f16 row-major + fused alphas ----------------
__global__ __launch_bounds__(256) void gemm_l2_kernel(
        const _Float16* __restrict__ Ah, const _Float16* __restrict__ Al,
        const _Float16* __restrict__ Bh, const _Float16* __restrict__ Bl,
        const float* __restrict__ a_src, const float* __restrict__ a_dst,
        _Float16* __restrict__ hOut, float* __restrict__ aS, float* __restrict__ aD,
        int Mpad, int M, int K) {
    const int Nn = 64;
    int tid = threadIdx.x;
    int wv = tid >> 6, lane = tid & 63;
    int m16 = lane & 15, quad = lane >> 4;
    int row0 = blockIdx.x * 128 + wv * 32;

    floatx4 acc[2][4];
#pragma unroll
    for (int t = 0; t < 2; t++)
#pragma unroll
        for (int c = 0; c < 4; c++)
#pragma unroll
            for (int i = 0; i < 4; i++) acc[t][c][i] = 0.f;

    size_t aoff = ((size_t)quad * Mpad + row0 + m16) * 8;
    size_t boff = ((size_t)quad * Nn + m16) * 8;
    const size_t aStep = (size_t)Mpad * 32;
    const size_t bStep = (size_t)Nn * 32;

    for (int kt = 0; kt < K; kt += 32) {
        h8_t ah0 = *reinterpret_cast<const h8_t*>(Ah + aoff);
        h8_t ah1 = *reinterpret_cast<const h8_t*>(Ah + aoff + 128);
        h8_t al0 = *reinterpret_cast<const h8_t*>(Al + aoff);
        h8_t al1 = *reinterpret_cast<const h8_t*>(Al + aoff + 128);
#pragma unroll
        for (int c = 0; c < 4; c++) {
            h8_t bh = *reinterpret_cast<const h8_t*>(Bh + boff + c * 128);
            h8_t bl = *reinterpret_cast<const h8_t*>(Bl + boff + c * 128);
            acc[0][c] = __builtin_amdgcn_mfma_f32_16x16x32_f16(ah0, bh, acc[0][c], 0, 0, 0);
            acc[1][c] = __builtin_amdgcn_mfma_f32_16x16x32_f16(ah1, bh, acc[1][c], 0, 0, 0);
            acc[0][c] = __builtin_amdgcn_mfma_f32_16x16x32_f16(ah0, bl, acc[0][c], 0, 0, 0);
            acc[1][c] = __builtin_amdgcn_mfma_f32_16x16x32_f16(ah1, bl, acc[1][c], 0, 0, 0);
            acc[0][c] = __builtin_amdgcn_mfma_f32_16x16x32_f16(al0, bh, acc[0][c], 0, 0, 0);
            acc[1][c] = __builtin_amdgcn_mfma_f32_16x16x32_f16(al1, bh, acc[1][c], 0, 0, 0);
        }
        aoff += aStep; boff += bStep;
    }

    float asv[4], adv[4];
#pragma unroll
    for (int c = 0; c < 4; c++) {
        asv[c] = a_src[c * 16 + m16];
        adv[c] = a_dst[c * 16 + m16];
    }
#pragma unroll
    for (int t = 0; t < 2; t++) {
#pragma unroll
        for (int i = 0; i < 4; i++) {
            int r = row0 + t * 16 + quad * 4 + i;
            float s0 = 0.f, d0 = 0.f;
            size_t ob = (size_t)r * 64 + m16;
#pragma unroll
            for (int c = 0; c < 4; c++) {
                float v = acc[t][c][i];
                hOut[ob + c * 16] = (_Float16)v;
                s0 += v * asv[c]; d0 += v * adv[c];
            }
#pragma unroll
            for (int off = 1; off < 16; off <<= 1) {
                s0 += __shfl_xor(s0, off);
                d0 += __shfl_xor(d0, off);
            }
            if (m16 == 0 && r < M) { aS[r] = s0; aD[r] = d0; }
        }
    }
}

// ---------------- aggregation H=4: gathers f16 h, writes hi/lo planes for next GEMM ----------------
__global__ __launch_bounds__(256) void aggregate4_kernel(const _Float16* __restrict__ hsrc,
                                                         const float* __restrict__ alpha_s,
                                                         const float* __restrict__ alpha_d,
                                                         const int* __restrict__ row_ptr,
                                                         const int* __restrict__ csr_src,
                                                         const float* __restrict__ bias,
                                                         _Float16* __restrict__ outH,
                                                         _Float16* __restrict__ outL,
                                                         int N, int Mpad) {
    __shared__ float wlds[4][64][4];
    __shared__ int   slds[4][64];
    int wv = threadIdx.x >> 6, lane = threadIdx.x & 63;
    int node = blockIdx.x * 4 + wv;
    if (node >= N) return;
    int rs = row_ptr[node], re = row_ptr[node + 1];
    int head = lane >> 4, c4 = (lane & 15) * 4;
    float4 ad4 = *(const float4*)(alpha_d + (size_t)node * 4);

    float m0 = -1e30f, m1 = -1e30f, m2 = -1e30f, m3 = -1e30f;
    for (int base = rs; base < re; base += 64) {
        int i = base + lane;
        if (i < re) {
            int s = csr_src[i];
            float4 as = *(const float4*)(alpha_s + (size_t)s * 4);
            m0 = fmaxf(m0, leaky(as.x + ad4.x));
            m1 = fmaxf(m1, leaky(as.y + ad4.y));
            m2 = fmaxf(m2, leaky(as.z + ad4.z));
            m3 = fmaxf(m3, leaky(as.w + ad4.w));
        }
    }
#pragma unroll
    for (int off = 32; off >= 1; off >>= 1) {
        m0 = fmaxf(m0, __shfl_xor(m0, off));
        m1 = fmaxf(m1, __shfl_xor(m1, off));
        m2 = fmaxf(m2, __shfl_xor(m2, off));
        m3 = fmaxf(m3, __shfl_xor(m3, off));
    }

    float den0 = 0.f, den1 = 0.f, den2 = 0.f, den3 = 0.f;
    float a0 = 0.f, a1 = 0.f, a2 = 0.f, a3 = 0.f;
    float* wp = &wlds[wv][0][0];
    int*   sp = &slds[wv][0];
    for (int base = rs; base < re; base += 64) {
        int i = base + lane;
        float w0 = 0.f, w1 = 0.f, w2 = 0.f, w3 = 0.f;
        int s = 0;
        if (i < re) {
            s = csr_src[i];
            float4 as = *(const float4*)(alpha_s + (size_t)s * 4);
            w0 = __expf(leaky(as.x + ad4.x) - m0);
            w1 = __expf(leaky(as.y + ad4.y) - m1);
            w2 = __expf(leaky(as.z + ad4.z) - m2);
            w3 = __expf(leaky(as.w + ad4.w) - m3);
        }
        den0 += w0; den1 += w1; den2 += w2; den3 += w3;
        sp[lane] = s;
        *(float4*)(wp + lane * 4) = make_float4(w0, w1, w2, w3);
        int cnt = min(64, re - base);
#pragma unroll 4
        for (int j = 0; j < cnt; j++) {
            int s2 = sp[j];
            float w = wp[j * 4 + head];
            h4_t hv = *reinterpret_cast<const h4_t*>(hsrc + (size_t)s2 * 256 + (head << 6) + c4);
            a0 += w * (float)hv[0]; a1 += w * (float)hv[1];
            a2 += w * (float)hv[2]; a3 += w * (float)hv[3];
        }
    }
#pragma unroll
    for (int off = 32; off >= 1; off >>= 1) {
        den0 += __shfl_xor(den0, off);
        den1 += __shfl_xor(den1, off);
        den2 += __shfl_xor(den2, off);
        den3 += __shfl_xor(den3, off);
    }
    float den = (head & 2) ? ((head & 1) ? den3 : den2) : ((head & 1) ? den1 : den0);
    float inv = 1.f / (den + 1e-16f);
    int cbase = (head << 6) + c4;
    float v0 = fmaxf(a0 * inv + bias[cbase + 0], 0.f);
    float v1 = fmaxf(a1 * inv + bias[cbase + 1], 0.f);
    float v2 = fmaxf(a2 * inv + bias[cbase + 2], 0.f);
    float v3 = fmaxf(a3 * inv + bias[cbase + 3], 0.f);
    h4_t hv, lv;
    _Float16 h;
    h = (_Float16)v0; hv[0] = h; lv[0] = (_Float16)(v0 - (float)h);
    h = (_Float16)v1; hv[1] = h; lv[1] = (_Float16)(v1 - (float)h);
    h = (_Float16)v2; hv[2] = h; lv[2] = (_Float16)(v2 - (float)h);
    h = (_Float16)v3; hv[3] = h; lv[3] = (_Float16)(v3 - (float)h);
    size_t o = ((size_t)(cbase >> 3) * Mpad + node) * 8 + (cbase & 7);
    *reinterpret_cast<h4_t*>(outH + o) = hv;
    *reinterpret_cast<h4_t*>(outL + o) = lv;
}

// ---------------- aggregation H=1: gathers f16, writes fp32 [N,64] ----------------
__global__ __launch_bounds__(256) void aggregate1_kernel(const _Float16* __restrict__ hsrc,
                                                         const float* __restrict__ alpha_s,
                                                         const float* __restrict__ alpha_d,
                                                         const int* __restrict__ row_ptr,
                                                         const int* __restrict__ csr_src,
                                                         const float* __restrict__ bias,
                                                         float* __restrict__ out, int N) {
    __shared__ float wlds[4][64];
    __shared__ int   slds[4][64];
    int wv = threadIdx.x >> 6, lane = threadIdx.x & 63;
    int node = blockIdx.x * 4 + wv;
    if (node >= N) return;
    int rs = row_ptr[node], re = row_ptr[node + 1];
    float ad = alpha_d[node];

    float m = -1e30f;
    for (int base = rs; base < re; base += 64) {
        int i = base + lane;
        if (i < re) {
            int s = csr_src[i];
            m = fmaxf(m, leaky(alpha_s[s] + ad));
        }
    }
#pragma unroll
    for (int off = 32; off >= 1; off >>= 1) m = fmaxf(m, __shfl_xor(m, off));

    float den = 0.f, acc = 0.f;
    float* wp = &wlds[wv][0];
    int*   sp = &slds[wv][0];
    for (int base = rs; base < re; base += 64) {
        int i = base + lane;
        float w = 0.f;
        int s = 0;
        if (i < re) {
            s = csr_src[i];
            w = __expf(leaky(alpha_s[s] + ad) - m);
        }
        den += w;
        sp[lane] = s;
        wp[lane] = w;
        int cnt = min(64, re - base);
#pragma unroll 4
        for (int j = 0; j < cnt; j++) {
            int s2 = sp[j];
            acc += wp[j] * (float)hsrc[(size_t)s2 * 64 + lane];
        }
    }
#pragma unroll
    for (int off = 32; off >= 1; off >>= 1) den += __shfl_xor(den, off);
    float v = acc / (den + 1e-16f) + bias[lane];
    out[(size_t)node * 64 + lane] = v;
}

// ---------------- head MLP ----------------
__global__ __launch_bounds__(256) void mlp_head_kernel(const float* __restrict__ hin,
                                                       const float* __restrict__ Wo1,
                                                       const float* __restrict__ bo1,
                                                       const float* __restrict__ Wo2,
                                                       const float* __restrict__ bo2,
                                                       float* __restrict__ out, int N) {
    __shared__ float w1[64 * 32];
    __shared__ float w2[32];
    __shared__ float b1s[32];
    int tid = threadIdx.x;
#pragma unroll
    for (int i = 0; i < 8; i++) w1[tid + i * 256] = Wo1[tid + i * 256];
    if (tid < 32) { w2[tid] = Wo2[tid]; b1s[tid] = bo1[tid]; }
    __syncthreads();
    int n = blockIdx.x * blockDim.x + tid;
    if (n >= N) return;
    float hrow[64];
    const float* pr = hin + (size_t)n * 64;
#pragma unroll
    for (int i = 0; i < 64; i++) hrow[i] = pr[i];
    float sum = 0.f;
    for (int j = 0; j < 32; j++) {
        float a = b1s[j];
#pragma unroll
        for (int k = 0; k < 64; k++) a += hrow[k] * w1[k * 32 + j];
        a = fmaxf(a, 0.f);
        sum += a * w2[j];
    }
    out[n] = sum + bo2[0];
}

// ---------------- launch ----------------
extern "C" void kernel_launch(void* const* d_in, const int* in_sizes, int n_in,
                              void* d_out, int out_size, void* d_ws, size_t ws_size,
                              hipStream_t stream) {
    const float* x     = (const float*)d_in[0];
    const float* W_emb = (const float*)d_in[1];
    const float* b_emb = (const float*)d_in[2];
    const float* W0    = (const float*)d_in[3];
    const float* as0   = (const float*)d_in[4];
    const float* ad0   = (const float*)d_in[5];
    const float* b0    = (const float*)d_in[6];
    const float* W1    = (const float*)d_in[7];
    const float* as1   = (const float*)d_in[8];
    const float* ad1   = (const float*)d_in[9];
    const float* b1    = (const float*)d_in[10];
    const float* W2    = (const float*)d_in[11];
    const float* as2   = (const float*)d_in[12];
    const float* ad2   = (const float*)d_in[13];
    const float* b2    = (const float*)d_in[14];
    const float* Wo1   = (const float*)d_in[15];
    const float* bo1   = (const float*)d_in[16];
    const float* Wo2   = (const float*)d_in[17];
    const float* bo2   = (const float*)d_in[18];
    const int* eidx    = (const int*)d_in[19];

    const int N = in_sizes[0] / 128;
    const int E = in_sizes[19] / 2;
    const int* esrc = eidx;
    const int* edst = eidx + E;
    const int gmB  = (N + 127) / 128;
    const int Mpad = gmB * 128;
    const int nb   = (N + 255) / 256;

    char* w = (char*)d_ws;
    auto alloc = [&](size_t bytes) {
        char* p = w;
        w += (bytes + 255) & ~(size_t)255;
        return (void*)p;
    };
    _Float16* hOut = (_Float16*)alloc((size_t)Mpad * 256 * 2);  // f16 h (gather source)
    _Float16* PHh  = (_Float16*)alloc((size_t)Mpad * 256 * 2);  // A planes hi
    _Float16* PHl  = (_Float16*)alloc((size_t)Mpad * 256 * 2);  // A planes lo
    _Float16* XPh  = (_Float16*)alloc((size_t)Mpad * 128 * 2);  // x planes hi
    _Float16* XPl  = (_Float16*)alloc((size_t)Mpad * 128 * 2);
    float* bufA    = (float*)alloc((size_t)Mpad * 64 * 4);      // agg1 out (fp32)
    float* aS      = (float*)alloc((size_t)N * 4 * 4);
    float* aD      = (float*)alloc((size_t)N * 4 * 4);
    int*   row_ptr = (int*)alloc((size_t)(N + 1) * 4);
    int*   cursor  = (int*)alloc((size_t)N * 4);
    int*   cnt     = (int*)alloc((size_t)N * 4);
    int*   bsum    = (int*)alloc((size_t)nb * 4);
    int*   csr     = (int*)alloc((size_t)(E + N) * 4);
    _Float16* WeH  = (_Float16*)alloc(128 * 64 * 2);
    _Float16* WeL  = (_Float16*)alloc(128 * 64 * 2);
    _Float16* W0H  = (_Float16*)alloc(64 * 256 * 2);
    _Float16* W0L  = (_Float16*)alloc(64 * 256 * 2);
    _Float16* W1H  = (_Float16*)alloc(256 * 256 * 2);
    _Float16* W1L  = (_Float16*)alloc(256 * 256 * 2);
    _Float16* W2H  = (_Float16*)alloc(256 * 64 * 2);
    _Float16* W2L  = (_Float16*)alloc(256 * 64 * 2);

    // CSR build (multi-block scan)
    hipMemsetAsync(cnt, 0, (size_t)N * 4, stream);
    hist_kernel<<<(E + 255) / 256, 256, 0, stream>>>(edst, E, cnt);
    blocksum_kernel<<<nb, 256, 0, stream>>>(cnt, N, bsum);
    scanbsum_kernel<<<1, 256, 0, stream>>>(bsum, nb, row_ptr + N);
    rowptr_kernel<<<nb, 256, 0, stream>>>(cnt, bsum, N, row_ptr, cursor);
    scatter_kernel<<<(E + N + 255) / 256, 256, 0, stream>>>(esrc, edst, E, N, cursor, csr);

    // weight planes
    prep_weight_kernel<<<(128 * 64 + 255) / 256, 256, 0, stream>>>(W_emb, WeH, WeL, 128, 64);
    prep_weight_kernel<<<(64 * 256 + 255) / 256, 256, 0, stream>>>(W0, W0H, W0L, 64, 256);
    prep_weight_kernel<<<(256 * 256 + 255) / 256, 256, 0, stream>>>(W1, W1H, W1L, 256, 256);
    prep_weight_kernel<<<(256 * 64 + 255) / 256, 256, 0, stream>>>(W2, W2H, W2L, 256, 64);

    int gn4 = (N + 3) / 4;

    // embedding: planes(x) -> relu(x@W_emb + b_emb) as hi/lo planes
    prep_act_kernel<<<((size_t)Mpad * 16 + 255) / 256, 256, 0, stream>>>(x, XPh, XPl, N, Mpad, 16, 128);
    gemm_emb_kernel<<<dim3(gmB, 1), 256, 0, stream>>>(XPh, XPl, WeH, WeL, b_emb, PHh, PHl, Mpad, N, 128);

    // GAT layer 0: GEMM (+fused alphas) -> aggregate (writes planes)
    gemm_gat_kernel<<<dim3(gmB, 2), 256, 0, stream>>>(PHh, PHl, W0H, W0L, as0, ad0, hOut, aS, aD, Mpad, N, 64);
    aggregate4_kernel<<<gn4, 256, 0, stream>>>(hOut, aS, aD, row_ptr, csr, b0, PHh, PHl, N, Mpad);

    // GAT layer 1
    gemm_gat_kernel<<<dim3(gmB, 2), 256, 0, stream>>>(PHh, PHl, W1H, W1L, as1, ad1, hOut, aS, aD, Mpad, N, 256);
    aggregate4_kernel<<<gn4, 256, 0, stream>>>(hOut, aS, aD, row_ptr, csr, b1, PHh, PHl, N, Mpad);

    // GAT layer 2 (1 head, no relu)
    gemm_l2_kernel<<<dim3(gmB, 1), 256, 0, stream>>>(PHh, PHl, W2H, W2L, as2, ad2, hOut, aS, aD, Mpad, N, 256);
    aggregate1_kernel<<<gn4, 256, 0, stream>>>(hOut, aS, aD, row_ptr, csr, b2, bufA, N);

    // head MLP -> out [N,1] fp32
    mlp_head_kernel<<<(N + 255) / 256, 256, 0, stream>>>(bufA, Wo1, bo1, Wo2, bo2, (float*)d_out, N);
}

// Round 9
// 528.897 us; speedup vs baseline: 1.5099x; 1.0432x over previous
//
#include <hip/hip_runtime.h>

typedef _Float16 h8_t __attribute__((ext_vector_type(8)));
typedef _Float16 h4_t __attribute__((ext_vector_type(4)));
typedef float floatx4 __attribute__((ext_vector_type(4)));

__device__ __forceinline__ float leaky(float v) { return v >= 0.f ? v : 0.2f * v; }

// ---------------- CSR build ----------------
__global__ void hist_kernel(const int* __restrict__ dst, int E, int* __restrict__ cnt) {
    int e = blockIdx.x * blockDim.x + threadIdx.x;
    if (e < E) atomicAdd(&cnt[dst[e]], 1);
}

__global__ __launch_bounds__(256) void blocksum_kernel(const int* __restrict__ cnt, int N,
                                                       int* __restrict__ bsum) {
    __shared__ int red[256];
    int tid = threadIdx.x;
    int idx = blockIdx.x * 256 + tid;
    red[tid] = idx < N ? cnt[idx] + 1 : 0;
    __syncthreads();
#pragma unroll
    for (int off = 128; off >= 1; off >>= 1) {
        if (tid < off) red[tid] += red[tid + off];
        __syncthreads();
    }
    if (tid == 0) bsum[blockIdx.x] = red[0];
}

__global__ __launch_bounds__(256) void scanbsum_kernel(int* __restrict__ bsum, int nb,
                                                       int* __restrict__ total) {
    __shared__ int part[256];
    int tid = threadIdx.x;
    int per = (nb + 255) / 256;
    int s0 = tid * per, s1 = min(s0 + per, nb);
    int s = 0;
    for (int i = s0; i < s1; i++) s += bsum[i];
    part[tid] = s;
    __syncthreads();
    for (int off = 1; off < 256; off <<= 1) {
        int v = (tid >= off) ? part[tid - off] : 0;
        __syncthreads();
        part[tid] += v;
        __syncthreads();
    }
    int base = (tid == 0) ? 0 : part[tid - 1];
    for (int i = s0; i < s1; i++) {
        int v = bsum[i];
        bsum[i] = base;
        base += v;
    }
    if (tid == 255) *total = part[255];
}

__global__ __launch_bounds__(256) void rowptr_kernel(const int* __restrict__ cnt,
                                                     const int* __restrict__ bsum, int N,
                                                     int* __restrict__ row_ptr,
                                                     int* __restrict__ cursor) {
    __shared__ int lds[256];
    int tid = threadIdx.x;
    int idx = blockIdx.x * 256 + tid;
    int v = idx < N ? cnt[idx] + 1 : 0;
    lds[tid] = v;
    __syncthreads();
    for (int off = 1; off < 256; off <<= 1) {
        int t = (tid >= off) ? lds[tid - off] : 0;
        __syncthreads();
        lds[tid] += t;
        __syncthreads();
    }
    if (idx < N) {
        int p = bsum[blockIdx.x] + lds[tid] - v;
        row_ptr[idx] = p;
        cursor[idx] = p;
    }
}

__global__ void scatter_kernel(const int* __restrict__ src, const int* __restrict__ dst,
                               int E, int N, int* __restrict__ cursor, int* __restrict__ csr_src) {
    int e = blockIdx.x * blockDim.x + threadIdx.x;
    if (e >= E + N) return;
    int s, d;
    if (e < E) { s = src[e]; d = dst[e]; }
    else       { s = e - E;  d = s; }
    int pos = atomicAdd(&cursor[d], 1);
    csr_src[pos] = s;
}

// ---------------- weight prep: fp32 [K,N] -> f16 hi/lo planes frag order [K/8][N][8] ----------------
__global__ void prep_weight_kernel(const float* __restrict__ W,
                                   _Float16* __restrict__ Wh, _Float16* __restrict__ Wl,
                                   int K, int N) {
    int idx = blockIdx.x * blockDim.x + threadIdx.x;
    if (idx >= K * N) return;
    int k = idx / N, n = idx % N;
    float v = W[idx];
    _Float16 hi = (_Float16)v;
    _Float16 lo = (_Float16)(v - (float)hi);
    size_t o = ((size_t)(k >> 3) * N + n) * 8 + (k & 7);
    Wh[o] = hi; Wl[o] = lo;
}

// ---------------- activation prep: fp32 [M,K] -> hi/lo planes [K/8][Mpad][8] ----------------
__global__ void prep_act_kernel(const float* __restrict__ X,
                                _Float16* __restrict__ Ph, _Float16* __restrict__ Pl,
                                int M, int Mpad, int Kg, int K) {
    int idx = blockIdx.x * blockDim.x + threadIdx.x;
    if (idx >= Mpad * Kg) return;
    int row = idx / Kg, kg = idx - row * Kg;
    float vs[8] = {0.f, 0.f, 0.f, 0.f, 0.f, 0.f, 0.f, 0.f};
    if (row < M) {
        const float4* p = (const float4*)(X + (size_t)row * K + kg * 8);
        float4 a = p[0], b = p[1];
        vs[0] = a.x; vs[1] = a.y; vs[2] = a.z; vs[3] = a.w;
        vs[4] = b.x; vs[5] = b.y; vs[6] = b.z; vs[7] = b.w;
    }
    h8_t hh, hl;
#pragma unroll
    for (int j = 0; j < 8; j++) {
        _Float16 hi = (_Float16)vs[j];
        hh[j] = hi;
        hl[j] = (_Float16)(vs[j] - (float)hi);
    }
    size_t o = ((size_t)kg * Mpad + row) * 8;
    *reinterpret_cast<h8_t*>(Ph + o) = hh;
    *reinterpret_cast<h8_t*>(Pl + o) = hl;
}

// ---------------- embedding GEMM -> hi/lo planes, LDS-staged coalesced stores ----------------
__global__ __launch_bounds__(256) void gemm_emb_kernel(
        const _Float16* __restrict__ Ah, const _Float16* __restrict__ Al,
        const _Float16* __restrict__ Bh, const _Float16* __restrict__ Bl,
        const float* __restrict__ bias,
        _Float16* __restrict__ Ph, _Float16* __restrict__ Pl,
        int Mpad, int M, int K) {
    const int Nn = 64;
    __shared__ _Float16 stH[4][16][72];
    __shared__ _Float16 stL[4][16][72];
    int tid = threadIdx.x;
    int wv = tid >> 6, lane = tid & 63;
    int m16 = lane & 15, quad = lane >> 4;
    int row0 = blockIdx.x * 128 + wv * 32;

    floatx4 acc[2][4];
#pragma unroll
    for (int t = 0; t < 2; t++)
#pragma unroll
        for (int c = 0; c < 4; c++)
#pragma unroll
            for (int i = 0; i < 4; i++) acc[t][c][i] = 0.f;

    size_t aoff = ((size_t)quad * Mpad + row0 + m16) * 8;
    size_t boff = ((size_t)quad * Nn + m16) * 8;
    const size_t aStep = (size_t)Mpad * 32;
    const size_t bStep = (size_t)Nn * 32;

    for (int kt = 0; kt < K; kt += 32) {
        h8_t ah0 = *reinterpret_cast<const h8_t*>(Ah + aoff);
        h8_t ah1 = *reinterpret_cast<const h8_t*>(Ah + aoff + 128);
        h8_t al0 = *reinterpret_cast<const h8_t*>(Al + aoff);
        h8_t al1 = *reinterpret_cast<const h8_t*>(Al + aoff + 128);
#pragma unroll
        for (int c = 0; c < 4; c++) {
            h8_t bh = *reinterpret_cast<const h8_t*>(Bh + boff + c * 128);
            h8_t bl = *reinterpret_cast<const h8_t*>(Bl + boff + c * 128);
            acc[0][c] = __builtin_amdgcn_mfma_f32_16x16x32_f16(ah0, bh, acc[0][c], 0, 0, 0);
            acc[1][c] = __builtin_amdgcn_mfma_f32_16x16x32_f16(ah1, bh, acc[1][c], 0, 0, 0);
            acc[0][c] = __builtin_amdgcn_mfma_f32_16x16x32_f16(ah0, bl, acc[0][c], 0, 0, 0);
            acc[1][c] = __builtin_amdgcn_mfma_f32_16x16x32_f16(ah1, bl, acc[1][c], 0, 0, 0);
            acc[0][c] = __builtin_amdgcn_mfma_f32_16x16x32_f16(al0, bh, acc[0][c], 0, 0, 0);
            acc[1][c] = __builtin_amdgcn_mfma_f32_16x16x32_f16(al1, bh, acc[1][c], 0, 0, 0);
        }
        aoff += aStep; boff += bStep;
    }

#pragma unroll
    for (int t = 0; t < 2; t++) {
#pragma unroll
        for (int c = 0; c < 4; c++) {
            float bv = bias[c * 16 + m16];
#pragma unroll
            for (int i = 0; i < 4; i++) {
                float v = fmaxf(acc[t][c][i] + bv, 0.f);
                _Float16 hi = (_Float16)v;
                stH[wv][quad * 4 + i][c * 16 + m16] = hi;
                stL[wv][quad * 4 + i][c * 16 + m16] = (_Float16)(v - (float)hi);
            }
        }
        __syncthreads();
        int rowChunk = row0 + t * 16;
#pragma unroll
        for (int it = 0; it < 2; it++) {
            int lid = it * 64 + lane;
            int kg = lid >> 4, rloc = lid & 15;
            h8_t vh = *reinterpret_cast<const h8_t*>(&stH[wv][rloc][kg * 8]);
            h8_t vl = *reinterpret_cast<const h8_t*>(&stL[wv][rloc][kg * 8]);
            size_t o = ((size_t)kg * Mpad + rowChunk + rloc) * 8;
            *reinterpret_cast<h8_t*>(Ph + o) = vh;
            *reinterpret_cast<h8_t*>(Pl + o) = vl;
        }
        __syncthreads();
    }
}

// ---------------- GAT GEMM (Nn=256) -> h f16 row-major (LDS-staged) + fused alphas ----------------
__global__ __launch_bounds__(256) void gemm_gat_kernel(
        const _Float16* __restrict__ Ah, const _Float16* __restrict__ Al,
        const _Float16* __restrict__ Bh, const _Float16* __restrict__ Bl,
        const float* __restrict__ a_src, const float* __restrict__ a_dst,
        _Float16* __restrict__ hOut, float* __restrict__ aS, float* __restrict__ aD,
        int Mpad, int M, int K) {
    const int Nn = 256;
    __shared__ _Float16 st[4][16][136];
    int tid = threadIdx.x;
    int wv = tid >> 6, lane = tid & 63;
    int m16 = lane & 15, quad = lane >> 4;
    int row0 = blockIdx.x * 128 + wv * 32;
    int colBase = blockIdx.y * 128;

    floatx4 acc[2][8];
#pragma unroll
    for (int t = 0; t < 2; t++)
#pragma unroll
        for (int c = 0; c < 8; c++)
#pragma unroll
            for (int i = 0; i < 4; i++) acc[t][c][i] = 0.f;

    size_t aoff = ((size_t)quad * Mpad + row0 + m16) * 8;
    size_t boff = ((size_t)quad * Nn + colBase + m16) * 8;
    const size_t aStep = (size_t)Mpad * 32;
    const size_t bStep = (size_t)Nn * 32;

    for (int kt = 0; kt < K; kt += 32) {
        h8_t ah0 = *reinterpret_cast<const h8_t*>(Ah + aoff);
        h8_t ah1 = *reinterpret_cast<const h8_t*>(Ah + aoff + 128);
        h8_t al0 = *reinterpret_cast<const h8_t*>(Al + aoff);
        h8_t al1 = *reinterpret_cast<const h8_t*>(Al + aoff + 128);
#pragma unroll
        for (int c = 0; c < 8; c++) {
            h8_t bh = *reinterpret_cast<const h8_t*>(Bh + boff + c * 128);
            h8_t bl = *reinterpret_cast<const h8_t*>(Bl + boff + c * 128);
            acc[0][c] = __builtin_amdgcn_mfma_f32_16x16x32_f16(ah0, bh, acc[0][c], 0, 0, 0);
            acc[1][c] = __builtin_amdgcn_mfma_f32_16x16x32_f16(ah1, bh, acc[1][c], 0, 0, 0);
            acc[0][c] = __builtin_amdgcn_mfma_f32_16x16x32_f16(ah0, bl, acc[0][c], 0, 0, 0);
            acc[1][c] = __builtin_amdgcn_mfma_f32_16x16x32_f16(ah1, bl, acc[1][c], 0, 0, 0);
            acc[0][c] = __builtin_amdgcn_mfma_f32_16x16x32_f16(al0, bh, acc[0][c], 0, 0, 0);
            acc[1][c] = __builtin_amdgcn_mfma_f32_16x16x32_f16(al1, bh, acc[1][c], 0, 0, 0);
        }
        aoff += aStep; boff += bStep;
    }

    // fused alphas (2 heads per 128-col block)
    float asv[8], adv[8];
#pragma unroll
    for (int c = 0; c < 8; c++) {
        asv[c] = a_src[colBase + c * 16 + m16];
        adv[c] = a_dst[colBase + c * 16 + m16];
    }
    int hb = colBase >> 6;
#pragma unroll
    for (int t = 0; t < 2; t++) {
#pragma unroll
        for (int i = 0; i < 4; i++) {
            int r = row0 + t * 16 + quad * 4 + i;
            float s0 = 0.f, d0 = 0.f, s1 = 0.f, d1 = 0.f;
#pragma unroll
            for (int c = 0; c < 8; c++) {
                float v = acc[t][c][i];
                if (c < 4) { s0 += v * asv[c]; d0 += v * adv[c]; }
                else       { s1 += v * asv[c]; d1 += v * adv[c]; }
            }
#pragma unroll
            for (int off = 1; off < 16; off <<= 1) {
                s0 += __shfl_xor(s0, off);
                d0 += __shfl_xor(d0, off);
                s1 += __shfl_xor(s1, off);
                d1 += __shfl_xor(d1, off);
            }
            if (m16 == 0 && r < M) {
                aS[r * 4 + hb] = s0;     aD[r * 4 + hb] = d0;
                aS[r * 4 + hb + 1] = s1; aD[r * 4 + hb + 1] = d1;
            }
        }
    }

    // LDS-staged coalesced hOut stores (16-row chunks)
#pragma unroll
    for (int t = 0; t < 2; t++) {
#pragma unroll
        for (int c = 0; c < 8; c++)
#pragma unroll
            for (int i = 0; i < 4; i++)
                st[wv][quad * 4 + i][c * 16 + m16] = (_Float16)acc[t][c][i];
        __syncthreads();
        int rowChunk = row0 + t * 16;
#pragma unroll
        for (int it = 0; it < 4; it++) {
            int lid = it * 64 + lane;
            int rloc = lid >> 4, u = lid & 15;
            h8_t v = *reinterpret_cast<const h8_t*>(&st[wv][rloc][u * 8]);
            *reinterpret_cast<h8_t*>(hOut + (size_t)(rowChunk + rloc) * 256 + colBase + u * 8) = v;
        }
        __syncthreads();
    }
}

// ---------------- layer-2 GEMM (Nn=64) -> h f16 row-major (LDS-staged) + fused alphas ----------------
__global__ __launch_bounds__(256) void gemm_l2_kernel(
        const _Float16* __restrict__ Ah, const _Float16* __restrict__ Al,
        const _Float16* __restrict__ Bh, const _Float16* __restrict__ Bl,
        const float* __restrict__ a_src, const float* __restrict__ a_dst,
        _Float16* __restrict__ hOut, float* __restrict__ aS, float* __restrict__ aD,
        int Mpad, int M, int K) {
    const int Nn = 64;
    __shared__ _Float16 st[4][16][72];
    int tid = threadIdx.x;
    int wv = tid >> 6, lane = tid & 63;
    int m16 = lane & 15, quad = lane >> 4;
    int row0 = blockIdx.x * 128 + wv * 32;

    floatx4 acc[2][4];
#pragma unroll
    for (int t = 0; t < 2; t++)
#pragma unroll
        for (int c = 0; c < 4; c++)
#pragma unroll
            for (int i = 0; i < 4; i++) acc[t][c][i] = 0.f;

    size_t aoff = ((size_t)quad * Mpad + row0 + m16) * 8;
    size_t boff = ((size_t)quad * Nn + m16) * 8;
    const size_t aStep = (size_t)Mpad * 32;
    const size_t bStep = (size_t)Nn * 32;

    for (int kt = 0; kt < K; kt += 32) {
        h8_t ah0 = *reinterpret_cast<const h8_t*>(Ah + aoff);
        h8_t ah1 = *reinterpret_cast<const h8_t*>(Ah + aoff + 128);
        h8_t al0 = *reinterpret_cast<const h8_t*>(Al + aoff);
        h8_t al1 = *reinterpret_cast<const h8_t*>(Al + aoff + 128);
#pragma unroll
        for (int c = 0; c < 4; c++) {
            h8_t bh = *reinterpret_cast<const h8_t*>(Bh + boff + c * 128);
            h8_t bl = *reinterpret_cast<const h8_t*>(Bl + boff + c * 128);
            acc[0][c] = __builtin_amdgcn_mfma_f32_16x16x32_f16(ah0, bh, acc[0][c], 0, 0, 0);
            acc[1][c] = __builtin_amdgcn_mfma_f32_16x16x32_f16(ah1, bh, acc[1][c], 0, 0, 0);
            acc[0][c] = __builtin_amdgcn_mfma_f32_16x16x32_f16(ah0, bl, acc[0][c], 0, 0, 0);
            acc[1][c] = __builtin_amdgcn_mfma_f32_16x16x32_f16(ah1, bl, acc[1][c], 0, 0, 0);
            acc[0][c] = __builtin_amdgcn_mfma_f32_16x16x32_f16(al0, bh, acc[0][c], 0, 0, 0);
            acc[1][c] = __builtin_amdgcn_mfma_f32_16x16x32_f16(al1, bh, acc[1][c], 0, 0, 0);
        }
        aoff += aStep; boff += bStep;
    }

    float asv[4], adv[4];
#pragma unroll
    for (int c = 0; c < 4; c++) {
        asv[c] = a_src[c * 16 + m16];
        adv[c] = a_dst[c * 16 + m16];
    }
#pragma unroll
    for (int t = 0; t < 2; t++) {
#pragma unroll
        for (int i = 0; i < 4; i++) {
            int r = row0 + t * 16 + quad * 4 + i;
            float s0 = 0.f, d0 = 0.f;
#pragma unroll
            for (int c = 0; c < 4; c++) {
                float v = acc[t][c][i];
                s0 += v * asv[c]; d0 += v * adv[c];
            }
#pragma unroll
            for (int off = 1; off < 16; off <<= 1) {
                s0 += __shfl_xor(s0, off);
                d0 += __shfl_xor(d0, off);
            }
            if (m16 == 0 && r < M) { aS[r] = s0; aD[r] = d0; }
        }
    }

#pragma unroll
    for (int t = 0; t < 2; t++) {
#pragma unroll
        for (int c = 0; c < 4; c++)
#pragma unroll
            for (int i = 0; i < 4; i++)
                st[wv][quad * 4 + i][c * 16 + m16] = (_Float16)acc[t][c][i];
        __syncthreads();
        int rowChunk = row0 + t * 16;
#pragma unroll
        for (int it = 0; it < 2; it++) {
            int lid = it * 64 + lane;
            int rloc = lid >> 3, u = lid & 7;
            h8_t v = *reinterpret_cast<const h8_t*>(&st[wv][rloc][u * 8]);
            *reinterpret_cast<h8_t*>(hOut + (size_t)(rowChunk + rloc) * 64 + u * 8) = v;
        }
        __syncthreads();
    }
}

// ---------------- aggregation H=4: gathers f16 h, writes hi/lo planes for next GEMM ----------------
__global__ __launch_bounds__(256) void aggregate4_kernel(const _Float16* __restrict__ hsrc,
                                                         const float* __restrict__ alpha_s,
                                                         const float* __restrict__ alpha_d,
                                                         const int* __restrict__ row_ptr,
                                                         const int* __restrict__ csr_src,
                                                         const float* __restrict__ bias,
                                                         _Float16* __restrict__ outH,
                                                         _Float16* __restrict__ outL,
                                                         int N, int Mpad) {
    __shared__ float wlds[4][64][4];
    __shared__ int   slds[4][64];
    int wv = threadIdx.x >> 6, lane = threadIdx.x & 63;
    int node = blockIdx.x * 4 + wv;
    if (node >= N) return;
    int rs = row_ptr[node], re = row_ptr[node + 1];
    int head = lane >> 4, c4 = (lane & 15) * 4;
    float4 ad4 = *(const float4*)(alpha_d + (size_t)node * 4);

    float m0 = -1e30f, m1 = -1e30f, m2 = -1e30f, m3 = -1e30f;
    for (int base = rs; base < re; base += 64) {
        int i = base + lane;
        if (i < re) {
            int s = csr_src[i];
            float4 as = *(const float4*)(alpha_s + (size_t)s * 4);
            m0 = fmaxf(m0, leaky(as.x + ad4.x));
            m1 = fmaxf(m1, leaky(as.y + ad4.y));
            m2 = fmaxf(m2, leaky(as.z + ad4.z));
            m3 = fmaxf(m3, leaky(as.w + ad4.w));
        }
    }
#pragma unroll
    for (int off = 32; off >= 1; off >>= 1) {
        m0 = fmaxf(m0, __shfl_xor(m0, off));
        m1 = fmaxf(m1, __shfl_xor(m1, off));
        m2 = fmaxf(m2, __shfl_xor(m2, off));
        m3 = fmaxf(m3, __shfl_xor(m3, off));
    }

    float den0 = 0.f, den1 = 0.f, den2 = 0.f, den3 = 0.f;
    float a0 = 0.f, a1 = 0.f, a2 = 0.f, a3 = 0.f;
    float* wp = &wlds[wv][0][0];
    int*   sp = &slds[wv][0];
    for (int base = rs; base < re; base += 64) {
        int i = base + lane;
        float w0 = 0.f, w1 = 0.f, w2 = 0.f, w3 = 0.f;
        int s = 0;
        if (i < re) {
            s = csr_src[i];
            float4 as = *(const float4*)(alpha_s + (size_t)s * 4);
            w0 = __expf(leaky(as.x + ad4.x) - m0);
            w1 = __expf(leaky(as.y + ad4.y) - m1);
            w2 = __expf(leaky(as.z + ad4.z) - m2);
            w3 = __expf(leaky(as.w + ad4.w) - m3);
        }
        den0 += w0; den1 += w1; den2 += w2; den3 += w3;
        sp[lane] = s;
        *(float4*)(wp + lane * 4) = make_float4(w0, w1, w2, w3);
        int cnt = min(64, re - base);
#pragma unroll 4
        for (int j = 0; j < cnt; j++) {
            int s2 = sp[j];
            float w = wp[j * 4 + head];
            h4_t hv = *reinterpret_cast<const h4_t*>(hsrc + (size_t)s2 * 256 + (head << 6) + c4);
            a0 += w * (float)hv[0]; a1 += w * (float)hv[1];
            a2 += w * (float)hv[2]; a3 += w * (float)hv[3];
        }
    }
#pragma unroll
    for (int off = 32; off >= 1; off >>= 1) {
        den0 += __shfl_xor(den0, off);
        den1 += __shfl_xor(den1, off);
        den2 += __shfl_xor(den2, off);
        den3 += __shfl_xor(den3, off);
    }
    float den = (head & 2) ? ((head & 1) ? den3 : den2) : ((head & 1) ? den1 : den0);
    float inv = 1.f / (den + 1e-16f);
    int cbase = (head << 6) + c4;
    float v0 = fmaxf(a0 * inv + bias[cbase + 0], 0.f);
    float v1 = fmaxf(a1 * inv + bias[cbase + 1], 0.f);
    float v2 = fmaxf(a2 * inv + bias[cbase + 2], 0.f);
    float v3 = fmaxf(a3 * inv + bias[cbase + 3], 0.f);
    h4_t hv, lv;
    _Float16 h;
    h = (_Float16)v0; hv[0] = h; lv[0] = (_Float16)(v0 - (float)h);
    h = (_Float16)v1; hv[1] = h; lv[1] = (_Float16)(v1 - (float)h);
    h = (_Float16)v2; hv[2] = h; lv[2] = (_Float16)(v2 - (float)h);
    h = (_Float16)v3; hv[3] = h; lv[3] = (_Float16)(v3 - (float)h);
    size_t o = ((size_t)(cbase >> 3) * Mpad + node) * 8 + (cbase & 7);
    *reinterpret_cast<h4_t*>(outH + o) = hv;
    *reinterpret_cast<h4_t*>(outL + o) = lv;
}

// ---------------- aggregation H=1: gathers f16, writes fp32 [N,64] ----------------
__global__ __launch_bounds__(256) void aggregate1_kernel(const _Float16* __restrict__ hsrc,
                                                         const float* __restrict__ alpha_s,
                                                         const float* __restrict__ alpha_d,
                                                         const int* __restrict__ row_ptr,
                                                         const int* __restrict__ csr_src,
                                                         const float* __restrict__ bias,
                                                         float* __restrict__ out, int N) {
    __shared__ float wlds[4][64];
    __shared__ int   slds[4][64];
    int wv = threadIdx.x >> 6, lane = threadIdx.x & 63;
    int node = blockIdx.x * 4 + wv;
    if (node >= N) return;
    int rs = row_ptr[node], re = row_ptr[node + 1];
    float ad = alpha_d[node];

    float m = -1e30f;
    for (int base = rs; base < re; base += 64) {
        int i = base + lane;
        if (i < re) {
            int s = csr_src[i];
            m = fmaxf(m, leaky(alpha_s[s] + ad));
        }
    }
#pragma unroll
    for (int off = 32; off >= 1; off >>= 1) m = fmaxf(m, __shfl_xor(m, off));

    float den = 0.f, acc = 0.f;
    float* wp = &wlds[wv][0];
    int*   sp = &slds[wv][0];
    for (int base = rs; base < re; base += 64) {
        int i = base + lane;
        float w = 0.f;
        int s = 0;
        if (i < re) {
            s = csr_src[i];
            w = __expf(leaky(alpha_s[s] + ad) - m);
        }
        den += w;
        sp[lane] = s;
        wp[lane] = w;
        int cnt = min(64, re - base);
#pragma unroll 4
        for (int j = 0; j < cnt; j++) {
            int s2 = sp[j];
            acc += wp[j] * (float)hsrc[(size_t)s2 * 64 + lane];
        }
    }
#pragma unroll
    for (int off = 32; off >= 1; off >>= 1) den += __shfl_xor(den, off);
    float v = acc / (den + 1e-16f) + bias[lane];
    out[(size_t)node * 64 + lane] = v;
}

// ---------------- head MLP ----------------
__global__ __launch_bounds__(256) void mlp_head_kernel(const float* __restrict__ hin,
                                                       const float* __restrict__ Wo1,
                                                       const float* __restrict__ bo1,
                                                       const float* __restrict__ Wo2,
                                                       const float* __restrict__ bo2,
                                                       float* __restrict__ out, int N) {
    __shared__ float w1[64 * 32];
    __shared__ float w2[32];
    __shared__ float b1s[32];
    int tid = threadIdx.x;
#pragma unroll
    for (int i = 0; i < 8; i++) w1[tid + i * 256] = Wo1[tid + i * 256];
    if (tid < 32) { w2[tid] = Wo2[tid]; b1s[tid] = bo1[tid]; }
    __syncthreads();
    int n = blockIdx.x * blockDim.x + tid;
    if (n >= N) return;
    float hrow[64];
    const float* pr = hin + (size_t)n * 64;
#pragma unroll
    for (int i = 0; i < 64; i++) hrow[i] = pr[i];
    float sum = 0.f;
    for (int j = 0; j < 32; j++) {
        float a = b1s[j];
#pragma unroll
        for (int k = 0; k < 64; k++) a += hrow[k] * w1[k * 32 + j];
        a = fmaxf(a, 0.f);
        sum += a * w2[j];
    }
    out[n] = sum + bo2[0];
}

// ---------------- launch ----------------
extern "C" void kernel_launch(void* const* d_in, const int* in_sizes, int n_in,
                              void* d_out, int out_size, void* d_ws, size_t ws_size,
                              hipStream_t stream) {
    const float* x     = (const float*)d_in[0];
    const float* W_emb = (const float*)d_in[1];
    const float* b_emb = (const float*)d_in[2];
    const float* W0    = (const float*)d_in[3];
    const float* as0   = (const float*)d_in[4];
    const float* ad0   = (const float*)d_in[5];
    const float* b0    = (const float*)d_in[6];
    const float* W1    = (const float*)d_in[7];
    const float* as1   = (const float*)d_in[8];
    const float* ad1   = (const float*)d_in[9];
    const float* b1    = (const float*)d_in[10];
    const float* W2    = (const float*)d_in[11];
    const float* as2   = (const float*)d_in[12];
    const float* ad2   = (const float*)d_in[13];
    const float* b2    = (const float*)d_in[14];
    const float* Wo1   = (const float*)d_in[15];
    const float* bo1   = (const float*)d_in[16];
    const float* Wo2   = (const float*)d_in[17];
    const float* bo2   = (const float*)d_in[18];
    const int* eidx    = (const int*)d_in[19];

    const int N = in_sizes[0] / 128;
    const int E = in_sizes[19] / 2;
    const int* esrc = eidx;
    const int* edst = eidx + E;
    const int gmB  = (N + 127) / 128;
    const int Mpad = gmB * 128;
    const int nb   = (N + 255) / 256;

    char* w = (char*)d_ws;
    auto alloc = [&](size_t bytes) {
        char* p = w;
        w += (bytes + 255) & ~(size_t)255;
        return (void*)p;
    };
    _Float16* hOut = (_Float16*)alloc((size_t)Mpad * 256 * 2);
    _Float16* PHh  = (_Float16*)alloc((size_t)Mpad * 256 * 2);
    _Float16* PHl  = (_Float16*)alloc((size_t)Mpad * 256 * 2);
    _Float16* XPh  = (_Float16*)alloc((size_t)Mpad * 128 * 2);
    _Float16* XPl  = (_Float16*)alloc((size_t)Mpad * 128 * 2);
    float* bufA    = (float*)alloc((size_t)Mpad * 64 * 4);
    float* aS      = (float*)alloc((size_t)N * 4 * 4);
    float* aD      = (float*)alloc((size_t)N * 4 * 4);
    int*   row_ptr = (int*)alloc((size_t)(N + 1) * 4);
    int*   cursor  = (int*)alloc((size_t)N * 4);
    int*   cnt     = (int*)alloc((size_t)N * 4);
    int*   bsum    = (int*)alloc((size_t)nb * 4);
    int*   csr     = (int*)alloc((size_t)(E + N) * 4);
    _Float16* WeH  = (_Float16*)alloc(128 * 64 * 2);
    _Float16* WeL  = (_Float16*)alloc(128 * 64 * 2);
    _Float16* W0H  = (_Float16*)alloc(64 * 256 * 2);
    _Float16* W0L  = (_Float16*)alloc(64 * 256 * 2);
    _Float16* W1H  = (_Float16*)alloc(256 * 256 * 2);
    _Float16* W1L  = (_Float16*)alloc(256 * 256 * 2);
    _Float16* W2H  = (_Float16*)alloc(256 * 64 * 2);
    _Float16* W2L  = (_Float16*)alloc(256 * 64 * 2);

    // CSR build (multi-block scan)
    hipMemsetAsync(cnt, 0, (size_t)N * 4, stream);
    hist_kernel<<<(E + 255) / 256, 256, 0, stream>>>(edst, E, cnt);
    blocksum_kernel<<<nb, 256, 0, stream>>>(cnt, N, bsum);
    scanbsum_kernel<<<1, 256, 0, stream>>>(bsum, nb, row_ptr + N);
    rowptr_kernel<<<nb, 256, 0, stream>>>(cnt, bsum, N, row_ptr, cursor);
    scatter_kernel<<<(E + N + 255) / 256, 256, 0, stream>>>(esrc, edst, E, N, cursor, csr);

    // weight planes
    prep_weight_kernel<<<(128 * 64 + 255) / 256, 256, 0, stream>>>(W_emb, WeH, WeL, 128, 64);
    prep_weight_kernel<<<(64 * 256 + 255) / 256, 256, 0, stream>>>(W0, W0H, W0L, 64, 256);
    prep_weight_kernel<<<(256 * 256 + 255) / 256, 256, 0, stream>>>(W1, W1H, W1L, 256, 256);
    prep_weight_kernel<<<(256 * 64 + 255) / 256, 256, 0, stream>>>(W2, W2H, W2L, 256, 64);

    int gn4 = (N + 3) / 4;

    // embedding: planes(x) -> relu(x@W_emb + b_emb) as hi/lo planes
    prep_act_kernel<<<((size_t)Mpad * 16 + 255) / 256, 256, 0, stream>>>(x, XPh, XPl, N, Mpad, 16, 128);
    gemm_emb_kernel<<<dim3(gmB, 1), 256, 0, stream>>>(XPh, XPl, WeH, WeL, b_emb, PHh, PHl, Mpad, N, 128);

    // GAT layer 0
    gemm_gat_kernel<<<dim3(gmB, 2), 256, 0, stream>>>(PHh, PHl, W0H, W0L, as0, ad0, hOut, aS, aD, Mpad, N, 64);
    aggregate4_kernel<<<gn4, 256, 0, stream>>>(hOut, aS, aD, row_ptr, csr, b0, PHh, PHl, N, Mpad);

    // GAT layer 1
    gemm_gat_kernel<<<dim3(gmB, 2), 256, 0, stream>>>(PHh, PHl, W1H, W1L, as1, ad1, hOut, aS, aD, Mpad, N, 256);
    aggregate4_kernel<<<gn4, 256, 0, stream>>>(hOut, aS, aD, row_ptr, csr, b1, PHh, PHl, N, Mpad);

    // GAT layer 2 (1 head, no relu)
    gemm_l2_kernel<<<dim3(gmB, 1), 256, 0, stream>>>(PHh, PHl, W2H, W2L, as2, ad2, hOut, aS, aD, Mpad, N, 256);
    aggregate1_kernel<<<gn4, 256, 0, stream>>>(hOut, aS, aD, row_ptr, csr, b2, bufA, N);

    // head MLP -> out [N,1] fp32
    mlp_head_kernel<<<(N + 255) / 256, 256, 0, stream>>>(bufA, Wo1, bo1, Wo2, bo2, (float*)d_out, N);
}

// Round 10
// 515.092 us; speedup vs baseline: 1.5504x; 1.0268x over previous
//
#include <hip/hip_runtime.h>

typedef _Float16 h8_t __attribute__((ext_vector_type(8)));
typedef _Float16 h4_t __attribute__((ext_vector_type(4)));
typedef float floatx4 __attribute__((ext_vector_type(4)));

__device__ __forceinline__ float leaky(float v) { return v >= 0.f ? v : 0.2f * v; }

// ---------------- CSR build ----------------
__global__ void hist_kernel(const int* __restrict__ dst, int E, int* __restrict__ cnt) {
    int e = blockIdx.x * blockDim.x + threadIdx.x;
    if (e < E) atomicAdd(&cnt[dst[e]], 1);
}

__global__ __launch_bounds__(256) void blocksum_kernel(const int* __restrict__ cnt, int N,
                                                       int* __restrict__ bsum) {
    __shared__ int red[256];
    int tid = threadIdx.x;
    int idx = blockIdx.x * 256 + tid;
    red[tid] = idx < N ? cnt[idx] + 1 : 0;
    __syncthreads();
#pragma unroll
    for (int off = 128; off >= 1; off >>= 1) {
        if (tid < off) red[tid] += red[tid + off];
        __syncthreads();
    }
    if (tid == 0) bsum[blockIdx.x] = red[0];
}

__global__ __launch_bounds__(256) void scanbsum_kernel(int* __restrict__ bsum, int nb,
                                                       int* __restrict__ total) {
    __shared__ int part[256];
    int tid = threadIdx.x;
    int per = (nb + 255) / 256;
    int s0 = tid * per, s1 = min(s0 + per, nb);
    int s = 0;
    for (int i = s0; i < s1; i++) s += bsum[i];
    part[tid] = s;
    __syncthreads();
    for (int off = 1; off < 256; off <<= 1) {
        int v = (tid >= off) ? part[tid - off] : 0;
        __syncthreads();
        part[tid] += v;
        __syncthreads();
    }
    int base = (tid == 0) ? 0 : part[tid - 1];
    for (int i = s0; i < s1; i++) {
        int v = bsum[i];
        bsum[i] = base;
        base += v;
    }
    if (tid == 255) *total = part[255];
}

__global__ __launch_bounds__(256) void rowptr_kernel(const int* __restrict__ cnt,
                                                     const int* __restrict__ bsum, int N,
                                                     int* __restrict__ row_ptr,
                                                     int* __restrict__ cursor) {
    __shared__ int lds[256];
    int tid = threadIdx.x;
    int idx = blockIdx.x * 256 + tid;
    int v = idx < N ? cnt[idx] + 1 : 0;
    lds[tid] = v;
    __syncthreads();
    for (int off = 1; off < 256; off <<= 1) {
        int t = (tid >= off) ? lds[tid - off] : 0;
        __syncthreads();
        lds[tid] += t;
        __syncthreads();
    }
    if (idx < N) {
        int p = bsum[blockIdx.x] + lds[tid] - v;
        row_ptr[idx] = p;
        cursor[idx] = p;
    }
}

__global__ void scatter_kernel(const int* __restrict__ src, const int* __restrict__ dst,
                               int E, int N, int* __restrict__ cursor, int* __restrict__ csr_src) {
    int e = blockIdx.x * blockDim.x + threadIdx.x;
    if (e >= E + N) return;
    int s, d;
    if (e < E) { s = src[e]; d = dst[e]; }
    else       { s = e - E;  d = s; }
    int pos = atomicAdd(&cursor[d], 1);
    csr_src[pos] = s;
}

// ---------------- fused weight prep: all 4 weights -> f16 hi/lo planes [K/8][N][8] ----------------
__global__ void prep_weights_all(const float* __restrict__ W_emb, const float* __restrict__ W0,
                                 const float* __restrict__ W1, const float* __restrict__ W2,
                                 _Float16* __restrict__ WeH, _Float16* __restrict__ WeL,
                                 _Float16* __restrict__ W0H, _Float16* __restrict__ W0L,
                                 _Float16* __restrict__ W1H, _Float16* __restrict__ W1L,
                                 _Float16* __restrict__ W2H, _Float16* __restrict__ W2L) {
    int which = blockIdx.y;
    const float* W;
    _Float16 *Wh, *Wl;
    int K, N;
    if (which == 0)      { W = W_emb; Wh = WeH; Wl = WeL; K = 128; N = 64; }
    else if (which == 1) { W = W0;    Wh = W0H; Wl = W0L; K = 64;  N = 256; }
    else if (which == 2) { W = W1;    Wh = W1H; Wl = W1L; K = 256; N = 256; }
    else                 { W = W2;    Wh = W2H; Wl = W2L; K = 256; N = 64; }
    int idx = blockIdx.x * blockDim.x + threadIdx.x;
    if (idx >= K * N) return;
    int k = idx / N, n = idx % N;
    float v = W[idx];
    _Float16 hi = (_Float16)v;
    _Float16 lo = (_Float16)(v - (float)hi);
    size_t o = ((size_t)(k >> 3) * N + n) * 8 + (k & 7);
    Wh[o] = hi; Wl[o] = lo;
}

// ---------------- activation prep: fp32 [M,K] -> hi/lo planes [K/8][Mpad][8] ----------------
__global__ void prep_act_kernel(const float* __restrict__ X,
                                _Float16* __restrict__ Ph, _Float16* __restrict__ Pl,
                                int M, int Mpad, int Kg, int K) {
    int idx = blockIdx.x * blockDim.x + threadIdx.x;
    if (idx >= Mpad * Kg) return;
    int row = idx / Kg, kg = idx - row * Kg;
    float vs[8] = {0.f, 0.f, 0.f, 0.f, 0.f, 0.f, 0.f, 0.f};
    if (row < M) {
        const float4* p = (const float4*)(X + (size_t)row * K + kg * 8);
        float4 a = p[0], b = p[1];
        vs[0] = a.x; vs[1] = a.y; vs[2] = a.z; vs[3] = a.w;
        vs[4] = b.x; vs[5] = b.y; vs[6] = b.z; vs[7] = b.w;
    }
    h8_t hh, hl;
#pragma unroll
    for (int j = 0; j < 8; j++) {
        _Float16 hi = (_Float16)vs[j];
        hh[j] = hi;
        hl[j] = (_Float16)(vs[j] - (float)hi);
    }
    size_t o = ((size_t)kg * Mpad + row) * 8;
    *reinterpret_cast<h8_t*>(Ph + o) = hh;
    *reinterpret_cast<h8_t*>(Pl + o) = hl;
}

// ---------------- embedding GEMM -> hi/lo planes, LDS-staged coalesced stores ----------------
__global__ __launch_bounds__(256) void gemm_emb_kernel(
        const _Float16* __restrict__ Ah, const _Float16* __restrict__ Al,
        const _Float16* __restrict__ Bh, const _Float16* __restrict__ Bl,
        const float* __restrict__ bias,
        _Float16* __restrict__ Ph, _Float16* __restrict__ Pl,
        int Mpad, int M, int K) {
    const int Nn = 64;
    __shared__ _Float16 stH[4][16][72];
    __shared__ _Float16 stL[4][16][72];
    int tid = threadIdx.x;
    int wv = tid >> 6, lane = tid & 63;
    int m16 = lane & 15, quad = lane >> 4;
    int row0 = blockIdx.x * 128 + wv * 32;

    floatx4 acc[2][4];
#pragma unroll
    for (int t = 0; t < 2; t++)
#pragma unroll
        for (int c = 0; c < 4; c++)
#pragma unroll
            for (int i = 0; i < 4; i++) acc[t][c][i] = 0.f;

    size_t aoff = ((size_t)quad * Mpad + row0 + m16) * 8;
    size_t boff = ((size_t)quad * Nn + m16) * 8;
    const size_t aStep = (size_t)Mpad * 32;
    const size_t bStep = (size_t)Nn * 32;

    for (int kt = 0; kt < K; kt += 32) {
        h8_t ah0 = *reinterpret_cast<const h8_t*>(Ah + aoff);
        h8_t ah1 = *reinterpret_cast<const h8_t*>(Ah + aoff + 128);
        h8_t al0 = *reinterpret_cast<const h8_t*>(Al + aoff);
        h8_t al1 = *reinterpret_cast<const h8_t*>(Al + aoff + 128);
#pragma unroll
        for (int c = 0; c < 4; c++) {
            h8_t bh = *reinterpret_cast<const h8_t*>(Bh + boff + c * 128);
            h8_t bl = *reinterpret_cast<const h8_t*>(Bl + boff + c * 128);
            acc[0][c] = __builtin_amdgcn_mfma_f32_16x16x32_f16(ah0, bh, acc[0][c], 0, 0, 0);
            acc[1][c] = __builtin_amdgcn_mfma_f32_16x16x32_f16(ah1, bh, acc[1][c], 0, 0, 0);
            acc[0][c] = __builtin_amdgcn_mfma_f32_16x16x32_f16(ah0, bl, acc[0][c], 0, 0, 0);
            acc[1][c] = __builtin_amdgcn_mfma_f32_16x16x32_f16(ah1, bl, acc[1][c], 0, 0, 0);
            acc[0][c] = __builtin_amdgcn_mfma_f32_16x16x32_f16(al0, bh, acc[0][c], 0, 0, 0);
            acc[1][c] = __builtin_amdgcn_mfma_f32_16x16x32_f16(al1, bh, acc[1][c], 0, 0, 0);
        }
        aoff += aStep; boff += bStep;
    }

#pragma unroll
    for (int t = 0; t < 2; t++) {
#pragma unroll
        for (int c = 0; c < 4; c++) {
            float bv = bias[c * 16 + m16];
#pragma unroll
            for (int i = 0; i < 4; i++) {
                float v = fmaxf(acc[t][c][i] + bv, 0.f);
                _Float16 hi = (_Float16)v;
                stH[wv][quad * 4 + i][c * 16 + m16] = hi;
                stL[wv][quad * 4 + i][c * 16 + m16] = (_Float16)(v - (float)hi);
            }
        }
        __syncthreads();
        int rowChunk = row0 + t * 16;
#pragma unroll
        for (int it = 0; it < 2; it++) {
            int lid = it * 64 + lane;
            int kg = lid >> 4, rloc = lid & 15;
            h8_t vh = *reinterpret_cast<const h8_t*>(&stH[wv][rloc][kg * 8]);
            h8_t vl = *reinterpret_cast<const h8_t*>(&stL[wv][rloc][kg * 8]);
            size_t o = ((size_t)kg * Mpad + rowChunk + rloc) * 8;
            *reinterpret_cast<h8_t*>(Ph + o) = vh;
            *reinterpret_cast<h8_t*>(Pl + o) = vl;
        }
        __syncthreads();
    }
}

// ---------------- GAT GEMM (Nn=256) -> h f16 row-major (LDS-staged) + fused alphas ----------------
template <int TAG>
__global__ __launch_bounds__(256) void gemm_gat_kernel(
        const _Float16* __restrict__ Ah, const _Float16* __restrict__ Al,
        const _Float16* __restrict__ Bh, const _Float16* __restrict__ Bl,
        const float* __restrict__ a_src, const float* __restrict__ a_dst,
        _Float16* __restrict__ hOut, float* __restrict__ aS, float* __restrict__ aD,
        int Mpad, int M, int K) {
    const int Nn = 256;
    __shared__ _Float16 st[4][16][136];
    int tid = threadIdx.x;
    int wv = tid >> 6, lane = tid & 63;
    int m16 = lane & 15, quad = lane >> 4;
    int row0 = blockIdx.x * 128 + wv * 32;
    int colBase = blockIdx.y * 128;

    floatx4 acc[2][8];
#pragma unroll
    for (int t = 0; t < 2; t++)
#pragma unroll
        for (int c = 0; c < 8; c++)
#pragma unroll
            for (int i = 0; i < 4; i++) acc[t][c][i] = 0.f;

    size_t aoff = ((size_t)quad * Mpad + row0 + m16) * 8;
    size_t boff = ((size_t)quad * Nn + colBase + m16) * 8;
    const size_t aStep = (size_t)Mpad * 32;
    const size_t bStep = (size_t)Nn * 32;

    for (int kt = 0; kt < K; kt += 32) {
        h8_t ah0 = *reinterpret_cast<const h8_t*>(Ah + aoff);
        h8_t ah1 = *reinterpret_cast<const h8_t*>(Ah + aoff + 128);
        h8_t al0 = *reinterpret_cast<const h8_t*>(Al + aoff);
        h8_t al1 = *reinterpret_cast<const h8_t*>(Al + aoff + 128);
#pragma unroll
        for (int c = 0; c < 8; c++) {
            h8_t bh = *reinterpret_cast<const h8_t*>(Bh + boff + c * 128);
            h8_t bl = *reinterpret_cast<const h8_t*>(Bl + boff + c * 128);
            acc[0][c] = __builtin_amdgcn_mfma_f32_16x16x32_f16(ah0, bh, acc[0][c], 0, 0, 0);
            acc[1][c] = __builtin_amdgcn_mfma_f32_16x16x32_f16(ah1, bh, acc[1][c], 0, 0, 0);
            acc[0][c] = __builtin_amdgcn_mfma_f32_16x16x32_f16(ah0, bl, acc[0][c], 0, 0, 0);
            acc[1][c] = __builtin_amdgcn_mfma_f32_16x16x32_f16(ah1, bl, acc[1][c], 0, 0, 0);
            acc[0][c] = __builtin_amdgcn_mfma_f32_16x16x32_f16(al0, bh, acc[0][c], 0, 0, 0);
            acc[1][c] = __builtin_amdgcn_mfma_f32_16x16x32_f16(al1, bh, acc[1][c], 0, 0, 0);
        }
        aoff += aStep; boff += bStep;
    }

    float asv[8], adv[8];
#pragma unroll
    for (int c = 0; c < 8; c++) {
        asv[c] = a_src[colBase + c * 16 + m16];
        adv[c] = a_dst[colBase + c * 16 + m16];
    }
    int hb = colBase >> 6;
#pragma unroll
    for (int t = 0; t < 2; t++) {
#pragma unroll
        for (int i = 0; i < 4; i++) {
            int r = row0 + t * 16 + quad * 4 + i;
            float s0 = 0.f, d0 = 0.f, s1 = 0.f, d1 = 0.f;
#pragma unroll
            for (int c = 0; c < 8; c++) {
                float v = acc[t][c][i];
                if (c < 4) { s0 += v * asv[c]; d0 += v * adv[c]; }
                else       { s1 += v * asv[c]; d1 += v * adv[c]; }
            }
#pragma unroll
            for (int off = 1; off < 16; off <<= 1) {
                s0 += __shfl_xor(s0, off);
                d0 += __shfl_xor(d0, off);
                s1 += __shfl_xor(s1, off);
                d1 += __shfl_xor(d1, off);
            }
            if (m16 == 0 && r < M) {
                aS[r * 4 + hb] = s0;     aD[r * 4 + hb] = d0;
                aS[r * 4 + hb + 1] = s1; aD[r * 4 + hb + 1] = d1;
            }
        }
    }

#pragma unroll
    for (int t = 0; t < 2; t++) {
#pragma unroll
        for (int c = 0; c < 8; c++)
#pragma unroll
            for (int i = 0; i < 4; i++)
                st[wv][quad * 4 + i][c * 16 + m16] = (_Float16)acc[t][c][i];
        __syncthreads();
        int rowChunk = row0 + t * 16;
#pragma unroll
        for (int it = 0; it < 4; it++) {
            int lid = it * 64 + lane;
            int rloc = lid >> 4, u = lid & 15;
            h8_t v = *reinterpret_cast<const h8_t*>(&st[wv][rloc][u * 8]);
            *reinterpret_cast<h8_t*>(hOut + (size_t)(rowChunk + rloc) * 256 + colBase + u * 8) = v;
        }
        __syncthreads();
    }
}

// ---------------- layer-2 GEMM (Nn=64) -> h f16 row-major (LDS-staged) + fused alphas ----------------
__global__ __launch_bounds__(256) void gemm_l2_kernel(
        const _Float16* __restrict__ Ah, const _Float16* __restrict__ Al,
        const _Float16* __restrict__ Bh, const _Float16* __restrict__ Bl,
        const float* __restrict__ a_src, const float* __restrict__ a_dst,
        _Float16* __restrict__ hOut, float* __restrict__ aS, float* __restrict__ aD,
        int Mpad, int M, int K) {
    const int Nn = 64;
    __shared__ _Float16 st[4][16][72];
    int tid = threadIdx.x;
    int wv = tid >> 6, lane = tid & 63;
    int m16 = lane & 15, quad = lane >> 4;
    int row0 = blockIdx.x * 128 + wv * 32;

    floatx4 acc[2][4];
#pragma unroll
    for (int t = 0; t < 2; t++)
#pragma unroll
        for (int c = 0; c < 4; c++)
#pragma unroll
            for (int i = 0; i < 4; i++) acc[t][c][i] = 0.f;

    size_t aoff = ((size_t)quad * Mpad + row0 + m16) * 8;
    size_t boff = ((size_t)quad * Nn + m16) * 8;
    const size_t aStep = (size_t)Mpad * 32;
    const size_t bStep = (size_t)Nn * 32;

    for (int kt = 0; kt < K; kt += 32) {
        h8_t ah0 = *reinterpret_cast<const h8_t*>(Ah + aoff);
        h8_t ah1 = *reinterpret_cast<const h8_t*>(Ah + aoff + 128);
        h8_t al0 = *reinterpret_cast<const h8_t*>(Al + aoff);
        h8_t al1 = *reinterpret_cast<const h8_t*>(Al + aoff + 128);
#pragma unroll
        for (int c = 0; c < 4; c++) {
            h8_t bh = *reinterpret_cast<const h8_t*>(Bh + boff + c * 128);
            h8_t bl = *reinterpret_cast<const h8_t*>(Bl + boff + c * 128);
            acc[0][c] = __builtin_amdgcn_mfma_f32_16x16x32_f16(ah0, bh, acc[0][c], 0, 0, 0);
            acc[1][c] = __builtin_amdgcn_mfma_f32_16x16x32_f16(ah1, bh, acc[1][c], 0, 0, 0);
            acc[0][c] = __builtin_amdgcn_mfma_f32_16x16x32_f16(ah0, bl, acc[0][c], 0, 0, 0);
            acc[1][c] = __builtin_amdgcn_mfma_f32_16x16x32_f16(ah1, bl, acc[1][c], 0, 0, 0);
            acc[0][c] = __builtin_amdgcn_mfma_f32_16x16x32_f16(al0, bh, acc[0][c], 0, 0, 0);
            acc[1][c] = __builtin_amdgcn_mfma_f32_16x16x32_f16(al1, bh, acc[1][c], 0, 0, 0);
        }
        aoff += aStep; boff += bStep;
    }

    float asv[4], adv[4];
#pragma unroll
    for (int c = 0; c < 4; c++) {
        asv[c] = a_src[c * 16 + m16];
        adv[c] = a_dst[c * 16 + m16];
    }
#pragma unroll
    for (int t = 0; t < 2; t++) {
#pragma unroll
        for (int i = 0; i < 4; i++) {
            int r = row0 + t * 16 + quad * 4 + i;
            float s0 = 0.f, d0 = 0.f;
#pragma unroll
            for (int c = 0; c < 4; c++) {
                float v = acc[t][c][i];
                s0 += v * asv[c]; d0 += v * adv[c];
            }
#pragma unroll
            for (int off = 1; off < 16; off <<= 1) {
                s0 += __shfl_xor(s0, off);
                d0 += __shfl_xor(d0, off);
            }
            if (m16 == 0 && r < M) { aS[r] = s0; aD[r] = d0; }
        }
    }

#pragma unroll
    for (int t = 0; t < 2; t++) {
#pragma unroll
        for (int c = 0; c < 4; c++)
#pragma unroll
            for (int i = 0; i < 4; i++)
                st[wv][quad * 4 + i][c * 16 + m16] = (_Float16)acc[t][c][i];
        __syncthreads();
        int rowChunk = row0 + t * 16;
#pragma unroll
        for (int it = 0; it < 2; it++) {
            int lid = it * 64 + lane;
            int rloc = lid >> 3, u = lid & 7;
            h8_t v = *reinterpret_cast<const h8_t*>(&st[wv][rloc][u * 8]);
            *reinterpret_cast<h8_t*>(hOut + (size_t)(rowChunk + rloc) * 64 + u * 8) = v;
        }
        __syncthreads();
    }
}

// ---------------- aggregation H=4: f16 gather, LDS-packed (offset,w), leaky cache ----------------
template <int TAG>
__global__ __launch_bounds__(256) void aggregate4_kernel(const _Float16* __restrict__ hsrc,
                                                         const float* __restrict__ alpha_s,
                                                         const float* __restrict__ alpha_d,
                                                         const int* __restrict__ row_ptr,
                                                         const int* __restrict__ csr_src,
                                                         const float* __restrict__ bias,
                                                         _Float16* __restrict__ outH,
                                                         _Float16* __restrict__ outL,
                                                         int N, int Mpad) {
    __shared__ float4 lkc[4][64];   // pass-A leaky scores cache (first chunk)
    __shared__ int    scc[4][64];   // pass-A src cache (first chunk)
    __shared__ int2   pk[4][256];   // (byte offset incl. head, w bits) per (edge, head)
    int wv = threadIdx.x >> 6, lane = threadIdx.x & 63;
    int node = blockIdx.x * 4 + wv;
    if (node >= N) return;
    int rs = row_ptr[node], re = row_ptr[node + 1];
    int head = lane >> 4, c4 = (lane & 15) * 4;
    float4 ad4 = *(const float4*)(alpha_d + (size_t)node * 4);

    // pass A: lane-parallel max per head; cache leaky scores + src for first chunk
    float m0 = -1e30f, m1 = -1e30f, m2 = -1e30f, m3 = -1e30f;
    for (int base = rs; base < re; base += 64) {
        int i = base + lane;
        if (i < re) {
            int s = csr_src[i];
            float4 as = *(const float4*)(alpha_s + (size_t)s * 4);
            float4 lk = make_float4(leaky(as.x + ad4.x), leaky(as.y + ad4.y),
                                    leaky(as.z + ad4.z), leaky(as.w + ad4.w));
            if (base == rs) { lkc[wv][lane] = lk; scc[wv][lane] = s; }
            m0 = fmaxf(m0, lk.x); m1 = fmaxf(m1, lk.y);
            m2 = fmaxf(m2, lk.z); m3 = fmaxf(m3, lk.w);
        }
    }
#pragma unroll
    for (int off = 32; off >= 1; off >>= 1) {
        m0 = fmaxf(m0, __shfl_xor(m0, off));
        m1 = fmaxf(m1, __shfl_xor(m1, off));
        m2 = fmaxf(m2, __shfl_xor(m2, off));
        m3 = fmaxf(m3, __shfl_xor(m3, off));
    }

    // pass B
    float den0 = 0.f, den1 = 0.f, den2 = 0.f, den3 = 0.f;
    float a0 = 0.f, a1 = 0.f, a2 = 0.f, a3 = 0.f;
    const char* hbase = (const char*)hsrc;
    int cbyte = c4 * 2;
    for (int base = rs; base < re; base += 64) {
        int i = base + lane;
        float w0 = 0.f, w1 = 0.f, w2 = 0.f, w3 = 0.f;
        int off = 0;
        if (i < re) {
            float4 lk;
            int s;
            if (base == rs) { lk = lkc[wv][lane]; s = scc[wv][lane]; }
            else {
                s = csr_src[i];
                float4 as = *(const float4*)(alpha_s + (size_t)s * 4);
                lk = make_float4(leaky(as.x + ad4.x), leaky(as.y + ad4.y),
                                 leaky(as.z + ad4.z), leaky(as.w + ad4.w));
            }
            w0 = __expf(lk.x - m0); w1 = __expf(lk.y - m1);
            w2 = __expf(lk.z - m2); w3 = __expf(lk.w - m3);
            off = s * 512;
        }
        den0 += w0; den1 += w1; den2 += w2; den3 += w3;
        pk[wv][lane * 4 + 0] = make_int2(off,       __float_as_int(w0));
        pk[wv][lane * 4 + 1] = make_int2(off + 128, __float_as_int(w1));
        pk[wv][lane * 4 + 2] = make_int2(off + 256, __float_as_int(w2));
        pk[wv][lane * 4 + 3] = make_int2(off + 384, __float_as_int(w3));
        int cnt = min(64, re - base);
#pragma unroll 4
        for (int j = 0; j < cnt; j++) {
            int2 t = pk[wv][j * 4 + head];
            float w = __int_as_float(t.y);
            h4_t hv = *reinterpret_cast<const h4_t*>(hbase + t.x + cbyte);
            a0 += w * (float)hv[0]; a1 += w * (float)hv[1];
            a2 += w * (float)hv[2]; a3 += w * (float)hv[3];
        }
    }
#pragma unroll
    for (int off = 32; off >= 1; off >>= 1) {
        den0 += __shfl_xor(den0, off);
        den1 += __shfl_xor(den1, off);
        den2 += __shfl_xor(den2, off);
        den3 += __shfl_xor(den3, off);
    }
    float den = (head & 2) ? ((head & 1) ? den3 : den2) : ((head & 1) ? den1 : den0);
    float inv = 1.f / (den + 1e-16f);
    int cbase = (head << 6) + c4;
    float v0 = fmaxf(a0 * inv + bias[cbase + 0], 0.f);
    float v1 = fmaxf(a1 * inv + bias[cbase + 1], 0.f);
    float v2 = fmaxf(a2 * inv + bias[cbase + 2], 0.f);
    float v3 = fmaxf(a3 * inv + bias[cbase + 3], 0.f);
    h4_t hv, lv;
    _Float16 h;
    h = (_Float16)v0; hv[0] = h; lv[0] = (_Float16)(v0 - (float)h);
    h = (_Float16)v1; hv[1] = h; lv[1] = (_Float16)(v1 - (float)h);
    h = (_Float16)v2; hv[2] = h; lv[2] = (_Float16)(v2 - (float)h);
    h = (_Float16)v3; hv[3] = h; lv[3] = (_Float16)(v3 - (float)h);
    size_t o = ((size_t)(cbase >> 3) * Mpad + node) * 8 + (cbase & 7);
    *reinterpret_cast<h4_t*>(outH + o) = hv;
    *reinterpret_cast<h4_t*>(outL + o) = lv;
}

// ---------------- aggregation H=1: 4 edges in flight, h4 loads, fp32 out ----------------
__global__ __launch_bounds__(256) void aggregate1_kernel(const _Float16* __restrict__ hsrc,
                                                         const float* __restrict__ alpha_s,
                                                         const float* __restrict__ alpha_d,
                                                         const int* __restrict__ row_ptr,
                                                         const int* __restrict__ csr_src,
                                                         const float* __restrict__ bias,
                                                         float* __restrict__ out, int N) {
    __shared__ int2 pk[4][64];  // (byte offset, w bits)
    int wv = threadIdx.x >> 6, lane = threadIdx.x & 63;
    int node = blockIdx.x * 4 + wv;
    if (node >= N) return;
    int rs = row_ptr[node], re = row_ptr[node + 1];
    float ad = alpha_d[node];
    int e4 = lane >> 4, c4 = (lane & 15) * 4;
    int cbyte = c4 * 2;

    float m = -1e30f;
    for (int base = rs; base < re; base += 64) {
        int i = base + lane;
        if (i < re) {
            int s = csr_src[i];
            m = fmaxf(m, leaky(alpha_s[s] + ad));
        }
    }
#pragma unroll
    for (int off = 32; off >= 1; off >>= 1) m = fmaxf(m, __shfl_xor(m, off));

    float den = 0.f;
    float ax = 0.f, ay = 0.f, az = 0.f, aw = 0.f;
    const char* hbase = (const char*)hsrc;
    for (int base = rs; base < re; base += 64) {
        int i = base + lane;
        float w = 0.f;
        int off = 0;
        if (i < re) {
            int s = csr_src[i];
            w = __expf(leaky(alpha_s[s] + ad) - m);
            off = s * 128;
        }
        den += w;
        pk[wv][lane] = make_int2(off, __float_as_int(w));
        int cnt = min(64, re - base);
#pragma unroll 4
        for (int j = e4; j < cnt; j += 4) {
            int2 t = pk[wv][j];
            float wj = __int_as_float(t.y);
            h4_t hv = *reinterpret_cast<const h4_t*>(hbase + t.x + cbyte);
            ax += wj * (float)hv[0]; ay += wj * (float)hv[1];
            az += wj * (float)hv[2]; aw += wj * (float)hv[3];
        }
    }
    // reduce across the 4 edge slots (lanes lane, lane^16, lane^32, lane^48)
    ax += __shfl_xor(ax, 16); ax += __shfl_xor(ax, 32);
    ay += __shfl_xor(ay, 16); ay += __shfl_xor(ay, 32);
    az += __shfl_xor(az, 16); az += __shfl_xor(az, 32);
    aw += __shfl_xor(aw, 16); aw += __shfl_xor(aw, 32);
#pragma unroll
    for (int off = 32; off >= 1; off >>= 1) den += __shfl_xor(den, off);
    if (e4 == 0) {
        float inv = 1.f / (den + 1e-16f);
        float4 o;
        o.x = ax * inv + bias[c4 + 0];
        o.y = ay * inv + bias[c4 + 1];
        o.z = az * inv + bias[c4 + 2];
        o.w = aw * inv + bias[c4 + 3];
        *(float4*)(out + (size_t)node * 64 + c4) = o;
    }
}

// ---------------- head MLP ----------------
__global__ __launch_bounds__(256) void mlp_head_kernel(const float* __restrict__ hin,
                                                       const float* __restrict__ Wo1,
                                                       const float* __restrict__ bo1,
                                                       const float* __restrict__ Wo2,
                                                       const float* __restrict__ bo2,
                                                       float* __restrict__ out, int N) {
    __shared__ float w1[64 * 32];
    __shared__ float w2[32];
    __shared__ float b1s[32];
    int tid = threadIdx.x;
#pragma unroll
    for (int i = 0; i < 8; i++) w1[tid + i * 256] = Wo1[tid + i * 256];
    if (tid < 32) { w2[tid] = Wo2[tid]; b1s[tid] = bo1[tid]; }
    __syncthreads();
    int n = blockIdx.x * blockDim.x + tid;
    if (n >= N) return;
    float hrow[64];
    const float* pr = hin + (size_t)n * 64;
#pragma unroll
    for (int i = 0; i < 64; i++) hrow[i] = pr[i];
    float sum = 0.f;
    for (int j = 0; j < 32; j++) {
        float a = b1s[j];
#pragma unroll
        for (int k = 0; k < 64; k++) a += hrow[k] * w1[k * 32 + j];
        a = fmaxf(a, 0.f);
        sum += a * w2[j];
    }
    out[n] = sum + bo2[0];
}

// ---------------- launch ----------------
extern "C" void kernel_launch(void* const* d_in, const int* in_sizes, int n_in,
                              void* d_out, int out_size, void* d_ws, size_t ws_size,
                              hipStream_t stream) {
    const float* x     = (const float*)d_in[0];
    const float* W_emb = (const float*)d_in[1];
    const float* b_emb = (const float*)d_in[2];
    const float* W0    = (const float*)d_in[3];
    const float* as0   = (const float*)d_in[4];
    const float* ad0   = (const float*)d_in[5];
    const float* b0    = (const float*)d_in[6];
    const float* W1    = (const float*)d_in[7];
    const float* as1   = (const float*)d_in[8];
    const float* ad1   = (const float*)d_in[9];
    const float* b1    = (const float*)d_in[10];
    const float* W2    = (const float*)d_in[11];
    const float* as2   = (const float*)d_in[12];
    const float* ad2   = (const float*)d_in[13];
    const float* b2    = (const float*)d_in[14];
    const float* Wo1   = (const float*)d_in[15];
    const float* bo1   = (const float*)d_in[16];
    const float* Wo2   = (const float*)d_in[17];
    const float* bo2   = (const float*)d_in[18];
    const int* eidx    = (const int*)d_in[19];

    const int N = in_sizes[0] / 128;
    const int E = in_sizes[19] / 2;
    const int* esrc = eidx;
    const int* edst = eidx + E;
    const int gmB  = (N + 127) / 128;
    const int Mpad = gmB * 128;
    const int nb   = (N + 255) / 256;

    char* w = (char*)d_ws;
    auto alloc = [&](size_t bytes) {
        char* p = w;
        w += (bytes + 255) & ~(size_t)255;
        return (void*)p;
    };
    _Float16* hOut = (_Float16*)alloc((size_t)Mpad * 256 * 2);
    _Float16* PHh  = (_Float16*)alloc((size_t)Mpad * 256 * 2);
    _Float16* PHl  = (_Float16*)alloc((size_t)Mpad * 256 * 2);
    _Float16* XPh  = (_Float16*)alloc((size_t)Mpad * 128 * 2);
    _Float16* XPl  = (_Float16*)alloc((size_t)Mpad * 128 * 2);
    float* bufA    = (float*)alloc((size_t)Mpad * 64 * 4);
    float* aS      = (float*)alloc((size_t)N * 4 * 4);
    float* aD      = (float*)alloc((size_t)N * 4 * 4);
    int*   row_ptr = (int*)alloc((size_t)(N + 1) * 4);
    int*   cursor  = (int*)alloc((size_t)N * 4);
    int*   cnt     = (int*)alloc((size_t)N * 4);
    int*   bsum    = (int*)alloc((size_t)nb * 4);
    int*   csr     = (int*)alloc((size_t)(E + N) * 4);
    _Float16* WeH  = (_Float16*)alloc(128 * 64 * 2);
    _Float16* WeL  = (_Float16*)alloc(128 * 64 * 2);
    _Float16* W0H  = (_Float16*)alloc(64 * 256 * 2);
    _Float16* W0L  = (_Float16*)alloc(64 * 256 * 2);
    _Float16* W1H  = (_Float16*)alloc(256 * 256 * 2);
    _Float16* W1L  = (_Float16*)alloc(256 * 256 * 2);
    _Float16* W2H  = (_Float16*)alloc(256 * 64 * 2);
    _Float16* W2L  = (_Float16*)alloc(256 * 64 * 2);

    // CSR build (multi-block scan)
    hipMemsetAsync(cnt, 0, (size_t)N * 4, stream);
    hist_kernel<<<(E + 255) / 256, 256, 0, stream>>>(edst, E, cnt);
    blocksum_kernel<<<nb, 256, 0, stream>>>(cnt, N, bsum);
    scanbsum_kernel<<<1, 256, 0, stream>>>(bsum, nb, row_ptr + N);
    rowptr_kernel<<<nb, 256, 0, stream>>>(cnt, bsum, N, row_ptr, cursor);
    scatter_kernel<<<(E + N + 255) / 256, 256, 0, stream>>>(esrc, edst, E, N, cursor, csr);

    // weight planes (fused single launch)
    prep_weights_all<<<dim3(256, 4), 256, 0, stream>>>(W_emb, W0, W1, W2,
                                                       WeH, WeL, W0H, W0L, W1H, W1L, W2H, W2L);

    int gn4 = (N + 3) / 4;

    // embedding: planes(x) -> relu(x@W_emb + b_emb) as hi/lo planes
    prep_act_kernel<<<((size_t)Mpad * 16 + 255) / 256, 256, 0, stream>>>(x, XPh, XPl, N, Mpad, 16, 128);
    gemm_emb_kernel<<<dim3(gmB, 1), 256, 0, stream>>>(XPh, XPl, WeH, WeL, b_emb, PHh, PHl, Mpad, N, 128);

    // GAT layer 0
    gemm_gat_kernel<0><<<dim3(gmB, 2), 256, 0, stream>>>(PHh, PHl, W0H, W0L, as0, ad0, hOut, aS, aD, Mpad, N, 64);
    aggregate4_kernel<0><<<gn4, 256, 0, stream>>>(hOut, aS, aD, row_ptr, csr, b0, PHh, PHl, N, Mpad);

    // GAT layer 1
    gemm_gat_kernel<1><<<dim3(gmB, 2), 256, 0, stream>>>(PHh, PHl, W1H, W1L, as1, ad1, hOut, aS, aD, Mpad, N, 256);
    aggregate4_kernel<1><<<gn4, 256, 0, stream>>>(hOut, aS, aD, row_ptr, csr, b1, PHh, PHl, N, Mpad);

    // GAT layer 2 (1 head, no relu)
    gemm_l2_kernel<<<dim3(gmB, 1), 256, 0, stream>>>(PHh, PHl, W2H, W2L, as2, ad2, hOut, aS, aD, Mpad, N, 256);
    aggregate1_kernel<<<gn4, 256, 0, stream>>>(hOut, aS, aD, row_ptr, csr, b2, bufA, N);

    // head MLP -> out [N,1] fp32
    mlp_head_kernel<<<(N + 255) / 256, 256, 0, stream>>>(bufA, Wo1, bo1, Wo2, bo2, (float*)d_out, N);
}

// Round 11
// 510.271 us; speedup vs baseline: 1.5650x; 1.0094x over previous
//
#include <hip/hip_runtime.h>

typedef _Float16 h8_t __attribute__((ext_vector_type(8)));
typedef _Float16 h4_t __attribute__((ext_vector_type(4)));
typedef float floatx4 __attribute__((ext_vector_type(4)));

__device__ __forceinline__ float leaky(float v) { return v >= 0.f ? v : 0.2f * v; }

// ---------------- CSR build ----------------
__global__ void hist_kernel(const int* __restrict__ dst, int E, int* __restrict__ cnt) {
    int e = blockIdx.x * blockDim.x + threadIdx.x;
    if (e < E) atomicAdd(&cnt[dst[e]], 1);
}

__global__ __launch_bounds__(256) void blocksum_kernel(const int* __restrict__ cnt, int N,
                                                       int* __restrict__ bsum) {
    __shared__ int red[256];
    int tid = threadIdx.x;
    int idx = blockIdx.x * 256 + tid;
    red[tid] = idx < N ? cnt[idx] + 1 : 0;
    __syncthreads();
#pragma unroll
    for (int off = 128; off >= 1; off >>= 1) {
        if (tid < off) red[tid] += red[tid + off];
        __syncthreads();
    }
    if (tid == 0) bsum[blockIdx.x] = red[0];
}

__global__ __launch_bounds__(256) void scanbsum_kernel(int* __restrict__ bsum, int nb,
                                                       int* __restrict__ total) {
    __shared__ int part[256];
    int tid = threadIdx.x;
    int per = (nb + 255) / 256;
    int s0 = tid * per, s1 = min(s0 + per, nb);
    int s = 0;
    for (int i = s0; i < s1; i++) s += bsum[i];
    part[tid] = s;
    __syncthreads();
    for (int off = 1; off < 256; off <<= 1) {
        int v = (tid >= off) ? part[tid - off] : 0;
        __syncthreads();
        part[tid] += v;
        __syncthreads();
    }
    int base = (tid == 0) ? 0 : part[tid - 1];
    for (int i = s0; i < s1; i++) {
        int v = bsum[i];
        bsum[i] = base;
        base += v;
    }
    if (tid == 255) *total = part[255];
}

__global__ __launch_bounds__(256) void rowptr_kernel(const int* __restrict__ cnt,
                                                     const int* __restrict__ bsum, int N,
                                                     int* __restrict__ row_ptr,
                                                     int* __restrict__ cursor) {
    __shared__ int lds[256];
    int tid = threadIdx.x;
    int idx = blockIdx.x * 256 + tid;
    int v = idx < N ? cnt[idx] + 1 : 0;
    lds[tid] = v;
    __syncthreads();
    for (int off = 1; off < 256; off <<= 1) {
        int t = (tid >= off) ? lds[tid - off] : 0;
        __syncthreads();
        lds[tid] += t;
        __syncthreads();
    }
    if (idx < N) {
        int p = bsum[blockIdx.x] + lds[tid] - v;
        row_ptr[idx] = p;
        cursor[idx] = p;
    }
}

__global__ void scatter_kernel(const int* __restrict__ src, const int* __restrict__ dst,
                               int E, int N, int* __restrict__ cursor, int* __restrict__ csr_src) {
    int e = blockIdx.x * blockDim.x + threadIdx.x;
    if (e >= E + N) return;
    int s, d;
    if (e < E) { s = src[e]; d = dst[e]; }
    else       { s = e - E;  d = s; }
    int pos = atomicAdd(&cursor[d], 1);
    csr_src[pos] = s;
}

// ---------------- fused weight prep ----------------
__global__ void prep_weights_all(const float* __restrict__ W_emb, const float* __restrict__ W0,
                                 const float* __restrict__ W1, const float* __restrict__ W2,
                                 _Float16* __restrict__ WeH, _Float16* __restrict__ WeL,
                                 _Float16* __restrict__ W0H, _Float16* __restrict__ W0L,
                                 _Float16* __restrict__ W1H, _Float16* __restrict__ W1L,
                                 _Float16* __restrict__ W2H, _Float16* __restrict__ W2L) {
    int which = blockIdx.y;
    const float* W;
    _Float16 *Wh, *Wl;
    int K, N;
    if (which == 0)      { W = W_emb; Wh = WeH; Wl = WeL; K = 128; N = 64; }
    else if (which == 1) { W = W0;    Wh = W0H; Wl = W0L; K = 64;  N = 256; }
    else if (which == 2) { W = W1;    Wh = W1H; Wl = W1L; K = 256; N = 256; }
    else                 { W = W2;    Wh = W2H; Wl = W2L; K = 256; N = 64; }
    int idx = blockIdx.x * blockDim.x + threadIdx.x;
    if (idx >= K * N) return;
    int k = idx / N, n = idx % N;
    float v = W[idx];
    _Float16 hi = (_Float16)v;
    _Float16 lo = (_Float16)(v - (float)hi);
    size_t o = ((size_t)(k >> 3) * N + n) * 8 + (k & 7);
    Wh[o] = hi; Wl[o] = lo;
}

// ---------------- activation prep ----------------
__global__ void prep_act_kernel(const float* __restrict__ X,
                                _Float16* __restrict__ Ph, _Float16* __restrict__ Pl,
                                int M, int Mpad, int Kg, int K) {
    int idx = blockIdx.x * blockDim.x + threadIdx.x;
    if (idx >= Mpad * Kg) return;
    int row = idx / Kg, kg = idx - row * Kg;
    float vs[8] = {0.f, 0.f, 0.f, 0.f, 0.f, 0.f, 0.f, 0.f};
    if (row < M) {
        const float4* p = (const float4*)(X + (size_t)row * K + kg * 8);
        float4 a = p[0], b = p[1];
        vs[0] = a.x; vs[1] = a.y; vs[2] = a.z; vs[3] = a.w;
        vs[4] = b.x; vs[5] = b.y; vs[6] = b.z; vs[7] = b.w;
    }
    h8_t hh, hl;
#pragma unroll
    for (int j = 0; j < 8; j++) {
        _Float16 hi = (_Float16)vs[j];
        hh[j] = hi;
        hl[j] = (_Float16)(vs[j] - (float)hi);
    }
    size_t o = ((size_t)kg * Mpad + row) * 8;
    *reinterpret_cast<h8_t*>(Ph + o) = hh;
    *reinterpret_cast<h8_t*>(Pl + o) = hl;
}

// ---------------- embedding GEMM -> hi/lo planes ----------------
__global__ __launch_bounds__(256) void gemm_emb_kernel(
        const _Float16* __restrict__ Ah, const _Float16* __restrict__ Al,
        const _Float16* __restrict__ Bh, const _Float16* __restrict__ Bl,
        const float* __restrict__ bias,
        _Float16* __restrict__ Ph, _Float16* __restrict__ Pl,
        int Mpad, int M, int K) {
    const int Nn = 64;
    __shared__ _Float16 stH[4][16][72];
    __shared__ _Float16 stL[4][16][72];
    int tid = threadIdx.x;
    int wv = tid >> 6, lane = tid & 63;
    int m16 = lane & 15, quad = lane >> 4;
    int row0 = blockIdx.x * 128 + wv * 32;

    floatx4 acc[2][4];
#pragma unroll
    for (int t = 0; t < 2; t++)
#pragma unroll
        for (int c = 0; c < 4; c++)
#pragma unroll
            for (int i = 0; i < 4; i++) acc[t][c][i] = 0.f;

    size_t aoff = ((size_t)quad * Mpad + row0 + m16) * 8;
    size_t boff = ((size_t)quad * Nn + m16) * 8;
    const size_t aStep = (size_t)Mpad * 32;
    const size_t bStep = (size_t)Nn * 32;

    for (int kt = 0; kt < K; kt += 32) {
        h8_t ah0 = *reinterpret_cast<const h8_t*>(Ah + aoff);
        h8_t ah1 = *reinterpret_cast<const h8_t*>(Ah + aoff + 128);
        h8_t al0 = *reinterpret_cast<const h8_t*>(Al + aoff);
        h8_t al1 = *reinterpret_cast<const h8_t*>(Al + aoff + 128);
#pragma unroll
        for (int c = 0; c < 4; c++) {
            h8_t bh = *reinterpret_cast<const h8_t*>(Bh + boff + c * 128);
            h8_t bl = *reinterpret_cast<const h8_t*>(Bl + boff + c * 128);
            acc[0][c] = __builtin_amdgcn_mfma_f32_16x16x32_f16(ah0, bh, acc[0][c], 0, 0, 0);
            acc[1][c] = __builtin_amdgcn_mfma_f32_16x16x32_f16(ah1, bh, acc[1][c], 0, 0, 0);
            acc[0][c] = __builtin_amdgcn_mfma_f32_16x16x32_f16(ah0, bl, acc[0][c], 0, 0, 0);
            acc[1][c] = __builtin_amdgcn_mfma_f32_16x16x32_f16(ah1, bl, acc[1][c], 0, 0, 0);
            acc[0][c] = __builtin_amdgcn_mfma_f32_16x16x32_f16(al0, bh, acc[0][c], 0, 0, 0);
            acc[1][c] = __builtin_amdgcn_mfma_f32_16x16x32_f16(al1, bh, acc[1][c], 0, 0, 0);
        }
        aoff += aStep; boff += bStep;
    }

#pragma unroll
    for (int t = 0; t < 2; t++) {
#pragma unroll
        for (int c = 0; c < 4; c++) {
            float bv = bias[c * 16 + m16];
#pragma unroll
            for (int i = 0; i < 4; i++) {
                float v = fmaxf(acc[t][c][i] + bv, 0.f);
                _Float16 hi = (_Float16)v;
                stH[wv][quad * 4 + i][c * 16 + m16] = hi;
                stL[wv][quad * 4 + i][c * 16 + m16] = (_Float16)(v - (float)hi);
            }
        }
        __syncthreads();
        int rowChunk = row0 + t * 16;
#pragma unroll
        for (int it = 0; it < 2; it++) {
            int lid = it * 64 + lane;
            int kg = lid >> 4, rloc = lid & 15;
            h8_t vh = *reinterpret_cast<const h8_t*>(&stH[wv][rloc][kg * 8]);
            h8_t vl = *reinterpret_cast<const h8_t*>(&stL[wv][rloc][kg * 8]);
            size_t o = ((size_t)kg * Mpad + rowChunk + rloc) * 8;
            *reinterpret_cast<h8_t*>(Ph + o) = vh;
            *reinterpret_cast<h8_t*>(Pl + o) = vl;
        }
        __syncthreads();
    }
}

// ---------------- GAT GEMM (Nn=256) + fused alphas ----------------
template <int TAG>
__global__ __launch_bounds__(256) void gemm_gat_kernel(
        const _Float16* __restrict__ Ah, const _Float16* __restrict__ Al,
        const _Float16* __restrict__ Bh, const _Float16* __restrict__ Bl,
        const float* __restrict__ a_src, const float* __restrict__ a_dst,
        _Float16* __restrict__ hOut, float* __restrict__ aS, float* __restrict__ aD,
        int Mpad, int M, int K) {
    const int Nn = 256;
    __shared__ _Float16 st[4][16][136];
    int tid = threadIdx.x;
    int wv = tid >> 6, lane = tid & 63;
    int m16 = lane & 15, quad = lane >> 4;
    int row0 = blockIdx.x * 128 + wv * 32;
    int colBase = blockIdx.y * 128;

    floatx4 acc[2][8];
#pragma unroll
    for (int t = 0; t < 2; t++)
#pragma unroll
        for (int c = 0; c < 8; c++)
#pragma unroll
            for (int i = 0; i < 4; i++) acc[t][c][i] = 0.f;

    size_t aoff = ((size_t)quad * Mpad + row0 + m16) * 8;
    size_t boff = ((size_t)quad * Nn + colBase + m16) * 8;
    const size_t aStep = (size_t)Mpad * 32;
    const size_t bStep = (size_t)Nn * 32;

    for (int kt = 0; kt < K; kt += 32) {
        h8_t ah0 = *reinterpret_cast<const h8_t*>(Ah + aoff);
        h8_t ah1 = *reinterpret_cast<const h8_t*>(Ah + aoff + 128);
        h8_t al0 = *reinterpret_cast<const h8_t*>(Al + aoff);
        h8_t al1 = *reinterpret_cast<const h8_t*>(Al + aoff + 128);
#pragma unroll
        for (int c = 0; c < 8; c++) {
            h8_t bh = *reinterpret_cast<const h8_t*>(Bh + boff + c * 128);
            h8_t bl = *reinterpret_cast<const h8_t*>(Bl + boff + c * 128);
            acc[0][c] = __builtin_amdgcn_mfma_f32_16x16x32_f16(ah0, bh, acc[0][c], 0, 0, 0);
            acc[1][c] = __builtin_amdgcn_mfma_f32_16x16x32_f16(ah1, bh, acc[1][c], 0, 0, 0);
            acc[0][c] = __builtin_amdgcn_mfma_f32_16x16x32_f16(ah0, bl, acc[0][c], 0, 0, 0);
            acc[1][c] = __builtin_amdgcn_mfma_f32_16x16x32_f16(ah1, bl, acc[1][c], 0, 0, 0);
            acc[0][c] = __builtin_amdgcn_mfma_f32_16x16x32_f16(al0, bh, acc[0][c], 0, 0, 0);
            acc[1][c] = __builtin_amdgcn_mfma_f32_16x16x32_f16(al1, bh, acc[1][c], 0, 0, 0);
        }
        aoff += aStep; boff += bStep;
    }

    float asv[8], adv[8];
#pragma unroll
    for (int c = 0; c < 8; c++) {
        asv[c] = a_src[colBase + c * 16 + m16];
        adv[c] = a_dst[colBase + c * 16 + m16];
    }
    int hb = colBase >> 6;
#pragma unroll
    for (int t = 0; t < 2; t++) {
#pragma unroll
        for (int i = 0; i < 4; i++) {
            int r = row0 + t * 16 + quad * 4 + i;
            float s0 = 0.f, d0 = 0.f, s1 = 0.f, d1 = 0.f;
#pragma unroll
            for (int c = 0; c < 8; c++) {
                float v = acc[t][c][i];
                if (c < 4) { s0 += v * asv[c]; d0 += v * adv[c]; }
                else       { s1 += v * asv[c]; d1 += v * adv[c]; }
            }
#pragma unroll
            for (int off = 1; off < 16; off <<= 1) {
                s0 += __shfl_xor(s0, off);
                d0 += __shfl_xor(d0, off);
                s1 += __shfl_xor(s1, off);
                d1 += __shfl_xor(d1, off);
            }
            if (m16 == 0 && r < M) {
                aS[r * 4 + hb] = s0;     aD[r * 4 + hb] = d0;
                aS[r * 4 + hb + 1] = s1; aD[r * 4 + hb + 1] = d1;
            }
        }
    }

#pragma unroll
    for (int t = 0; t < 2; t++) {
#pragma unroll
        for (int c = 0; c < 8; c++)
#pragma unroll
            for (int i = 0; i < 4; i++)
                st[wv][quad * 4 + i][c * 16 + m16] = (_Float16)acc[t][c][i];
        __syncthreads();
        int rowChunk = row0 + t * 16;
#pragma unroll
        for (int it = 0; it < 4; it++) {
            int lid = it * 64 + lane;
            int rloc = lid >> 4, u = lid & 15;
            h8_t v = *reinterpret_cast<const h8_t*>(&st[wv][rloc][u * 8]);
            *reinterpret_cast<h8_t*>(hOut + (size_t)(rowChunk + rloc) * 256 + colBase + u * 8) = v;
        }
        __syncthreads();
    }
}

// ---------------- layer-2 GEMM (Nn=64) + fused alphas ----------------
__global__ __launch_bounds__(256) void gemm_l2_kernel(
        const _Float16* __restrict__ Ah, const _Float16* __restrict__ Al,
        const _Float16* __restrict__ Bh, const _Float16* __restrict__ Bl,
        const float* __restrict__ a_src, const float* __restrict__ a_dst,
        _Float16* __restrict__ hOut, float* __restrict__ aS, float* __restrict__ aD,
        int Mpad, int M, int K) {
    const int Nn = 64;
    __shared__ _Float16 st[4][16][72];
    int tid = threadIdx.x;
    int wv = tid >> 6, lane = tid & 63;
    int m16 = lane & 15, quad = lane >> 4;
    int row0 = blockIdx.x * 128 + wv * 32;

    floatx4 acc[2][4];
#pragma unroll
    for (int t = 0; t < 2; t++)
#pragma unroll
        for (int c = 0; c < 4; c++)
#pragma unroll
            for (int i = 0; i < 4; i++) acc[t][c][i] = 0.f;

    size_t aoff = ((size_t)quad * Mpad + row0 + m16) * 8;
    size_t boff = ((size_t)quad * Nn + m16) * 8;
    const size_t aStep = (size_t)Mpad * 32;
    const size_t bStep = (size_t)Nn * 32;

    for (int kt = 0; kt < K; kt += 32) {
        h8_t ah0 = *reinterpret_cast<const h8_t*>(Ah + aoff);
        h8_t ah1 = *reinterpret_cast<const h8_t*>(Ah + aoff + 128);
        h8_t al0 = *reinterpret_cast<const h8_t*>(Al + aoff);
        h8_t al1 = *reinterpret_cast<const h8_t*>(Al + aoff + 128);
#pragma unroll
        for (int c = 0; c < 4; c++) {
            h8_t bh = *reinterpret_cast<const h8_t*>(Bh + boff + c * 128);
            h8_t bl = *reinterpret_cast<const h8_t*>(Bl + boff + c * 128);
            acc[0][c] = __builtin_amdgcn_mfma_f32_16x16x32_f16(ah0, bh, acc[0][c], 0, 0, 0);
            acc[1][c] = __builtin_amdgcn_mfma_f32_16x16x32_f16(ah1, bh, acc[1][c], 0, 0, 0);
            acc[0][c] = __builtin_amdgcn_mfma_f32_16x16x32_f16(ah0, bl, acc[0][c], 0, 0, 0);
            acc[1][c] = __builtin_amdgcn_mfma_f32_16x16x32_f16(ah1, bl, acc[1][c], 0, 0, 0);
            acc[0][c] = __builtin_amdgcn_mfma_f32_16x16x32_f16(al0, bh, acc[0][c], 0, 0, 0);
            acc[1][c] = __builtin_amdgcn_mfma_f32_16x16x32_f16(al1, bh, acc[1][c], 0, 0, 0);
        }
        aoff += aStep; boff += bStep;
    }

    float asv[4], adv[4];
#pragma unroll
    for (int c = 0; c < 4; c++) {
        asv[c] = a_src[c * 16 + m16];
        adv[c] = a_dst[c * 16 + m16];
    }
#pragma unroll
    for (int t = 0; t < 2; t++) {
#pragma unroll
        for (int i = 0; i < 4; i++) {
            int r = row0 + t * 16 + quad * 4 + i;
            float s0 = 0.f, d0 = 0.f;
#pragma unroll
            for (int c = 0; c < 4; c++) {
                float v = acc[t][c][i];
                s0 += v * asv[c]; d0 += v * adv[c];
            }
#pragma unroll
            for (int off = 1; off < 16; off <<= 1) {
                s0 += __shfl_xor(s0, off);
                d0 += __shfl_xor(d0, off);
            }
            if (m16 == 0 && r < M) { aS[r] = s0; aD[r] = d0; }
        }
    }

#pragma unroll
    for (int t = 0; t < 2; t++) {
#pragma unroll
        for (int c = 0; c < 4; c++)
#pragma unroll
            for (int i = 0; i < 4; i++)
                st[wv][quad * 4 + i][c * 16 + m16] = (_Float16)acc[t][c][i];
        __syncthreads();
        int rowChunk = row0 + t * 16;
#pragma unroll
        for (int it = 0; it < 2; it++) {
            int lid = it * 64 + lane;
            int rloc = lid >> 3, u = lid & 7;
            h8_t v = *reinterpret_cast<const h8_t*>(&st[wv][rloc][u * 8]);
            *reinterpret_cast<h8_t*>(hOut + (size_t)(rowChunk + rloc) * 64 + u * 8) = v;
        }
        __syncthreads();
    }
}

// ---------------- aggregation H=4: single-pass (no max), conflict-free LDS staging ----------------
template <int TAG>
__global__ __launch_bounds__(256) void aggregate4_kernel(const _Float16* __restrict__ hsrc,
                                                         const float* __restrict__ alpha_s,
                                                         const float* __restrict__ alpha_d,
                                                         const int* __restrict__ row_ptr,
                                                         const int* __restrict__ csr_src,
                                                         const float* __restrict__ bias,
                                                         _Float16* __restrict__ outH,
                                                         _Float16* __restrict__ outL,
                                                         int N, int Mpad) {
    __shared__ float wlds[4][64][4];
    __shared__ int   slds[4][64];
    int wv = threadIdx.x >> 6, lane = threadIdx.x & 63;
    int node = blockIdx.x * 4 + wv;
    if (node >= N) return;
    int rs = row_ptr[node], re = row_ptr[node + 1];
    int head = lane >> 4, c4 = (lane & 15) * 4;
    float4 ad4 = *(const float4*)(alpha_d + (size_t)node * 4);

    float den0 = 0.f, den1 = 0.f, den2 = 0.f, den3 = 0.f;
    float a0 = 0.f, a1 = 0.f, a2 = 0.f, a3 = 0.f;
    float* wp = &wlds[wv][0][0];
    int*   sp = &slds[wv][0];
    const char* hbase = (const char*)hsrc;
    int hoff = (head << 7) + c4 * 2;   // head*128B + channel byte offset
    for (int base = rs; base < re; base += 64) {
        int i = base + lane;
        float w0 = 0.f, w1 = 0.f, w2 = 0.f, w3 = 0.f;
        int off = 0;
        if (i < re) {
            int s = csr_src[i];
            float4 as = *(const float4*)(alpha_s + (size_t)s * 4);
            // exp without max-subtraction: scores are O(<=10), fp32-safe (clamped)
            w0 = __expf(fminf(leaky(as.x + ad4.x), 60.f));
            w1 = __expf(fminf(leaky(as.y + ad4.y), 60.f));
            w2 = __expf(fminf(leaky(as.z + ad4.z), 60.f));
            w3 = __expf(fminf(leaky(as.w + ad4.w), 60.f));
            off = s * 512;
        }
        den0 += w0; den1 += w1; den2 += w2; den3 += w3;
        sp[lane] = off;
        *(float4*)(wp + lane * 4) = make_float4(w0, w1, w2, w3);
        int cnt = min(64, re - base);
#pragma unroll 4
        for (int j = 0; j < cnt; j++) {
            int o2 = sp[j];
            float w = wp[j * 4 + head];
            h4_t hv = *reinterpret_cast<const h4_t*>(hbase + o2 + hoff);
            a0 += w * (float)hv[0]; a1 += w * (float)hv[1];
            a2 += w * (float)hv[2]; a3 += w * (float)hv[3];
        }
    }
#pragma unroll
    for (int off = 32; off >= 1; off >>= 1) {
        den0 += __shfl_xor(den0, off);
        den1 += __shfl_xor(den1, off);
        den2 += __shfl_xor(den2, off);
        den3 += __shfl_xor(den3, off);
    }
    float den = (head & 2) ? ((head & 1) ? den3 : den2) : ((head & 1) ? den1 : den0);
    float inv = 1.f / (den + 1e-16f);
    int cbase = (head << 6) + c4;
    float v0 = fmaxf(a0 * inv + bias[cbase + 0], 0.f);
    float v1 = fmaxf(a1 * inv + bias[cbase + 1], 0.f);
    float v2 = fmaxf(a2 * inv + bias[cbase + 2], 0.f);
    float v3 = fmaxf(a3 * inv + bias[cbase + 3], 0.f);
    h4_t hv, lv;
    _Float16 h;
    h = (_Float16)v0; hv[0] = h; lv[0] = (_Float16)(v0 - (float)h);
    h = (_Float16)v1; hv[1] = h; lv[1] = (_Float16)(v1 - (float)h);
    h = (_Float16)v2; hv[2] = h; lv[2] = (_Float16)(v2 - (float)h);
    h = (_Float16)v3; hv[3] = h; lv[3] = (_Float16)(v3 - (float)h);
    size_t o = ((size_t)(cbase >> 3) * Mpad + node) * 8 + (cbase & 7);
    *reinterpret_cast<h4_t*>(outH + o) = hv;
    *reinterpret_cast<h4_t*>(outL + o) = lv;
}

// ---------------- aggregation H=1: single-pass, 4 edges in flight ----------------
__global__ __launch_bounds__(256) void aggregate1_kernel(const _Float16* __restrict__ hsrc,
                                                         const float* __restrict__ alpha_s,
                                                         const float* __restrict__ alpha_d,
                                                         const int* __restrict__ row_ptr,
                                                         const int* __restrict__ csr_src,
                                                         const float* __restrict__ bias,
                                                         float* __restrict__ out, int N) {
    __shared__ float wlds[4][64];
    __shared__ int   slds[4][64];
    int wv = threadIdx.x >> 6, lane = threadIdx.x & 63;
    int node = blockIdx.x * 4 + wv;
    if (node >= N) return;
    int rs = row_ptr[node], re = row_ptr[node + 1];
    float ad = alpha_d[node];
    int e4 = lane >> 4, c4 = (lane & 15) * 4;
    int cbyte = c4 * 2;

    float den = 0.f;
    float ax = 0.f, ay = 0.f, az = 0.f, aw = 0.f;
    const char* hbase = (const char*)hsrc;
    float* wp = &wlds[wv][0];
    int*   sp = &slds[wv][0];
    for (int base = rs; base < re; base += 64) {
        int i = base + lane;
        float w = 0.f;
        int off = 0;
        if (i < re) {
            int s = csr_src[i];
            w = __expf(fminf(leaky(alpha_s[s] + ad), 60.f));
            off = s * 128;
        }
        den += w;
        sp[lane] = off;
        wp[lane] = w;
        int cnt = min(64, re - base);
#pragma unroll 4
        for (int j = e4; j < cnt; j += 4) {
            float wj = wp[j];
            h4_t hv = *reinterpret_cast<const h4_t*>(hbase + sp[j] + cbyte);
            ax += wj * (float)hv[0]; ay += wj * (float)hv[1];
            az += wj * (float)hv[2]; aw += wj * (float)hv[3];
        }
    }
    ax += __shfl_xor(ax, 16); ax += __shfl_xor(ax, 32);
    ay += __shfl_xor(ay, 16); ay += __shfl_xor(ay, 32);
    az += __shfl_xor(az, 16); az += __shfl_xor(az, 32);
    aw += __shfl_xor(aw, 16); aw += __shfl_xor(aw, 32);
#pragma unroll
    for (int off = 32; off >= 1; off >>= 1) den += __shfl_xor(den, off);
    if (e4 == 0) {
        float inv = 1.f / (den + 1e-16f);
        float4 o;
        o.x = ax * inv + bias[c4 + 0];
        o.y = ay * inv + bias[c4 + 1];
        o.z = az * inv + bias[c4 + 2];
        o.w = aw * inv + bias[c4 + 3];
        *(float4*)(out + (size_t)node * 64 + c4) = o;
    }
}

// ---------------- head MLP ----------------
__global__ __launch_bounds__(256) void mlp_head_kernel(const float* __restrict__ hin,
                                                       const float* __restrict__ Wo1,
                                                       const float* __restrict__ bo1,
                                                       const float* __restrict__ Wo2,
                                                       const float* __restrict__ bo2,
                                                       float* __restrict__ out, int N) {
    __shared__ float w1[64 * 32];
    __shared__ float w2[32];
    __shared__ float b1s[32];
    int tid = threadIdx.x;
#pragma unroll
    for (int i = 0; i < 8; i++) w1[tid + i * 256] = Wo1[tid + i * 256];
    if (tid < 32) { w2[tid] = Wo2[tid]; b1s[tid] = bo1[tid]; }
    __syncthreads();
    int n = blockIdx.x * blockDim.x + tid;
    if (n >= N) return;
    float hrow[64];
    const float* pr = hin + (size_t)n * 64;
#pragma unroll
    for (int i = 0; i < 64; i++) hrow[i] = pr[i];
    float sum = 0.f;
    for (int j = 0; j < 32; j++) {
        float a = b1s[j];
#pragma unroll
        for (int k = 0; k < 64; k++) a += hrow[k] * w1[k * 32 + j];
        a = fmaxf(a, 0.f);
        sum += a * w2[j];
    }
    out[n] = sum + bo2[0];
}

// ---------------- launch ----------------
extern "C" void kernel_launch(void* const* d_in, const int* in_sizes, int n_in,
                              void* d_out, int out_size, void* d_ws, size_t ws_size,
                              hipStream_t stream) {
    const float* x     = (const float*)d_in[0];
    const float* W_emb = (const float*)d_in[1];
    const float* b_emb = (const float*)d_in[2];
    const float* W0    = (const float*)d_in[3];
    const float* as0   = (const float*)d_in[4];
    const float* ad0   = (const float*)d_in[5];
    const float* b0    = (const float*)d_in[6];
    const float* W1    = (const float*)d_in[7];
    const float* as1   = (const float*)d_in[8];
    const float* ad1   = (const float*)d_in[9];
    const float* b1    = (const float*)d_in[10];
    const float* W2    = (const float*)d_in[11];
    const float* as2   = (const float*)d_in[12];
    const float* ad2   = (const float*)d_in[13];
    const float* b2    = (const float*)d_in[14];
    const float* Wo1   = (const float*)d_in[15];
    const float* bo1   = (const float*)d_in[16];
    const float* Wo2   = (const float*)d_in[17];
    const float* bo2   = (const float*)d_in[18];
    const int* eidx    = (const int*)d_in[19];

    const int N = in_sizes[0] / 128;
    const int E = in_sizes[19] / 2;
    const int* esrc = eidx;
    const int* edst = eidx + E;
    const int gmB  = (N + 127) / 128;
    const int Mpad = gmB * 128;
    const int nb   = (N + 255) / 256;

    char* w = (char*)d_ws;
    auto alloc = [&](size_t bytes) {
        char* p = w;
        w += (bytes + 255) & ~(size_t)255;
        return (void*)p;
    };
    _Float16* hOut = (_Float16*)alloc((size_t)Mpad * 256 * 2);
    _Float16* PHh  = (_Float16*)alloc((size_t)Mpad * 256 * 2);
    _Float16* PHl  = (_Float16*)alloc((size_t)Mpad * 256 * 2);
    _Float16* XPh  = (_Float16*)alloc((size_t)Mpad * 128 * 2);
    _Float16* XPl  = (_Float16*)alloc((size_t)Mpad * 128 * 2);
    float* bufA    = (float*)alloc((size_t)Mpad * 64 * 4);
    float* aS      = (float*)alloc((size_t)N * 4 * 4);
    float* aD      = (float*)alloc((size_t)N * 4 * 4);
    int*   row_ptr = (int*)alloc((size_t)(N + 1) * 4);
    int*   cursor  = (int*)alloc((size_t)N * 4);
    int*   cnt     = (int*)alloc((size_t)N * 4);
    int*   bsum    = (int*)alloc((size_t)nb * 4);
    int*   csr     = (int*)alloc((size_t)(E + N) * 4);
    _Float16* WeH  = (_Float16*)alloc(128 * 64 * 2);
    _Float16* WeL  = (_Float16*)alloc(128 * 64 * 2);
    _Float16* W0H  = (_Float16*)alloc(64 * 256 * 2);
    _Float16* W0L  = (_Float16*)alloc(64 * 256 * 2);
    _Float16* W1H  = (_Float16*)alloc(256 * 256 * 2);
    _Float16* W1L  = (_Float16*)alloc(256 * 256 * 2);
    _Float16* W2H  = (_Float16*)alloc(256 * 64 * 2);
    _Float16* W2L  = (_Float16*)alloc(256 * 64 * 2);

    // CSR build (multi-block scan)
    hipMemsetAsync(cnt, 0, (size_t)N * 4, stream);
    hist_kernel<<<(E + 255) / 256, 256, 0, stream>>>(edst, E, cnt);
    blocksum_kernel<<<nb, 256, 0, stream>>>(cnt, N, bsum);
    scanbsum_kernel<<<1, 256, 0, stream>>>(bsum, nb, row_ptr + N);
    rowptr_kernel<<<nb, 256, 0, stream>>>(cnt, bsum, N, row_ptr, cursor);
    scatter_kernel<<<(E + N + 255) / 256, 256, 0, stream>>>(esrc, edst, E, N, cursor, csr);

    // weight planes (fused single launch)
    prep_weights_all<<<dim3(256, 4), 256, 0, stream>>>(W_emb, W0, W1, W2,
                                                       WeH, WeL, W0H, W0L, W1H, W1L, W2H, W2L);

    int gn4 = (N + 3) / 4;

    // embedding
    prep_act_kernel<<<((size_t)Mpad * 16 + 255) / 256, 256, 0, stream>>>(x, XPh, XPl, N, Mpad, 16, 128);
    gemm_emb_kernel<<<dim3(gmB, 1), 256, 0, stream>>>(XPh, XPl, WeH, WeL, b_emb, PHh, PHl, Mpad, N, 128);

    // GAT layer 0
    gemm_gat_kernel<0><<<dim3(gmB, 2), 256, 0, stream>>>(PHh, PHl, W0H, W0L, as0, ad0, hOut, aS, aD, Mpad, N, 64);
    aggregate4_kernel<0><<<gn4, 256, 0, stream>>>(hOut, aS, aD, row_ptr, csr, b0, PHh, PHl, N, Mpad);

    // GAT layer 1
    gemm_gat_kernel<1><<<dim3(gmB, 2), 256, 0, stream>>>(PHh, PHl, W1H, W1L, as1, ad1, hOut, aS, aD, Mpad, N, 256);
    aggregate4_kernel<1><<<gn4, 256, 0, stream>>>(hOut, aS, aD, row_ptr, csr, b1, PHh, PHl, N, Mpad);

    // GAT layer 2 (1 head, no relu)
    gemm_l2_kernel<<<dim3(gmB, 1), 256, 0, stream>>>(PHh, PHl, W2H, W2L, as2, ad2, hOut, aS, aD, Mpad, N, 256);
    aggregate1_kernel<<<gn4, 256, 0, stream>>>(hOut, aS, aD, row_ptr, csr, b2, bufA, N);

    // head MLP -> out [N,1] fp32
    mlp_head_kernel<<<(N + 255) / 256, 256, 0, stream>>>(bufA, Wo1, bo1, Wo2, bo2, (float*)d_out, N);
}

// Round 12
// 493.282 us; speedup vs baseline: 1.6189x; 1.0344x over previous
//
#include <hip/hip_runtime.h>

typedef _Float16 h8_t __attribute__((ext_vector_type(8)));
typedef _Float16 h4_t __attribute__((ext_vector_type(4)));
typedef float floatx4 __attribute__((ext_vector_type(4)));

__device__ __forceinline__ float leaky(float v) { return v >= 0.f ? v : 0.2f * v; }

// ---------------- CSR build ----------------
__global__ void hist_kernel(const int* __restrict__ dst, int E, int* __restrict__ cnt) {
    int e = blockIdx.x * blockDim.x + threadIdx.x;
    if (e < E) atomicAdd(&cnt[dst[e]], 1);
}

__global__ __launch_bounds__(256) void blocksum_kernel(const int* __restrict__ cnt, int N,
                                                       int* __restrict__ bsum) {
    __shared__ int red[256];
    int tid = threadIdx.x;
    int idx = blockIdx.x * 256 + tid;
    red[tid] = idx < N ? cnt[idx] + 1 : 0;
    __syncthreads();
#pragma unroll
    for (int off = 128; off >= 1; off >>= 1) {
        if (tid < off) red[tid] += red[tid + off];
        __syncthreads();
    }
    if (tid == 0) bsum[blockIdx.x] = red[0];
}

__global__ __launch_bounds__(256) void scanbsum_kernel(int* __restrict__ bsum, int nb,
                                                       int* __restrict__ total) {
    __shared__ int part[256];
    int tid = threadIdx.x;
    int per = (nb + 255) / 256;
    int s0 = tid * per, s1 = min(s0 + per, nb);
    int s = 0;
    for (int i = s0; i < s1; i++) s += bsum[i];
    part[tid] = s;
    __syncthreads();
    for (int off = 1; off < 256; off <<= 1) {
        int v = (tid >= off) ? part[tid - off] : 0;
        __syncthreads();
        part[tid] += v;
        __syncthreads();
    }
    int base = (tid == 0) ? 0 : part[tid - 1];
    for (int i = s0; i < s1; i++) {
        int v = bsum[i];
        bsum[i] = base;
        base += v;
    }
    if (tid == 255) *total = part[255];
}

__global__ __launch_bounds__(256) void rowptr_kernel(const int* __restrict__ cnt,
                                                     const int* __restrict__ bsum, int N,
                                                     int* __restrict__ row_ptr,
                                                     int* __restrict__ cursor) {
    __shared__ int lds[256];
    int tid = threadIdx.x;
    int idx = blockIdx.x * 256 + tid;
    int v = idx < N ? cnt[idx] + 1 : 0;
    lds[tid] = v;
    __syncthreads();
    for (int off = 1; off < 256; off <<= 1) {
        int t = (tid >= off) ? lds[tid - off] : 0;
        __syncthreads();
        lds[tid] += t;
        __syncthreads();
    }
    if (idx < N) {
        int p = bsum[blockIdx.x] + lds[tid] - v;
        row_ptr[idx] = p;
        cursor[idx] = p;
    }
}

__global__ void scatter_kernel(const int* __restrict__ src, const int* __restrict__ dst,
                               int E, int N, int* __restrict__ cursor, int* __restrict__ csr_src) {
    int e = blockIdx.x * blockDim.x + threadIdx.x;
    if (e >= E + N) return;
    int s, d;
    if (e < E) { s = src[e]; d = dst[e]; }
    else       { s = e - E;  d = s; }
    int pos = atomicAdd(&cursor[d], 1);
    csr_src[pos] = s;
}

// ---------------- fused weight prep ----------------
__global__ void prep_weights_all(const float* __restrict__ W_emb, const float* __restrict__ W0,
                                 const float* __restrict__ W1, const float* __restrict__ W2,
                                 _Float16* __restrict__ WeH, _Float16* __restrict__ WeL,
                                 _Float16* __restrict__ W0H, _Float16* __restrict__ W0L,
                                 _Float16* __restrict__ W1H, _Float16* __restrict__ W1L,
                                 _Float16* __restrict__ W2H, _Float16* __restrict__ W2L) {
    int which = blockIdx.y;
    const float* W;
    _Float16 *Wh, *Wl;
    int K, N;
    if (which == 0)      { W = W_emb; Wh = WeH; Wl = WeL; K = 128; N = 64; }
    else if (which == 1) { W = W0;    Wh = W0H; Wl = W0L; K = 64;  N = 256; }
    else if (which == 2) { W = W1;    Wh = W1H; Wl = W1L; K = 256; N = 256; }
    else                 { W = W2;    Wh = W2H; Wl = W2L; K = 256; N = 64; }
    int idx = blockIdx.x * blockDim.x + threadIdx.x;
    if (idx >= K * N) return;
    int k = idx / N, n = idx % N;
    float v = W[idx];
    _Float16 hi = (_Float16)v;
    _Float16 lo = (_Float16)(v - (float)hi);
    size_t o = ((size_t)(k >> 3) * N + n) * 8 + (k & 7);
    Wh[o] = hi; Wl[o] = lo;
}

// ---------------- activation prep ----------------
__global__ void prep_act_kernel(const float* __restrict__ X,
                                _Float16* __restrict__ Ph, _Float16* __restrict__ Pl,
                                int M, int Mpad, int Kg, int K) {
    int idx = blockIdx.x * blockDim.x + threadIdx.x;
    if (idx >= Mpad * Kg) return;
    int row = idx / Kg, kg = idx - row * Kg;
    float vs[8] = {0.f, 0.f, 0.f, 0.f, 0.f, 0.f, 0.f, 0.f};
    if (row < M) {
        const float4* p = (const float4*)(X + (size_t)row * K + kg * 8);
        float4 a = p[0], b = p[1];
        vs[0] = a.x; vs[1] = a.y; vs[2] = a.z; vs[3] = a.w;
        vs[4] = b.x; vs[5] = b.y; vs[6] = b.z; vs[7] = b.w;
    }
    h8_t hh, hl;
#pragma unroll
    for (int j = 0; j < 8; j++) {
        _Float16 hi = (_Float16)vs[j];
        hh[j] = hi;
        hl[j] = (_Float16)(vs[j] - (float)hi);
    }
    size_t o = ((size_t)kg * Mpad + row) * 8;
    *reinterpret_cast<h8_t*>(Ph + o) = hh;
    *reinterpret_cast<h8_t*>(Pl + o) = hl;
}

// ---------------- embedding GEMM (Nn=64) -> hi/lo planes; B staged in LDS ----------------
__global__ __launch_bounds__(256) void gemm_emb_kernel(
        const _Float16* __restrict__ Ah, const _Float16* __restrict__ Al,
        const _Float16* __restrict__ Bh, const _Float16* __restrict__ Bl,
        const float* __restrict__ bias,
        _Float16* __restrict__ Ph, _Float16* __restrict__ Pl,
        int Mpad, int M, int K) {
    const int Nn = 64;
    __shared__ _Float16 Bs[2][4][64][8];   // 8 KB per kt tile
    __shared__ _Float16 stH[4][16][72];
    __shared__ _Float16 stL[4][16][72];
    int tid = threadIdx.x;
    int wv = tid >> 6, lane = tid & 63;
    int m16 = lane & 15, quad = lane >> 4;
    int row0 = blockIdx.x * 128 + wv * 32;

    floatx4 acc[2][4];
#pragma unroll
    for (int t = 0; t < 2; t++)
#pragma unroll
        for (int c = 0; c < 4; c++)
#pragma unroll
            for (int i = 0; i < 4; i++) acc[t][c][i] = 0.f;

    size_t aoff = ((size_t)quad * Mpad + row0 + m16) * 8;
    size_t kqbase = 0;
    const size_t aStep = (size_t)Mpad * 32;
    const size_t bStep = (size_t)Nn * 32;

    for (int kt = 0; kt < K; kt += 32) {
        h8_t ah0 = *reinterpret_cast<const h8_t*>(Ah + aoff);
        h8_t ah1 = *reinterpret_cast<const h8_t*>(Ah + aoff + 128);
        h8_t al0 = *reinterpret_cast<const h8_t*>(Al + aoff);
        h8_t al1 = *reinterpret_cast<const h8_t*>(Al + aoff + 128);
        // stage B tile: 512 chunks of 16 B (2 planes x 4 kq x 64 cols)
#pragma unroll
        for (int cc = 0; cc < 2; cc++) {
            int c = tid + cc * 256;
            int plane = c >> 8, rem = c & 255, q = rem >> 6, col = rem & 63;
            const _Float16* srcp = (plane ? Bl : Bh) + kqbase + ((size_t)q * Nn + col) * 8;
            *reinterpret_cast<h8_t*>(&Bs[plane][q][col][0]) = *reinterpret_cast<const h8_t*>(srcp);
        }
        __syncthreads();
#pragma unroll
        for (int c = 0; c < 4; c++) {
            h8_t bh = *reinterpret_cast<const h8_t*>(&Bs[0][quad][c * 16 + m16][0]);
            h8_t bl = *reinterpret_cast<const h8_t*>(&Bs[1][quad][c * 16 + m16][0]);
            acc[0][c] = __builtin_amdgcn_mfma_f32_16x16x32_f16(ah0, bh, acc[0][c], 0, 0, 0);
            acc[1][c] = __builtin_amdgcn_mfma_f32_16x16x32_f16(ah1, bh, acc[1][c], 0, 0, 0);
            acc[0][c] = __builtin_amdgcn_mfma_f32_16x16x32_f16(ah0, bl, acc[0][c], 0, 0, 0);
            acc[1][c] = __builtin_amdgcn_mfma_f32_16x16x32_f16(ah1, bl, acc[1][c], 0, 0, 0);
            acc[0][c] = __builtin_amdgcn_mfma_f32_16x16x32_f16(al0, bh, acc[0][c], 0, 0, 0);
            acc[1][c] = __builtin_amdgcn_mfma_f32_16x16x32_f16(al1, bh, acc[1][c], 0, 0, 0);
        }
        __syncthreads();
        aoff += aStep; kqbase += bStep;
    }

#pragma unroll
    for (int t = 0; t < 2; t++) {
#pragma unroll
        for (int c = 0; c < 4; c++) {
            float bv = bias[c * 16 + m16];
#pragma unroll
            for (int i = 0; i < 4; i++) {
                float v = fmaxf(acc[t][c][i] + bv, 0.f);
                _Float16 hi = (_Float16)v;
                stH[wv][quad * 4 + i][c * 16 + m16] = hi;
                stL[wv][quad * 4 + i][c * 16 + m16] = (_Float16)(v - (float)hi);
            }
        }
        __syncthreads();
        int rowChunk = row0 + t * 16;
#pragma unroll
        for (int it = 0; it < 2; it++) {
            int lid = it * 64 + lane;
            int kg = lid >> 4, rloc = lid & 15;
            h8_t vh = *reinterpret_cast<const h8_t*>(&stH[wv][rloc][kg * 8]);
            h8_t vl = *reinterpret_cast<const h8_t*>(&stL[wv][rloc][kg * 8]);
            size_t o = ((size_t)kg * Mpad + rowChunk + rloc) * 8;
            *reinterpret_cast<h8_t*>(Ph + o) = vh;
            *reinterpret_cast<h8_t*>(Pl + o) = vl;
        }
        __syncthreads();
    }
}

// ---------------- GAT GEMM (Nn=256) + fused alphas; B staged in LDS ----------------
template <int TAG>
__global__ __launch_bounds__(256) void gemm_gat_kernel(
        const _Float16* __restrict__ Ah, const _Float16* __restrict__ Al,
        const _Float16* __restrict__ Bh, const _Float16* __restrict__ Bl,
        const float* __restrict__ a_src, const float* __restrict__ a_dst,
        _Float16* __restrict__ hOut, float* __restrict__ aS, float* __restrict__ aD,
        int Mpad, int M, int K) {
    const int Nn = 256;
    __shared__ _Float16 Bs[2][4][128][8];  // 16 KB per kt tile
    __shared__ _Float16 st[4][16][136];
    int tid = threadIdx.x;
    int wv = tid >> 6, lane = tid & 63;
    int m16 = lane & 15, quad = lane >> 4;
    int row0 = blockIdx.x * 128 + wv * 32;
    int colBase = blockIdx.y * 128;

    floatx4 acc[2][8];
#pragma unroll
    for (int t = 0; t < 2; t++)
#pragma unroll
        for (int c = 0; c < 8; c++)
#pragma unroll
            for (int i = 0; i < 4; i++) acc[t][c][i] = 0.f;

    size_t aoff = ((size_t)quad * Mpad + row0 + m16) * 8;
    size_t kqbase = (size_t)colBase * 8;
    const size_t aStep = (size_t)Mpad * 32;
    const size_t bStep = (size_t)Nn * 32;

    for (int kt = 0; kt < K; kt += 32) {
        h8_t ah0 = *reinterpret_cast<const h8_t*>(Ah + aoff);
        h8_t ah1 = *reinterpret_cast<const h8_t*>(Ah + aoff + 128);
        h8_t al0 = *reinterpret_cast<const h8_t*>(Al + aoff);
        h8_t al1 = *reinterpret_cast<const h8_t*>(Al + aoff + 128);
        // stage B tile: 1024 chunks of 16 B (2 planes x 4 kq x 128 cols)
#pragma unroll
        for (int cc = 0; cc < 4; cc++) {
            int c = tid + cc * 256;
            int plane = c >> 9, rem = c & 511, q = rem >> 7, col = rem & 127;
            const _Float16* srcp = (plane ? Bl : Bh) + kqbase + ((size_t)q * Nn + col) * 8;
            *reinterpret_cast<h8_t*>(&Bs[plane][q][col][0]) = *reinterpret_cast<const h8_t*>(srcp);
        }
        __syncthreads();
#pragma unroll
        for (int c = 0; c < 8; c++) {
            h8_t bh = *reinterpret_cast<const h8_t*>(&Bs[0][quad][c * 16 + m16][0]);
            h8_t bl = *reinterpret_cast<const h8_t*>(&Bs[1][quad][c * 16 + m16][0]);
            acc[0][c] = __builtin_amdgcn_mfma_f32_16x16x32_f16(ah0, bh, acc[0][c], 0, 0, 0);
            acc[1][c] = __builtin_amdgcn_mfma_f32_16x16x32_f16(ah1, bh, acc[1][c], 0, 0, 0);
            acc[0][c] = __builtin_amdgcn_mfma_f32_16x16x32_f16(ah0, bl, acc[0][c], 0, 0, 0);
            acc[1][c] = __builtin_amdgcn_mfma_f32_16x16x32_f16(ah1, bl, acc[1][c], 0, 0, 0);
            acc[0][c] = __builtin_amdgcn_mfma_f32_16x16x32_f16(al0, bh, acc[0][c], 0, 0, 0);
            acc[1][c] = __builtin_amdgcn_mfma_f32_16x16x32_f16(al1, bh, acc[1][c], 0, 0, 0);
        }
        __syncthreads();
        aoff += aStep; kqbase += bStep;
    }

    float asv[8], adv[8];
#pragma unroll
    for (int c = 0; c < 8; c++) {
        asv[c] = a_src[colBase + c * 16 + m16];
        adv[c] = a_dst[colBase + c * 16 + m16];
    }
    int hb = colBase >> 6;
#pragma unroll
    for (int t = 0; t < 2; t++) {
#pragma unroll
        for (int i = 0; i < 4; i++) {
            int r = row0 + t * 16 + quad * 4 + i;
            float s0 = 0.f, d0 = 0.f, s1 = 0.f, d1 = 0.f;
#pragma unroll
            for (int c = 0; c < 8; c++) {
                float v = acc[t][c][i];
                if (c < 4) { s0 += v * asv[c]; d0 += v * adv[c]; }
                else       { s1 += v * asv[c]; d1 += v * adv[c]; }
            }
#pragma unroll
            for (int off = 1; off < 16; off <<= 1) {
                s0 += __shfl_xor(s0, off);
                d0 += __shfl_xor(d0, off);
                s1 += __shfl_xor(s1, off);
                d1 += __shfl_xor(d1, off);
            }
            if (m16 == 0 && r < M) {
                aS[r * 4 + hb] = s0;     aD[r * 4 + hb] = d0;
                aS[r * 4 + hb + 1] = s1; aD[r * 4 + hb + 1] = d1;
            }
        }
    }

#pragma unroll
    for (int t = 0; t < 2; t++) {
#pragma unroll
        for (int c = 0; c < 8; c++)
#pragma unroll
            for (int i = 0; i < 4; i++)
                st[wv][quad * 4 + i][c * 16 + m16] = (_Float16)acc[t][c][i];
        __syncthreads();
        int rowChunk = row0 + t * 16;
#pragma unroll
        for (int it = 0; it < 4; it++) {
            int lid = it * 64 + lane;
            int rloc = lid >> 4, u = lid & 15;
            h8_t v = *reinterpret_cast<const h8_t*>(&st[wv][rloc][u * 8]);
            *reinterpret_cast<h8_t*>(hOut + (size_t)(rowChunk + rloc) * 256 + colBase + u * 8) = v;
        }
        __syncthreads();
    }
}

// ---------------- layer-2 GEMM (Nn=64) + fused alphas; B staged in LDS ----------------
__global__ __launch_bounds__(256) void gemm_l2_kernel(
        const _Float16* __restrict__ Ah, const _Float16* __restrict__ Al,
        const _Float16* __restrict__ Bh, const _Float16* __restrict__ Bl,
        const float* __restrict__ a_src, const float* __restrict__ a_dst,
        _Float16* __restrict__ hOut, float* __restrict__ aS, float* __restrict__ aD,
        int Mpad, int M, int K) {
    const int Nn = 64;
    __shared__ _Float16 Bs[2][4][64][8];
    __shared__ _Float16 st[4][16][72];
    int tid = threadIdx.x;
    int wv = tid >> 6, lane = tid & 63;
    int m16 = lane & 15, quad = lane >> 4;
    int row0 = blockIdx.x * 128 + wv * 32;

    floatx4 acc[2][4];
#pragma unroll
    for (int t = 0; t < 2; t++)
#pragma unroll
        for (int c = 0; c < 4; c++)
#pragma unroll
            for (int i = 0; i < 4; i++) acc[t][c][i] = 0.f;

    size_t aoff = ((size_t)quad * Mpad + row0 + m16) * 8;
    size_t kqbase = 0;
    const size_t aStep = (size_t)Mpad * 32;
    const size_t bStep = (size_t)Nn * 32;

    for (int kt = 0; kt < K; kt += 32) {
        h8_t ah0 = *reinterpret_cast<const h8_t*>(Ah + aoff);
        h8_t ah1 = *reinterpret_cast<const h8_t*>(Ah + aoff + 128);
        h8_t al0 = *reinterpret_cast<const h8_t*>(Al + aoff);
        h8_t al1 = *reinterpret_cast<const h8_t*>(Al + aoff + 128);
#pragma unroll
        for (int cc = 0; cc < 2; cc++) {
            int c = tid + cc * 256;
            int plane = c >> 8, rem = c & 255, q = rem >> 6, col = rem & 63;
            const _Float16* srcp = (plane ? Bl : Bh) + kqbase + ((size_t)q * Nn + col) * 8;
            *reinterpret_cast<h8_t*>(&Bs[plane][q][col][0]) = *reinterpret_cast<const h8_t*>(srcp);
        }
        __syncthreads();
#pragma unroll
        for (int c = 0; c < 4; c++) {
            h8_t bh = *reinterpret_cast<const h8_t*>(&Bs[0][quad][c * 16 + m16][0]);
            h8_t bl = *reinterpret_cast<const h8_t*>(&Bs[1][quad][c * 16 + m16][0]);
            acc[0][c] = __builtin_amdgcn_mfma_f32_16x16x32_f16(ah0, bh, acc[0][c], 0, 0, 0);
            acc[1][c] = __builtin_amdgcn_mfma_f32_16x16x32_f16(ah1, bh, acc[1][c], 0, 0, 0);
            acc[0][c] = __builtin_amdgcn_mfma_f32_16x16x32_f16(ah0, bl, acc[0][c], 0, 0, 0);
            acc[1][c] = __builtin_amdgcn_mfma_f32_16x16x32_f16(ah1, bl, acc[1][c], 0, 0, 0);
            acc[0][c] = __builtin_amdgcn_mfma_f32_16x16x32_f16(al0, bh, acc[0][c], 0, 0, 0);
            acc[1][c] = __builtin_amdgcn_mfma_f32_16x16x32_f16(al1, bh, acc[1][c], 0, 0, 0);
        }
        __syncthreads();
        aoff += aStep; kqbase += bStep;
    }

    float asv[4], adv[4];
#pragma unroll
    for (int c = 0; c < 4; c++) {
        asv[c] = a_src[c * 16 + m16];
        adv[c] = a_dst[c * 16 + m16];
    }
#pragma unroll
    for (int t = 0; t < 2; t++) {
#pragma unroll
        for (int i = 0; i < 4; i++) {
            int r = row0 + t * 16 + quad * 4 + i;
            float s0 = 0.f, d0 = 0.f;
#pragma unroll
            for (int c = 0; c < 4; c++) {
                float v = acc[t][c][i];
                s0 += v * asv[c]; d0 += v * adv[c];
            }
#pragma unroll
            for (int off = 1; off < 16; off <<= 1) {
                s0 += __shfl_xor(s0, off);
                d0 += __shfl_xor(d0, off);
            }
            if (m16 == 0 && r < M) { aS[r] = s0; aD[r] = d0; }
        }
    }

#pragma unroll
    for (int t = 0; t < 2; t++) {
#pragma unroll
        for (int c = 0; c < 4; c++)
#pragma unroll
            for (int i = 0; i < 4; i++)
                st[wv][quad * 4 + i][c * 16 + m16] = (_Float16)acc[t][c][i];
        __syncthreads();
        int rowChunk = row0 + t * 16;
#pragma unroll
        for (int it = 0; it < 2; it++) {
            int lid = it * 64 + lane;
            int rloc = lid >> 3, u = lid & 7;
            h8_t v = *reinterpret_cast<const h8_t*>(&st[wv][rloc][u * 8]);
            *reinterpret_cast<h8_t*>(hOut + (size_t)(rowChunk + rloc) * 64 + u * 8) = v;
        }
        __syncthreads();
    }
}

// ---------------- aggregation H=4: single-pass, conflict-free LDS staging ----------------
template <int TAG>
__global__ __launch_bounds__(256) void aggregate4_kernel(const _Float16* __restrict__ hsrc,
                                                         const float* __restrict__ alpha_s,
                                                         const float* __restrict__ alpha_d,
                                                         const int* __restrict__ row_ptr,
                                                         const int* __restrict__ csr_src,
                                                         const float* __restrict__ bias,
                                                         _Float16* __restrict__ outH,
                                                         _Float16* __restrict__ outL,
                                                         int N, int Mpad) {
    __shared__ float wlds[4][64][4];
    __shared__ int   slds[4][64];
    int wv = threadIdx.x >> 6, lane = threadIdx.x & 63;
    int node = blockIdx.x * 4 + wv;
    if (node >= N) return;
    int rs = row_ptr[node], re = row_ptr[node + 1];
    int head = lane >> 4, c4 = (lane & 15) * 4;
    float4 ad4 = *(const float4*)(alpha_d + (size_t)node * 4);

    float den0 = 0.f, den1 = 0.f, den2 = 0.f, den3 = 0.f;
    float a0 = 0.f, a1 = 0.f, a2 = 0.f, a3 = 0.f;
    float* wp = &wlds[wv][0][0];
    int*   sp = &slds[wv][0];
    const char* hbase = (const char*)hsrc;
    int hoff = (head << 7) + c4 * 2;
    for (int base = rs; base < re; base += 64) {
        int i = base + lane;
        float w0 = 0.f, w1 = 0.f, w2 = 0.f, w3 = 0.f;
        int off = 0;
        if (i < re) {
            int s = csr_src[i];
            float4 as = *(const float4*)(alpha_s + (size_t)s * 4);
            w0 = __expf(fminf(leaky(as.x + ad4.x), 60.f));
            w1 = __expf(fminf(leaky(as.y + ad4.y), 60.f));
            w2 = __expf(fminf(leaky(as.z + ad4.z), 60.f));
            w3 = __expf(fminf(leaky(as.w + ad4.w), 60.f));
            off = s * 512;
        }
        den0 += w0; den1 += w1; den2 += w2; den3 += w3;
        sp[lane] = off;
        *(float4*)(wp + lane * 4) = make_float4(w0, w1, w2, w3);
        int cnt = min(64, re - base);
#pragma unroll 4
        for (int j = 0; j < cnt; j++) {
            int o2 = sp[j];
            float w = wp[j * 4 + head];
            h4_t hv = *reinterpret_cast<const h4_t*>(hbase + o2 + hoff);
            a0 += w * (float)hv[0]; a1 += w * (float)hv[1];
            a2 += w * (float)hv[2]; a3 += w * (float)hv[3];
        }
    }
#pragma unroll
    for (int off = 32; off >= 1; off >>= 1) {
        den0 += __shfl_xor(den0, off);
        den1 += __shfl_xor(den1, off);
        den2 += __shfl_xor(den2, off);
        den3 += __shfl_xor(den3, off);
    }
    float den = (head & 2) ? ((head & 1) ? den3 : den2) : ((head & 1) ? den1 : den0);
    float inv = 1.f / (den + 1e-16f);
    int cbase = (head << 6) + c4;
    float v0 = fmaxf(a0 * inv + bias[cbase + 0], 0.f);
    float v1 = fmaxf(a1 * inv + bias[cbase + 1], 0.f);
    float v2 = fmaxf(a2 * inv + bias[cbase + 2], 0.f);
    float v3 = fmaxf(a3 * inv + bias[cbase + 3], 0.f);
    h4_t hv, lv;
    _Float16 h;
    h = (_Float16)v0; hv[0] = h; lv[0] = (_Float16)(v0 - (float)h);
    h = (_Float16)v1; hv[1] = h; lv[1] = (_Float16)(v1 - (float)h);
    h = (_Float16)v2; hv[2] = h; lv[2] = (_Float16)(v2 - (float)h);
    h = (_Float16)v3; hv[3] = h; lv[3] = (_Float16)(v3 - (float)h);
    size_t o = ((size_t)(cbase >> 3) * Mpad + node) * 8 + (cbase & 7);
    *reinterpret_cast<h4_t*>(outH + o) = hv;
    *reinterpret_cast<h4_t*>(outL + o) = lv;
}

// ---------------- aggregation H=1: single-pass, 4 edges in flight ----------------
__global__ __launch_bounds__(256) void aggregate1_kernel(const _Float16* __restrict__ hsrc,
                                                         const float* __restrict__ alpha_s,
                                                         const float* __restrict__ alpha_d,
                                                         const int* __restrict__ row_ptr,
                                                         const int* __restrict__ csr_src,
                                                         const float* __restrict__ bias,
                                                         float* __restrict__ out, int N) {
    __shared__ float wlds[4][64];
    __shared__ int   slds[4][64];
    int wv = threadIdx.x >> 6, lane = threadIdx.x & 63;
    int node = blockIdx.x * 4 + wv;
    if (node >= N) return;
    int rs = row_ptr[node], re = row_ptr[node + 1];
    float ad = alpha_d[node];
    int e4 = lane >> 4, c4 = (lane & 15) * 4;
    int cbyte = c4 * 2;

    float den = 0.f;
    float ax = 0.f, ay = 0.f, az = 0.f, aw = 0.f;
    const char* hbase = (const char*)hsrc;
    float* wp = &wlds[wv][0];
    int*   sp = &slds[wv][0];
    for (int base = rs; base < re; base += 64) {
        int i = base + lane;
        float w = 0.f;
        int off = 0;
        if (i < re) {
            int s = csr_src[i];
            w = __expf(fminf(leaky(alpha_s[s] + ad), 60.f));
            off = s * 128;
        }
        den += w;
        sp[lane] = off;
        wp[lane] = w;
        int cnt = min(64, re - base);
#pragma unroll 4
        for (int j = e4; j < cnt; j += 4) {
            float wj = wp[j];
            h4_t hv = *reinterpret_cast<const h4_t*>(hbase + sp[j] + cbyte);
            ax += wj * (float)hv[0]; ay += wj * (float)hv[1];
            az += wj * (float)hv[2]; aw += wj * (float)hv[3];
        }
    }
    ax += __shfl_xor(ax, 16); ax += __shfl_xor(ax, 32);
    ay += __shfl_xor(ay, 16); ay += __shfl_xor(ay, 32);
    az += __shfl_xor(az, 16); az += __shfl_xor(az, 32);
    aw += __shfl_xor(aw, 16); aw += __shfl_xor(aw, 32);
#pragma unroll
    for (int off = 32; off >= 1; off >>= 1) den += __shfl_xor(den, off);
    if (e4 == 0) {
        float inv = 1.f / (den + 1e-16f);
        float4 o;
        o.x = ax * inv + bias[c4 + 0];
        o.y = ay * inv + bias[c4 + 1];
        o.z = az * inv + bias[c4 + 2];
        o.w = aw * inv + bias[c4 + 3];
        *(float4*)(out + (size_t)node * 64 + c4) = o;
    }
}

// ---------------- head MLP ----------------
__global__ __launch_bounds__(256) void mlp_head_kernel(const float* __restrict__ hin,
                                                       const float* __restrict__ Wo1,
                                                       const float* __restrict__ bo1,
                                                       const float* __restrict__ Wo2,
                                                       const float* __restrict__ bo2,
                                                       float* __restrict__ out, int N) {
    __shared__ float w1[64 * 32];
    __shared__ float w2[32];
    __shared__ float b1s[32];
    int tid = threadIdx.x;
#pragma unroll
    for (int i = 0; i < 8; i++) w1[tid + i * 256] = Wo1[tid + i * 256];
    if (tid < 32) { w2[tid] = Wo2[tid]; b1s[tid] = bo1[tid]; }
    __syncthreads();
    int n = blockIdx.x * blockDim.x + tid;
    if (n >= N) return;
    float hrow[64];
    const float* pr = hin + (size_t)n * 64;
#pragma unroll
    for (int i = 0; i < 64; i++) hrow[i] = pr[i];
    float sum = 0.f;
    for (int j = 0; j < 32; j++) {
        float a = b1s[j];
#pragma unroll
        for (int k = 0; k < 64; k++) a += hrow[k] * w1[k * 32 + j];
        a = fmaxf(a, 0.f);
        sum += a * w2[j];
    }
    out[n] = sum + bo2[0];
}

// ---------------- launch ----------------
extern "C" void kernel_launch(void* const* d_in, const int* in_sizes, int n_in,
                              void* d_out, int out_size, void* d_ws, size_t ws_size,
                              hipStream_t stream) {
    const float* x     = (const float*)d_in[0];
    const float* W_emb = (const float*)d_in[1];
    const float* b_emb = (const float*)d_in[2];
    const float* W0    = (const float*)d_in[3];
    const float* as0   = (const float*)d_in[4];
    const float* ad0   = (const float*)d_in[5];
    const float* b0    = (const float*)d_in[6];
    const float* W1    = (const float*)d_in[7];
    const float* as1   = (const float*)d_in[8];
    const float* ad1   = (const float*)d_in[9];
    const float* b1    = (const float*)d_in[10];
    const float* W2    = (const float*)d_in[11];
    const float* as2   = (const float*)d_in[12];
    const float* ad2   = (const float*)d_in[13];
    const float* b2    = (const float*)d_in[14];
    const float* Wo1   = (const float*)d_in[15];
    const float* bo1   = (const float*)d_in[16];
    const float* Wo2   = (const float*)d_in[17];
    const float* bo2   = (const float*)d_in[18];
    const int* eidx    = (const int*)d_in[19];

    const int N = in_sizes[0] / 128;
    const int E = in_sizes[19] / 2;
    const int* esrc = eidx;
    const int* edst = eidx + E;
    const int gmB  = (N + 127) / 128;
    const int Mpad = gmB * 128;
    const int nb   = (N + 255) / 256;

    char* w = (char*)d_ws;
    auto alloc = [&](size_t bytes) {
        char* p = w;
        w += (bytes + 255) & ~(size_t)255;
        return (void*)p;
    };
    _Float16* hOut = (_Float16*)alloc((size_t)Mpad * 256 * 2);
    _Float16* PHh  = (_Float16*)alloc((size_t)Mpad * 256 * 2);
    _Float16* PHl  = (_Float16*)alloc((size_t)Mpad * 256 * 2);
    _Float16* XPh  = (_Float16*)alloc((size_t)Mpad * 128 * 2);
    _Float16* XPl  = (_Float16*)alloc((size_t)Mpad * 128 * 2);
    float* bufA    = (float*)alloc((size_t)Mpad * 64 * 4);
    float* aS      = (float*)alloc((size_t)N * 4 * 4);
    float* aD      = (float*)alloc((size_t)N * 4 * 4);
    int*   row_ptr = (int*)alloc((size_t)(N + 1) * 4);
    int*   cursor  = (int*)alloc((size_t)N * 4);
    int*   cnt     = (int*)alloc((size_t)N * 4);
    int*   bsum    = (int*)alloc((size_t)nb * 4);
    int*   csr     = (int*)alloc((size_t)(E + N) * 4);
    _Float16* WeH  = (_Float16*)alloc(128 * 64 * 2);
    _Float16* WeL  = (_Float16*)alloc(128 * 64 * 2);
    _Float16* W0H  = (_Float16*)alloc(64 * 256 * 2);
    _Float16* W0L  = (_Float16*)alloc(64 * 256 * 2);
    _Float16* W1H  = (_Float16*)alloc(256 * 256 * 2);
    _Float16* W1L  = (_Float16*)alloc(256 * 256 * 2);
    _Float16* W2H  = (_Float16*)alloc(256 * 64 * 2);
    _Float16* W2L  = (_Float16*)alloc(256 * 64 * 2);

    // CSR build (multi-block scan)
    hipMemsetAsync(cnt, 0, (size_t)N * 4, stream);
    hist_kernel<<<(E + 255) / 256, 256, 0, stream>>>(edst, E, cnt);
    blocksum_kernel<<<nb, 256, 0, stream>>>(cnt, N, bsum);
    scanbsum_kernel<<<1, 256, 0, stream>>>(bsum, nb, row_ptr + N);
    rowptr_kernel<<<nb, 256, 0, stream>>>(cnt, bsum, N, row_ptr, cursor);
    scatter_kernel<<<(E + N + 255) / 256, 256, 0, stream>>>(esrc, edst, E, N, cursor, csr);

    // weight planes (fused single launch)
    prep_weights_all<<<dim3(256, 4), 256, 0, stream>>>(W_emb, W0, W1, W2,
                                                       WeH, WeL, W0H, W0L, W1H, W1L, W2H, W2L);

    int gn4 = (N + 3) / 4;

    // embedding
    prep_act_kernel<<<((size_t)Mpad * 16 + 255) / 256, 256, 0, stream>>>(x, XPh, XPl, N, Mpad, 16, 128);
    gemm_emb_kernel<<<dim3(gmB, 1), 256, 0, stream>>>(XPh, XPl, WeH, WeL, b_emb, PHh, PHl, Mpad, N, 128);

    // GAT layer 0
    gemm_gat_kernel<0><<<dim3(gmB, 2), 256, 0, stream>>>(PHh, PHl, W0H, W0L, as0, ad0, hOut, aS, aD, Mpad, N, 64);
    aggregate4_kernel<0><<<gn4, 256, 0, stream>>>(hOut, aS, aD, row_ptr, csr, b0, PHh, PHl, N, Mpad);

    // GAT layer 1
    gemm_gat_kernel<1><<<dim3(gmB, 2), 256, 0, stream>>>(PHh, PHl, W1H, W1L, as1, ad1, hOut, aS, aD, Mpad, N, 256);
    aggregate4_kernel<1><<<gn4, 256, 0, stream>>>(hOut, aS, aD, row_ptr, csr, b1, PHh, PHl, N, Mpad);

    // GAT layer 2 (1 head, no relu)
    gemm_l2_kernel<<<dim3(gmB, 1), 256, 0, stream>>>(PHh, PHl, W2H, W2L, as2, ad2, hOut, aS, aD, Mpad, N, 256);
    aggregate1_kernel<<<gn4, 256, 0, stream>>>(hOut, aS, aD, row_ptr, csr, b2, bufA, N);

    // head MLP -> out [N,1] fp32
    mlp_head_kernel<<<(N + 255) / 256, 256, 0, stream>>>(bufA, Wo1, bo1, Wo2, bo2, (float*)d_out, N);
}

// Round 13
// 488.473 us; speedup vs baseline: 1.6349x; 1.0098x over previous
//
#include <hip/hip_runtime.h>

typedef _Float16 h8_t __attribute__((ext_vector_type(8)));
typedef _Float16 h4_t __attribute__((ext_vector_type(4)));
typedef float floatx4 __attribute__((ext_vector_type(4)));

__device__ __forceinline__ float leaky(float v) { return v >= 0.f ? v : 0.2f * v; }

// ---------------- CSR build ----------------
__global__ void hist_kernel(const int* __restrict__ dst, int E, int* __restrict__ cnt) {
    int e = blockIdx.x * blockDim.x + threadIdx.x;
    if (e < E) atomicAdd(&cnt[dst[e]], 1);
}

__global__ __launch_bounds__(256) void blocksum_kernel(const int* __restrict__ cnt, int N,
                                                       int* __restrict__ bsum) {
    __shared__ int red[256];
    int tid = threadIdx.x;
    int idx = blockIdx.x * 256 + tid;
    red[tid] = idx < N ? cnt[idx] + 1 : 0;
    __syncthreads();
#pragma unroll
    for (int off = 128; off >= 1; off >>= 1) {
        if (tid < off) red[tid] += red[tid + off];
        __syncthreads();
    }
    if (tid == 0) bsum[blockIdx.x] = red[0];
}

__global__ __launch_bounds__(256) void scanbsum_kernel(int* __restrict__ bsum, int nb,
                                                       int* __restrict__ total) {
    __shared__ int part[256];
    int tid = threadIdx.x;
    int per = (nb + 255) / 256;
    int s0 = tid * per, s1 = min(s0 + per, nb);
    int s = 0;
    for (int i = s0; i < s1; i++) s += bsum[i];
    part[tid] = s;
    __syncthreads();
    for (int off = 1; off < 256; off <<= 1) {
        int v = (tid >= off) ? part[tid - off] : 0;
        __syncthreads();
        part[tid] += v;
        __syncthreads();
    }
    int base = (tid == 0) ? 0 : part[tid - 1];
    for (int i = s0; i < s1; i++) {
        int v = bsum[i];
        bsum[i] = base;
        base += v;
    }
    if (tid == 255) *total = part[255];
}

__global__ __launch_bounds__(256) void rowptr_kernel(const int* __restrict__ cnt,
                                                     const int* __restrict__ bsum, int N,
                                                     int* __restrict__ row_ptr,
                                                     int* __restrict__ cursor) {
    __shared__ int lds[256];
    int tid = threadIdx.x;
    int idx = blockIdx.x * 256 + tid;
    int v = idx < N ? cnt[idx] + 1 : 0;
    lds[tid] = v;
    __syncthreads();
    for (int off = 1; off < 256; off <<= 1) {
        int t = (tid >= off) ? lds[tid - off] : 0;
        __syncthreads();
        lds[tid] += t;
        __syncthreads();
    }
    if (idx < N) {
        int p = bsum[blockIdx.x] + lds[tid] - v;
        row_ptr[idx] = p;
        cursor[idx] = p;
    }
}

__global__ void scatter_kernel(const int* __restrict__ src, const int* __restrict__ dst,
                               int E, int N, int* __restrict__ cursor, int* __restrict__ csr_src) {
    int e = blockIdx.x * blockDim.x + threadIdx.x;
    if (e >= E + N) return;
    int s, d;
    if (e < E) { s = src[e]; d = dst[e]; }
    else       { s = e - E;  d = s; }
    int pos = atomicAdd(&cursor[d], 1);
    csr_src[pos] = s;
}

// ---------------- fused weight prep ----------------
__global__ void prep_weights_all(const float* __restrict__ W_emb, const float* __restrict__ W0,
                                 const float* __restrict__ W1, const float* __restrict__ W2,
                                 _Float16* __restrict__ WeH, _Float16* __restrict__ WeL,
                                 _Float16* __restrict__ W0H, _Float16* __restrict__ W0L,
                                 _Float16* __restrict__ W1H, _Float16* __restrict__ W1L,
                                 _Float16* __restrict__ W2H, _Float16* __restrict__ W2L) {
    int which = blockIdx.y;
    const float* W;
    _Float16 *Wh, *Wl;
    int K, N;
    if (which == 0)      { W = W_emb; Wh = WeH; Wl = WeL; K = 128; N = 64; }
    else if (which == 1) { W = W0;    Wh = W0H; Wl = W0L; K = 64;  N = 256; }
    else if (which == 2) { W = W1;    Wh = W1H; Wl = W1L; K = 256; N = 256; }
    else                 { W = W2;    Wh = W2H; Wl = W2L; K = 256; N = 64; }
    int idx = blockIdx.x * blockDim.x + threadIdx.x;
    if (idx >= K * N) return;
    int k = idx / N, n = idx % N;
    float v = W[idx];
    _Float16 hi = (_Float16)v;
    _Float16 lo = (_Float16)(v - (float)hi);
    size_t o = ((size_t)(k >> 3) * N + n) * 8 + (k & 7);
    Wh[o] = hi; Wl[o] = lo;
}

// ---------------- activation prep ----------------
__global__ void prep_act_kernel(const float* __restrict__ X,
                                _Float16* __restrict__ Ph, _Float16* __restrict__ Pl,
                                int M, int Mpad, int Kg, int K) {
    int idx = blockIdx.x * blockDim.x + threadIdx.x;
    if (idx >= Mpad * Kg) return;
    int row = idx / Kg, kg = idx - row * Kg;
    float vs[8] = {0.f, 0.f, 0.f, 0.f, 0.f, 0.f, 0.f, 0.f};
    if (row < M) {
        const float4* p = (const float4*)(X + (size_t)row * K + kg * 8);
        float4 a = p[0], b = p[1];
        vs[0] = a.x; vs[1] = a.y; vs[2] = a.z; vs[3] = a.w;
        vs[4] = b.x; vs[5] = b.y; vs[6] = b.z; vs[7] = b.w;
    }
    h8_t hh, hl;
#pragma unroll
    for (int j = 0; j < 8; j++) {
        _Float16 hi = (_Float16)vs[j];
        hh[j] = hi;
        hl[j] = (_Float16)(vs[j] - (float)hi);
    }
    size_t o = ((size_t)kg * Mpad + row) * 8;
    *reinterpret_cast<h8_t*>(Ph + o) = hh;
    *reinterpret_cast<h8_t*>(Pl + o) = hl;
}

// ---------------- embedding GEMM (Nn=64) -> hi/lo planes; B staged in LDS ----------------
__global__ __launch_bounds__(256) void gemm_emb_kernel(
        const _Float16* __restrict__ Ah, const _Float16* __restrict__ Al,
        const _Float16* __restrict__ Bh, const _Float16* __restrict__ Bl,
        const float* __restrict__ bias,
        _Float16* __restrict__ Ph, _Float16* __restrict__ Pl,
        int Mpad, int M, int K) {
    const int Nn = 64;
    __shared__ _Float16 Bs[2][4][64][8];
    __shared__ _Float16 stH[4][16][72];
    __shared__ _Float16 stL[4][16][72];
    int tid = threadIdx.x;
    int wv = tid >> 6, lane = tid & 63;
    int m16 = lane & 15, quad = lane >> 4;
    int row0 = blockIdx.x * 128 + wv * 32;

    floatx4 acc[2][4];
#pragma unroll
    for (int t = 0; t < 2; t++)
#pragma unroll
        for (int c = 0; c < 4; c++)
#pragma unroll
            for (int i = 0; i < 4; i++) acc[t][c][i] = 0.f;

    size_t aoff = ((size_t)quad * Mpad + row0 + m16) * 8;
    size_t kqbase = 0;
    const size_t aStep = (size_t)Mpad * 32;
    const size_t bStep = (size_t)Nn * 32;

    for (int kt = 0; kt < K; kt += 32) {
        h8_t ah0 = *reinterpret_cast<const h8_t*>(Ah + aoff);
        h8_t ah1 = *reinterpret_cast<const h8_t*>(Ah + aoff + 128);
        h8_t al0 = *reinterpret_cast<const h8_t*>(Al + aoff);
        h8_t al1 = *reinterpret_cast<const h8_t*>(Al + aoff + 128);
#pragma unroll
        for (int cc = 0; cc < 2; cc++) {
            int c = tid + cc * 256;
            int plane = c >> 8, rem = c & 255, q = rem >> 6, col = rem & 63;
            const _Float16* srcp = (plane ? Bl : Bh) + kqbase + ((size_t)q * Nn + col) * 8;
            *reinterpret_cast<h8_t*>(&Bs[plane][q][col][0]) = *reinterpret_cast<const h8_t*>(srcp);
        }
        __syncthreads();
#pragma unroll
        for (int c = 0; c < 4; c++) {
            h8_t bh = *reinterpret_cast<const h8_t*>(&Bs[0][quad][c * 16 + m16][0]);
            h8_t bl = *reinterpret_cast<const h8_t*>(&Bs[1][quad][c * 16 + m16][0]);
            acc[0][c] = __builtin_amdgcn_mfma_f32_16x16x32_f16(ah0, bh, acc[0][c], 0, 0, 0);
            acc[1][c] = __builtin_amdgcn_mfma_f32_16x16x32_f16(ah1, bh, acc[1][c], 0, 0, 0);
            acc[0][c] = __builtin_amdgcn_mfma_f32_16x16x32_f16(ah0, bl, acc[0][c], 0, 0, 0);
            acc[1][c] = __builtin_amdgcn_mfma_f32_16x16x32_f16(ah1, bl, acc[1][c], 0, 0, 0);
            acc[0][c] = __builtin_amdgcn_mfma_f32_16x16x32_f16(al0, bh, acc[0][c], 0, 0, 0);
            acc[1][c] = __builtin_amdgcn_mfma_f32_16x16x32_f16(al1, bh, acc[1][c], 0, 0, 0);
        }
        __syncthreads();
        aoff += aStep; kqbase += bStep;
    }

#pragma unroll
    for (int t = 0; t < 2; t++) {
#pragma unroll
        for (int c = 0; c < 4; c++) {
            float bv = bias[c * 16 + m16];
#pragma unroll
            for (int i = 0; i < 4; i++) {
                float v = fmaxf(acc[t][c][i] + bv, 0.f);
                _Float16 hi = (_Float16)v;
                stH[wv][quad * 4 + i][c * 16 + m16] = hi;
                stL[wv][quad * 4 + i][c * 16 + m16] = (_Float16)(v - (float)hi);
            }
        }
        __syncthreads();
        int rowChunk = row0 + t * 16;
#pragma unroll
        for (int it = 0; it < 2; it++) {
            int lid = it * 64 + lane;
            int kg = lid >> 4, rloc = lid & 15;
            h8_t vh = *reinterpret_cast<const h8_t*>(&stH[wv][rloc][kg * 8]);
            h8_t vl = *reinterpret_cast<const h8_t*>(&stL[wv][rloc][kg * 8]);
            size_t o = ((size_t)kg * Mpad + rowChunk + rloc) * 8;
            *reinterpret_cast<h8_t*>(Ph + o) = vh;
            *reinterpret_cast<h8_t*>(Pl + o) = vl;
        }
        __syncthreads();
    }
}

// ---------------- GAT GEMM (Nn=256) + fused alphas; B staged in LDS ----------------
template <int TAG>
__global__ __launch_bounds__(256) void gemm_gat_kernel(
        const _Float16* __restrict__ Ah, const _Float16* __restrict__ Al,
        const _Float16* __restrict__ Bh, const _Float16* __restrict__ Bl,
        const float* __restrict__ a_src, const float* __restrict__ a_dst,
        _Float16* __restrict__ hOut, float* __restrict__ aS, float* __restrict__ aD,
        int Mpad, int M, int K) {
    const int Nn = 256;
    __shared__ _Float16 Bs[2][4][128][8];
    __shared__ _Float16 st[4][16][136];
    int tid = threadIdx.x;
    int wv = tid >> 6, lane = tid & 63;
    int m16 = lane & 15, quad = lane >> 4;
    int row0 = blockIdx.x * 128 + wv * 32;
    int colBase = blockIdx.y * 128;

    floatx4 acc[2][8];
#pragma unroll
    for (int t = 0; t < 2; t++)
#pragma unroll
        for (int c = 0; c < 8; c++)
#pragma unroll
            for (int i = 0; i < 4; i++) acc[t][c][i] = 0.f;

    size_t aoff = ((size_t)quad * Mpad + row0 + m16) * 8;
    size_t kqbase = (size_t)colBase * 8;
    const size_t aStep = (size_t)Mpad * 32;
    const size_t bStep = (size_t)Nn * 32;

    for (int kt = 0; kt < K; kt += 32) {
        h8_t ah0 = *reinterpret_cast<const h8_t*>(Ah + aoff);
        h8_t ah1 = *reinterpret_cast<const h8_t*>(Ah + aoff + 128);
        h8_t al0 = *reinterpret_cast<const h8_t*>(Al + aoff);
        h8_t al1 = *reinterpret_cast<const h8_t*>(Al + aoff + 128);
#pragma unroll
        for (int cc = 0; cc < 4; cc++) {
            int c = tid + cc * 256;
            int plane = c >> 9, rem = c & 511, q = rem >> 7, col = rem & 127;
            const _Float16* srcp = (plane ? Bl : Bh) + kqbase + ((size_t)q * Nn + col) * 8;
            *reinterpret_cast<h8_t*>(&Bs[plane][q][col][0]) = *reinterpret_cast<const h8_t*>(srcp);
        }
        __syncthreads();
#pragma unroll
        for (int c = 0; c < 8; c++) {
            h8_t bh = *reinterpret_cast<const h8_t*>(&Bs[0][quad][c * 16 + m16][0]);
            h8_t bl = *reinterpret_cast<const h8_t*>(&Bs[1][quad][c * 16 + m16][0]);
            acc[0][c] = __builtin_amdgcn_mfma_f32_16x16x32_f16(ah0, bh, acc[0][c], 0, 0, 0);
            acc[1][c] = __builtin_amdgcn_mfma_f32_16x16x32_f16(ah1, bh, acc[1][c], 0, 0, 0);
            acc[0][c] = __builtin_amdgcn_mfma_f32_16x16x32_f16(ah0, bl, acc[0][c], 0, 0, 0);
            acc[1][c] = __builtin_amdgcn_mfma_f32_16x16x32_f16(ah1, bl, acc[1][c], 0, 0, 0);
            acc[0][c] = __builtin_amdgcn_mfma_f32_16x16x32_f16(al0, bh, acc[0][c], 0, 0, 0);
            acc[1][c] = __builtin_amdgcn_mfma_f32_16x16x32_f16(al1, bh, acc[1][c], 0, 0, 0);
        }
        __syncthreads();
        aoff += aStep; kqbase += bStep;
    }

    float asv[8], adv[8];
#pragma unroll
    for (int c = 0; c < 8; c++) {
        asv[c] = a_src[colBase + c * 16 + m16];
        adv[c] = a_dst[colBase + c * 16 + m16];
    }
    int hb = colBase >> 6;
#pragma unroll
    for (int t = 0; t < 2; t++) {
#pragma unroll
        for (int i = 0; i < 4; i++) {
            int r = row0 + t * 16 + quad * 4 + i;
            float s0 = 0.f, d0 = 0.f, s1 = 0.f, d1 = 0.f;
#pragma unroll
            for (int c = 0; c < 8; c++) {
                float v = acc[t][c][i];
                if (c < 4) { s0 += v * asv[c]; d0 += v * adv[c]; }
                else       { s1 += v * asv[c]; d1 += v * adv[c]; }
            }
#pragma unroll
            for (int off = 1; off < 16; off <<= 1) {
                s0 += __shfl_xor(s0, off);
                d0 += __shfl_xor(d0, off);
                s1 += __shfl_xor(s1, off);
                d1 += __shfl_xor(d1, off);
            }
            if (m16 == 0 && r < M) {
                aS[r * 4 + hb] = s0;     aD[r * 4 + hb] = d0;
                aS[r * 4 + hb + 1] = s1; aD[r * 4 + hb + 1] = d1;
            }
        }
    }

#pragma unroll
    for (int t = 0; t < 2; t++) {
#pragma unroll
        for (int c = 0; c < 8; c++)
#pragma unroll
            for (int i = 0; i < 4; i++)
                st[wv][quad * 4 + i][c * 16 + m16] = (_Float16)acc[t][c][i];
        __syncthreads();
        int rowChunk = row0 + t * 16;
#pragma unroll
        for (int it = 0; it < 4; it++) {
            int lid = it * 64 + lane;
            int rloc = lid >> 4, u = lid & 15;
            h8_t v = *reinterpret_cast<const h8_t*>(&st[wv][rloc][u * 8]);
            *reinterpret_cast<h8_t*>(hOut + (size_t)(rowChunk + rloc) * 256 + colBase + u * 8) = v;
        }
        __syncthreads();
    }
}

// ---------------- layer-2 GEMM (Nn=64) + fused alphas; B staged in LDS ----------------
__global__ __launch_bounds__(256) void gemm_l2_kernel(
        const _Float16* __restrict__ Ah, const _Float16* __restrict__ Al,
        const _Float16* __restrict__ Bh, const _Float16* __restrict__ Bl,
        const float* __restrict__ a_src, const float* __restrict__ a_dst,
        _Float16* __restrict__ hOut, float* __restrict__ aS, float* __restrict__ aD,
        int Mpad, int M, int K) {
    const int Nn = 64;
    __shared__ _Float16 Bs[2][4][64][8];
    __shared__ _Float16 st[4][16][72];
    int tid = threadIdx.x;
    int wv = tid >> 6, lane = tid & 63;
    int m16 = lane & 15, quad = lane >> 4;
    int row0 = blockIdx.x * 128 + wv * 32;

    floatx4 acc[2][4];
#pragma unroll
    for (int t = 0; t < 2; t++)
#pragma unroll
        for (int c = 0; c < 4; c++)
#pragma unroll
            for (int i = 0; i < 4; i++) acc[t][c][i] = 0.f;

    size_t aoff = ((size_t)quad * Mpad + row0 + m16) * 8;
    size_t kqbase = 0;
    const size_t aStep = (size_t)Mpad * 32;
    const size_t bStep = (size_t)Nn * 32;

    for (int kt = 0; kt < K; kt += 32) {
        h8_t ah0 = *reinterpret_cast<const h8_t*>(Ah + aoff);
        h8_t ah1 = *reinterpret_cast<const h8_t*>(Ah + aoff + 128);
        h8_t al0 = *reinterpret_cast<const h8_t*>(Al + aoff);
        h8_t al1 = *reinterpret_cast<const h8_t*>(Al + aoff + 128);
#pragma unroll
        for (int cc = 0; cc < 2; cc++) {
            int c = tid + cc * 256;
            int plane = c >> 8, rem = c & 255, q = rem >> 6, col = rem & 63;
            const _Float16* srcp = (plane ? Bl : Bh) + kqbase + ((size_t)q * Nn + col) * 8;
            *reinterpret_cast<h8_t*>(&Bs[plane][q][col][0]) = *reinterpret_cast<const h8_t*>(srcp);
        }
        __syncthreads();
#pragma unroll
        for (int c = 0; c < 4; c++) {
            h8_t bh = *reinterpret_cast<const h8_t*>(&Bs[0][quad][c * 16 + m16][0]);
            h8_t bl = *reinterpret_cast<const h8_t*>(&Bs[1][quad][c * 16 + m16][0]);
            acc[0][c] = __builtin_amdgcn_mfma_f32_16x16x32_f16(ah0, bh, acc[0][c], 0, 0, 0);
            acc[1][c] = __builtin_amdgcn_mfma_f32_16x16x32_f16(ah1, bh, acc[1][c], 0, 0, 0);
            acc[0][c] = __builtin_amdgcn_mfma_f32_16x16x32_f16(ah0, bl, acc[0][c], 0, 0, 0);
            acc[1][c] = __builtin_amdgcn_mfma_f32_16x16x32_f16(ah1, bl, acc[1][c], 0, 0, 0);
            acc[0][c] = __builtin_amdgcn_mfma_f32_16x16x32_f16(al0, bh, acc[0][c], 0, 0, 0);
            acc[1][c] = __builtin_amdgcn_mfma_f32_16x16x32_f16(al1, bh, acc[1][c], 0, 0, 0);
        }
        __syncthreads();
        aoff += aStep; kqbase += bStep;
    }

    float asv[4], adv[4];
#pragma unroll
    for (int c = 0; c < 4; c++) {
        asv[c] = a_src[c * 16 + m16];
        adv[c] = a_dst[c * 16 + m16];
    }
#pragma unroll
    for (int t = 0; t < 2; t++) {
#pragma unroll
        for (int i = 0; i < 4; i++) {
            int r = row0 + t * 16 + quad * 4 + i;
            float s0 = 0.f, d0 = 0.f;
#pragma unroll
            for (int c = 0; c < 4; c++) {
                float v = acc[t][c][i];
                s0 += v * asv[c]; d0 += v * adv[c];
            }
#pragma unroll
            for (int off = 1; off < 16; off <<= 1) {
                s0 += __shfl_xor(s0, off);
                d0 += __shfl_xor(d0, off);
            }
            if (m16 == 0 && r < M) { aS[r] = s0; aD[r] = d0; }
        }
    }

#pragma unroll
    for (int t = 0; t < 2; t++) {
#pragma unroll
        for (int c = 0; c < 4; c++)
#pragma unroll
            for (int i = 0; i < 4; i++)
                st[wv][quad * 4 + i][c * 16 + m16] = (_Float16)acc[t][c][i];
        __syncthreads();
        int rowChunk = row0 + t * 16;
#pragma unroll
        for (int it = 0; it < 2; it++) {
            int lid = it * 64 + lane;
            int rloc = lid >> 3, u = lid & 7;
            h8_t v = *reinterpret_cast<const h8_t*>(&st[wv][rloc][u * 8]);
            *reinterpret_cast<h8_t*>(hOut + (size_t)(rowChunk + rloc) * 64 + u * 8) = v;
        }
        __syncthreads();
    }
}

// ---------------- aggregation H=4: 16B/lane gather, 2 edges in flight ----------------
template <int TAG>
__global__ __launch_bounds__(256) void aggregate4_kernel(const _Float16* __restrict__ hsrc,
                                                         const float* __restrict__ alpha_s,
                                                         const float* __restrict__ alpha_d,
                                                         const int* __restrict__ row_ptr,
                                                         const int* __restrict__ csr_src,
                                                         const float* __restrict__ bias,
                                                         _Float16* __restrict__ outH,
                                                         _Float16* __restrict__ outL,
                                                         int N, int Mpad) {
    __shared__ float wlds[4][64][4];
    __shared__ int   slds[4][64];
    int wv = threadIdx.x >> 6, lane = threadIdx.x & 63;
    int node = blockIdx.x * 4 + wv;
    if (node >= N) return;
    int rs = row_ptr[node], re = row_ptr[node + 1];
    // gather mapping: slot = lane>>5 (edge slot), lp = lane&31 covers full 512B row
    int slot = lane >> 5, lp = lane & 31;
    int ghead = lp >> 3;          // head of the 8 channels this lane covers
    int gbyte = lp * 16;          // byte offset within the h row
    float4 ad4 = *(const float4*)(alpha_d + (size_t)node * 4);

    float den0 = 0.f, den1 = 0.f, den2 = 0.f, den3 = 0.f;
    float acc8[8] = {0.f, 0.f, 0.f, 0.f, 0.f, 0.f, 0.f, 0.f};
    float* wp = &wlds[wv][0][0];
    int*   sp = &slds[wv][0];
    const char* hbase = (const char*)hsrc;
    for (int base = rs; base < re; base += 64) {
        int i = base + lane;
        float w0 = 0.f, w1 = 0.f, w2 = 0.f, w3 = 0.f;
        int off = 0;
        if (i < re) {
            int s = csr_src[i];
            float4 as = *(const float4*)(alpha_s + (size_t)s * 4);
            w0 = __expf(fminf(leaky(as.x + ad4.x), 60.f));
            w1 = __expf(fminf(leaky(as.y + ad4.y), 60.f));
            w2 = __expf(fminf(leaky(as.z + ad4.z), 60.f));
            w3 = __expf(fminf(leaky(as.w + ad4.w), 60.f));
            off = s * 512;
        }
        den0 += w0; den1 += w1; den2 += w2; den3 += w3;
        sp[lane] = off;
        *(float4*)(wp + lane * 4) = make_float4(w0, w1, w2, w3);
        int cnt = min(64, re - base);
#pragma unroll 2
        for (int j = slot; j < cnt; j += 2) {
            int o2 = sp[j];
            float w = wp[j * 4 + ghead];
            h8_t hv = *reinterpret_cast<const h8_t*>(hbase + o2 + gbyte);
#pragma unroll
            for (int k = 0; k < 8; k++) acc8[k] += w * (float)hv[k];
        }
    }
    // reduce edge slots (lane <-> lane^32)
#pragma unroll
    for (int k = 0; k < 8; k++) acc8[k] += __shfl_xor(acc8[k], 32);
#pragma unroll
    for (int off = 32; off >= 1; off >>= 1) {
        den0 += __shfl_xor(den0, off);
        den1 += __shfl_xor(den1, off);
        den2 += __shfl_xor(den2, off);
        den3 += __shfl_xor(den3, off);
    }
    if (slot == 0) {
        float den = (ghead & 2) ? ((ghead & 1) ? den3 : den2) : ((ghead & 1) ? den1 : den0);
        float inv = 1.f / (den + 1e-16f);
        int cbase = lp * 8;
        float4 b0 = *(const float4*)(bias + cbase);
        float4 b1 = *(const float4*)(bias + cbase + 4);
        float bv[8] = {b0.x, b0.y, b0.z, b0.w, b1.x, b1.y, b1.z, b1.w};
        h8_t hv, lv;
#pragma unroll
        for (int k = 0; k < 8; k++) {
            float v = fmaxf(acc8[k] * inv + bv[k], 0.f);
            _Float16 hi = (_Float16)v;
            hv[k] = hi;
            lv[k] = (_Float16)(v - (float)hi);
        }
        size_t o = ((size_t)lp * Mpad + node) * 8;
        *reinterpret_cast<h8_t*>(outH + o) = hv;
        *reinterpret_cast<h8_t*>(outL + o) = lv;
    }
}

// ---------------- aggregation H=1: 16B/lane gather, 8 edges in flight ----------------
__global__ __launch_bounds__(256) void aggregate1_kernel(const _Float16* __restrict__ hsrc,
                                                         const float* __restrict__ alpha_s,
                                                         const float* __restrict__ alpha_d,
                                                         const int* __restrict__ row_ptr,
                                                         const int* __restrict__ csr_src,
                                                         const float* __restrict__ bias,
                                                         float* __restrict__ out, int N) {
    __shared__ float wlds[4][64];
    __shared__ int   slds[4][64];
    int wv = threadIdx.x >> 6, lane = threadIdx.x & 63;
    int node = blockIdx.x * 4 + wv;
    if (node >= N) return;
    int rs = row_ptr[node], re = row_ptr[node + 1];
    float ad = alpha_d[node];
    int slot = lane >> 3, lp = lane & 7;   // 8 edge slots, lp covers 128B row
    int gbyte = lp * 16;

    float den = 0.f;
    float acc8[8] = {0.f, 0.f, 0.f, 0.f, 0.f, 0.f, 0.f, 0.f};
    const char* hbase = (const char*)hsrc;
    float* wp = &wlds[wv][0];
    int*   sp = &slds[wv][0];
    for (int base = rs; base < re; base += 64) {
        int i = base + lane;
        float w = 0.f;
        int off = 0;
        if (i < re) {
            int s = csr_src[i];
            w = __expf(fminf(leaky(alpha_s[s] + ad), 60.f));
            off = s * 128;
        }
        den += w;
        sp[lane] = off;
        wp[lane] = w;
        int cnt = min(64, re - base);
#pragma unroll 2
        for (int j = slot; j < cnt; j += 8) {
            float wj = wp[j];
            h8_t hv = *reinterpret_cast<const h8_t*>(hbase + sp[j] + gbyte);
#pragma unroll
            for (int k = 0; k < 8; k++) acc8[k] += wj * (float)hv[k];
        }
    }
    // reduce across 8 edge slots (xor 8, 16, 32)
#pragma unroll
    for (int k = 0; k < 8; k++) {
        acc8[k] += __shfl_xor(acc8[k], 8);
        acc8[k] += __shfl_xor(acc8[k], 16);
        acc8[k] += __shfl_xor(acc8[k], 32);
    }
#pragma unroll
    for (int off = 32; off >= 1; off >>= 1) den += __shfl_xor(den, off);
    if (slot == 0) {
        float inv = 1.f / (den + 1e-16f);
        int cbase = lp * 8;
        float4 b0 = *(const float4*)(bias + cbase);
        float4 b1 = *(const float4*)(bias + cbase + 4);
        float bv[8] = {b0.x, b0.y, b0.z, b0.w, b1.x, b1.y, b1.z, b1.w};
        float4 o0, o1;
        o0.x = acc8[0] * inv + bv[0]; o0.y = acc8[1] * inv + bv[1];
        o0.z = acc8[2] * inv + bv[2]; o0.w = acc8[3] * inv + bv[3];
        o1.x = acc8[4] * inv + bv[4]; o1.y = acc8[5] * inv + bv[5];
        o1.z = acc8[6] * inv + bv[6]; o1.w = acc8[7] * inv + bv[7];
        float* po = out + (size_t)node * 64 + cbase;
        *(float4*)po = o0;
        *(float4*)(po + 4) = o1;
    }
}

// ---------------- head MLP ----------------
__global__ __launch_bounds__(256) void mlp_head_kernel(const float* __restrict__ hin,
                                                       const float* __restrict__ Wo1,
                                                       const float* __restrict__ bo1,
                                                       const float* __restrict__ Wo2,
                                                       const float* __restrict__ bo2,
                                                       float* __restrict__ out, int N) {
    __shared__ float w1[64 * 32];
    __shared__ float w2[32];
    __shared__ float b1s[32];
    int tid = threadIdx.x;
#pragma unroll
    for (int i = 0; i < 8; i++) w1[tid + i * 256] = Wo1[tid + i * 256];
    if (tid < 32) { w2[tid] = Wo2[tid]; b1s[tid] = bo1[tid]; }
    __syncthreads();
    int n = blockIdx.x * blockDim.x + tid;
    if (n >= N) return;
    float hrow[64];
    const float* pr = hin + (size_t)n * 64;
#pragma unroll
    for (int i = 0; i < 64; i++) hrow[i] = pr[i];
    float sum = 0.f;
    for (int j = 0; j < 32; j++) {
        float a = b1s[j];
#pragma unroll
        for (int k = 0; k < 64; k++) a += hrow[k] * w1[k * 32 + j];
        a = fmaxf(a, 0.f);
        sum += a * w2[j];
    }
    out[n] = sum + bo2[0];
}

// ---------------- launch ----------------
extern "C" void kernel_launch(void* const* d_in, const int* in_sizes, int n_in,
                              void* d_out, int out_size, void* d_ws, size_t ws_size,
                              hipStream_t stream) {
    const float* x     = (const float*)d_in[0];
    const float* W_emb = (const float*)d_in[1];
    const float* b_emb = (const float*)d_in[2];
    const float* W0    = (const float*)d_in[3];
    const float* as0   = (const float*)d_in[4];
    const float* ad0   = (const float*)d_in[5];
    const float* b0    = (const float*)d_in[6];
    const float* W1    = (const float*)d_in[7];
    const float* as1   = (const float*)d_in[8];
    const float* ad1   = (const float*)d_in[9];
    const float* b1    = (const float*)d_in[10];
    const float* W2    = (const float*)d_in[11];
    const float* as2   = (const float*)d_in[12];
    const float* ad2   = (const float*)d_in[13];
    const float* b2    = (const float*)d_in[14];
    const float* Wo1   = (const float*)d_in[15];
    const float* bo1   = (const float*)d_in[16];
    const float* Wo2   = (const float*)d_in[17];
    const float* bo2   = (const float*)d_in[18];
    const int* eidx    = (const int*)d_in[19];

    const int N = in_sizes[0] / 128;
    const int E = in_sizes[19] / 2;
    const int* esrc = eidx;
    const int* edst = eidx + E;
    const int gmB  = (N + 127) / 128;
    const int Mpad = gmB * 128;
    const int nb   = (N + 255) / 256;

    char* w = (char*)d_ws;
    auto alloc = [&](size_t bytes) {
        char* p = w;
        w += (bytes + 255) & ~(size_t)255;
        return (void*)p;
    };
    _Float16* hOut = (_Float16*)alloc((size_t)Mpad * 256 * 2);
    _Float16* PHh  = (_Float16*)alloc((size_t)Mpad * 256 * 2);
    _Float16* PHl  = (_Float16*)alloc((size_t)Mpad * 256 * 2);
    _Float16* XPh  = (_Float16*)alloc((size_t)Mpad * 128 * 2);
    _Float16* XPl  = (_Float16*)alloc((size_t)Mpad * 128 * 2);
    float* bufA    = (float*)alloc((size_t)Mpad * 64 * 4);
    float* aS      = (float*)alloc((size_t)N * 4 * 4);
    float* aD      = (float*)alloc((size_t)N * 4 * 4);
    int*   row_ptr = (int*)alloc((size_t)(N + 1) * 4);
    int*   cursor  = (int*)alloc((size_t)N * 4);
    int*   cnt     = (int*)alloc((size_t)N * 4);
    int*   bsum    = (int*)alloc((size_t)nb * 4);
    int*   csr     = (int*)alloc((size_t)(E + N) * 4);
    _Float16* WeH  = (_Float16*)alloc(128 * 64 * 2);
    _Float16* WeL  = (_Float16*)alloc(128 * 64 * 2);
    _Float16* W0H  = (_Float16*)alloc(64 * 256 * 2);
    _Float16* W0L  = (_Float16*)alloc(64 * 256 * 2);
    _Float16* W1H  = (_Float16*)alloc(256 * 256 * 2);
    _Float16* W1L  = (_Float16*)alloc(256 * 256 * 2);
    _Float16* W2H  = (_Float16*)alloc(256 * 64 * 2);
    _Float16* W2L  = (_Float16*)alloc(256 * 64 * 2);

    // CSR build (multi-block scan)
    hipMemsetAsync(cnt, 0, (size_t)N * 4, stream);
    hist_kernel<<<(E + 255) / 256, 256, 0, stream>>>(edst, E, cnt);
    blocksum_kernel<<<nb, 256, 0, stream>>>(cnt, N, bsum);
    scanbsum_kernel<<<1, 256, 0, stream>>>(bsum, nb, row_ptr + N);
    rowptr_kernel<<<nb, 256, 0, stream>>>(cnt, bsum, N, row_ptr, cursor);
    scatter_kernel<<<(E + N + 255) / 256, 256, 0, stream>>>(esrc, edst, E, N, cursor, csr);

    // weight planes (fused single launch)
    prep_weights_all<<<dim3(256, 4), 256, 0, stream>>>(W_emb, W0, W1, W2,
                                                       WeH, WeL, W0H, W0L, W1H, W1L, W2H, W2L);

    int gn4 = (N + 3) / 4;

    // embedding
    prep_act_kernel<<<((size_t)Mpad * 16 + 255) / 256, 256, 0, stream>>>(x, XPh, XPl, N, Mpad, 16, 128);
    gemm_emb_kernel<<<dim3(gmB, 1), 256, 0, stream>>>(XPh, XPl, WeH, WeL, b_emb, PHh, PHl, Mpad, N, 128);

    // GAT layer 0
    gemm_gat_kernel<0><<<dim3(gmB, 2), 256, 0, stream>>>(PHh, PHl, W0H, W0L, as0, ad0, hOut, aS, aD, Mpad, N, 64);
    aggregate4_kernel<0><<<gn4, 256, 0, stream>>>(hOut, aS, aD, row_ptr, csr, b0, PHh, PHl, N, Mpad);

    // GAT layer 1
    gemm_gat_kernel<1><<<dim3(gmB, 2), 256, 0, stream>>>(PHh, PHl, W1H, W1L, as1, ad1, hOut, aS, aD, Mpad, N, 256);
    aggregate4_kernel<1><<<gn4, 256, 0, stream>>>(hOut, aS, aD, row_ptr, csr, b1, PHh, PHl, N, Mpad);

    // GAT layer 2 (1 head, no relu)
    gemm_l2_kernel<<<dim3(gmB, 1), 256, 0, stream>>>(PHh, PHl, W2H, W2L, as2, ad2, hOut, aS, aD, Mpad, N, 256);
    aggregate1_kernel<<<gn4, 256, 0, stream>>>(hOut, aS, aD, row_ptr, csr, b2, bufA, N);

    // head MLP -> out [N,1] fp32
    mlp_head_kernel<<<(N + 255) / 256, 256, 0, stream>>>(bufA, Wo1, bo1, Wo2, bo2, (float*)d_out, N);
}

// Round 14
// 484.531 us; speedup vs baseline: 1.6482x; 1.0081x over previous
//
#include <hip/hip_runtime.h>

typedef _Float16 h8_t __attribute__((ext_vector_type(8)));
typedef _Float16 h4_t __attribute__((ext_vector_type(4)));
typedef float floatx4 __attribute__((ext_vector_type(4)));

__device__ __forceinline__ float leaky(float v) { return v >= 0.f ? v : 0.2f * v; }

// ---------------- CSR build ----------------
__global__ void hist_kernel(const int* __restrict__ dst, int E, int* __restrict__ cnt) {
    int e = blockIdx.x * blockDim.x + threadIdx.x;
    if (e < E) atomicAdd(&cnt[dst[e]], 1);
}

__global__ __launch_bounds__(256) void blocksum_kernel(const int* __restrict__ cnt, int N,
                                                       int* __restrict__ bsum) {
    __shared__ int red[256];
    int tid = threadIdx.x;
    int idx = blockIdx.x * 256 + tid;
    red[tid] = idx < N ? cnt[idx] + 1 : 0;
    __syncthreads();
#pragma unroll
    for (int off = 128; off >= 1; off >>= 1) {
        if (tid < off) red[tid] += red[tid + off];
        __syncthreads();
    }
    if (tid == 0) bsum[blockIdx.x] = red[0];
}

__global__ __launch_bounds__(256) void scanbsum_kernel(int* __restrict__ bsum, int nb,
                                                       int* __restrict__ total) {
    __shared__ int part[256];
    int tid = threadIdx.x;
    int per = (nb + 255) / 256;
    int s0 = tid * per, s1 = min(s0 + per, nb);
    int s = 0;
    for (int i = s0; i < s1; i++) s += bsum[i];
    part[tid] = s;
    __syncthreads();
    for (int off = 1; off < 256; off <<= 1) {
        int v = (tid >= off) ? part[tid - off] : 0;
        __syncthreads();
        part[tid] += v;
        __syncthreads();
    }
    int base = (tid == 0) ? 0 : part[tid - 1];
    for (int i = s0; i < s1; i++) {
        int v = bsum[i];
        bsum[i] = base;
        base += v;
    }
    if (tid == 255) *total = part[255];
}

__global__ __launch_bounds__(256) void rowptr_kernel(const int* __restrict__ cnt,
                                                     const int* __restrict__ bsum, int N,
                                                     int* __restrict__ row_ptr,
                                                     int* __restrict__ cursor) {
    __shared__ int lds[256];
    int tid = threadIdx.x;
    int idx = blockIdx.x * 256 + tid;
    int v = idx < N ? cnt[idx] + 1 : 0;
    lds[tid] = v;
    __syncthreads();
    for (int off = 1; off < 256; off <<= 1) {
        int t = (tid >= off) ? lds[tid - off] : 0;
        __syncthreads();
        lds[tid] += t;
        __syncthreads();
    }
    if (idx < N) {
        int p = bsum[blockIdx.x] + lds[tid] - v;
        row_ptr[idx] = p;
        cursor[idx] = p;
    }
}

__global__ void scatter_kernel(const int* __restrict__ src, const int* __restrict__ dst,
                               int E, int N, int* __restrict__ cursor, int* __restrict__ csr_src) {
    int e = blockIdx.x * blockDim.x + threadIdx.x;
    if (e >= E + N) return;
    int s, d;
    if (e < E) { s = src[e]; d = dst[e]; }
    else       { s = e - E;  d = s; }
    int pos = atomicAdd(&cursor[d], 1);
    csr_src[pos] = s;
}

// ---------------- fused weight prep ----------------
__global__ void prep_weights_all(const float* __restrict__ W_emb, const float* __restrict__ W0,
                                 const float* __restrict__ W1, const float* __restrict__ W2,
                                 _Float16* __restrict__ WeH, _Float16* __restrict__ WeL,
                                 _Float16* __restrict__ W0H, _Float16* __restrict__ W0L,
                                 _Float16* __restrict__ W1H, _Float16* __restrict__ W1L,
                                 _Float16* __restrict__ W2H, _Float16* __restrict__ W2L) {
    int which = blockIdx.y;
    const float* W;
    _Float16 *Wh, *Wl;
    int K, N;
    if (which == 0)      { W = W_emb; Wh = WeH; Wl = WeL; K = 128; N = 64; }
    else if (which == 1) { W = W0;    Wh = W0H; Wl = W0L; K = 64;  N = 256; }
    else if (which == 2) { W = W1;    Wh = W1H; Wl = W1L; K = 256; N = 256; }
    else                 { W = W2;    Wh = W2H; Wl = W2L; K = 256; N = 64; }
    int idx = blockIdx.x * blockDim.x + threadIdx.x;
    if (idx >= K * N) return;
    int k = idx / N, n = idx % N;
    float v = W[idx];
    _Float16 hi = (_Float16)v;
    _Float16 lo = (_Float16)(v - (float)hi);
    size_t o = ((size_t)(k >> 3) * N + n) * 8 + (k & 7);
    Wh[o] = hi; Wl[o] = lo;
}

// ---------------- embedding GEMM: direct-x A, full-B LDS stage, -> hi/lo planes ----------------
__global__ __launch_bounds__(256) void gemm_emb_kernel(
        const float* __restrict__ X,
        const _Float16* __restrict__ Bh, const _Float16* __restrict__ Bl,
        const float* __restrict__ bias,
        _Float16* __restrict__ Ph, _Float16* __restrict__ Pl,
        int Mpad, int M) {
    const int Nn = 64, K = 128;
    __shared__ _Float16 Bs[2][16][64][8];   // full B: 32 KB
    __shared__ _Float16 stH[4][16][72];
    __shared__ _Float16 stL[4][16][72];
    int tid = threadIdx.x;
    int wv = tid >> 6, lane = tid & 63;
    int m16 = lane & 15, quad = lane >> 4;
    int row0 = blockIdx.x * 128 + wv * 32;

    // stage entire B (2 planes x 16 kq x 64 cols), 2048 x 16B chunks
#pragma unroll
    for (int cc = 0; cc < 8; cc++) {
        int c = tid + cc * 256;
        int plane = c >> 10, rem = c & 1023, q = rem >> 6, col = rem & 63;
        const _Float16* srcp = (plane ? Bl : Bh) + ((size_t)q * Nn + col) * 8;
        *reinterpret_cast<h8_t*>(&Bs[plane][q][col][0]) = *reinterpret_cast<const h8_t*>(srcp);
    }
    __syncthreads();

    floatx4 acc[2][4];
#pragma unroll
    for (int t = 0; t < 2; t++)
#pragma unroll
        for (int c = 0; c < 4; c++)
#pragma unroll
            for (int i = 0; i < 4; i++) acc[t][c][i] = 0.f;

    int r0 = row0 + m16, r1 = row0 + 16 + m16;
#pragma unroll
    for (int kt4 = 0; kt4 < 4; kt4++) {
        int kcol = kt4 * 32 + quad * 8;
        float vs0[8] = {0,0,0,0,0,0,0,0}, vs1[8] = {0,0,0,0,0,0,0,0};
        if (r0 < M) {
            const float4* p = (const float4*)(X + (size_t)r0 * K + kcol);
            float4 a = p[0], b = p[1];
            vs0[0]=a.x; vs0[1]=a.y; vs0[2]=a.z; vs0[3]=a.w;
            vs0[4]=b.x; vs0[5]=b.y; vs0[6]=b.z; vs0[7]=b.w;
        }
        if (r1 < M) {
            const float4* p = (const float4*)(X + (size_t)r1 * K + kcol);
            float4 a = p[0], b = p[1];
            vs1[0]=a.x; vs1[1]=a.y; vs1[2]=a.z; vs1[3]=a.w;
            vs1[4]=b.x; vs1[5]=b.y; vs1[6]=b.z; vs1[7]=b.w;
        }
        h8_t ah0, al0, ah1, al1;
#pragma unroll
        for (int j = 0; j < 8; j++) {
            _Float16 hi0 = (_Float16)vs0[j];
            ah0[j] = hi0; al0[j] = (_Float16)(vs0[j] - (float)hi0);
            _Float16 hi1 = (_Float16)vs1[j];
            ah1[j] = hi1; al1[j] = (_Float16)(vs1[j] - (float)hi1);
        }
        int kq = kt4 * 4 + quad;
#pragma unroll
        for (int c = 0; c < 4; c++) {
            h8_t bh = *reinterpret_cast<const h8_t*>(&Bs[0][kq][c * 16 + m16][0]);
            h8_t bl = *reinterpret_cast<const h8_t*>(&Bs[1][kq][c * 16 + m16][0]);
            acc[0][c] = __builtin_amdgcn_mfma_f32_16x16x32_f16(ah0, bh, acc[0][c], 0, 0, 0);
            acc[1][c] = __builtin_amdgcn_mfma_f32_16x16x32_f16(ah1, bh, acc[1][c], 0, 0, 0);
            acc[0][c] = __builtin_amdgcn_mfma_f32_16x16x32_f16(ah0, bl, acc[0][c], 0, 0, 0);
            acc[1][c] = __builtin_amdgcn_mfma_f32_16x16x32_f16(ah1, bl, acc[1][c], 0, 0, 0);
            acc[0][c] = __builtin_amdgcn_mfma_f32_16x16x32_f16(al0, bh, acc[0][c], 0, 0, 0);
            acc[1][c] = __builtin_amdgcn_mfma_f32_16x16x32_f16(al1, bh, acc[1][c], 0, 0, 0);
        }
    }

#pragma unroll
    for (int t = 0; t < 2; t++) {
#pragma unroll
        for (int c = 0; c < 4; c++) {
            float bv = bias[c * 16 + m16];
#pragma unroll
            for (int i = 0; i < 4; i++) {
                float v = fmaxf(acc[t][c][i] + bv, 0.f);
                _Float16 hi = (_Float16)v;
                stH[wv][quad * 4 + i][c * 16 + m16] = hi;
                stL[wv][quad * 4 + i][c * 16 + m16] = (_Float16)(v - (float)hi);
            }
        }
        __syncthreads();
        int rowChunk = row0 + t * 16;
#pragma unroll
        for (int it = 0; it < 2; it++) {
            int lid = it * 64 + lane;
            int kg = lid >> 4, rloc = lid & 15;
            h8_t vh = *reinterpret_cast<const h8_t*>(&stH[wv][rloc][kg * 8]);
            h8_t vl = *reinterpret_cast<const h8_t*>(&stL[wv][rloc][kg * 8]);
            size_t o = ((size_t)kg * Mpad + rowChunk + rloc) * 8;
            *reinterpret_cast<h8_t*>(Ph + o) = vh;
            *reinterpret_cast<h8_t*>(Pl + o) = vl;
        }
        __syncthreads();
    }
}

// ---------------- GAT GEMM layer0 (K=64, full-B stage) + fused alphas ----------------
__global__ __launch_bounds__(256) void gemm_gat0_kernel(
        const _Float16* __restrict__ Ah, const _Float16* __restrict__ Al,
        const _Float16* __restrict__ Bh, const _Float16* __restrict__ Bl,
        const float* __restrict__ a_src, const float* __restrict__ a_dst,
        _Float16* __restrict__ hOut, float* __restrict__ aS, float* __restrict__ aD,
        int Mpad, int M) {
    const int Nn = 256;
    __shared__ _Float16 Bs[2][8][128][8];   // full B col-block: 32 KB
    __shared__ _Float16 st[4][16][136];
    int tid = threadIdx.x;
    int wv = tid >> 6, lane = tid & 63;
    int m16 = lane & 15, quad = lane >> 4;
    int row0 = blockIdx.x * 128 + wv * 32;
    int colBase = blockIdx.y * 128;
    size_t kqbase = (size_t)colBase * 8;

#pragma unroll
    for (int cc = 0; cc < 8; cc++) {
        int c = tid + cc * 256;
        int plane = c >> 10, rem = c & 1023, q = rem >> 7, col = rem & 127;
        const _Float16* srcp = (plane ? Bl : Bh) + kqbase + ((size_t)q * Nn + col) * 8;
        *reinterpret_cast<h8_t*>(&Bs[plane][q][col][0]) = *reinterpret_cast<const h8_t*>(srcp);
    }
    __syncthreads();

    floatx4 acc[2][8];
#pragma unroll
    for (int t = 0; t < 2; t++)
#pragma unroll
        for (int c = 0; c < 8; c++)
#pragma unroll
            for (int i = 0; i < 4; i++) acc[t][c][i] = 0.f;

#pragma unroll
    for (int kt = 0; kt < 2; kt++) {
        int kq = kt * 4 + quad;
        size_t aoff = ((size_t)kq * Mpad + row0 + m16) * 8;
        h8_t ah0 = *reinterpret_cast<const h8_t*>(Ah + aoff);
        h8_t ah1 = *reinterpret_cast<const h8_t*>(Ah + aoff + 128);
        h8_t al0 = *reinterpret_cast<const h8_t*>(Al + aoff);
        h8_t al1 = *reinterpret_cast<const h8_t*>(Al + aoff + 128);
#pragma unroll
        for (int c = 0; c < 8; c++) {
            h8_t bh = *reinterpret_cast<const h8_t*>(&Bs[0][kq][c * 16 + m16][0]);
            h8_t bl = *reinterpret_cast<const h8_t*>(&Bs[1][kq][c * 16 + m16][0]);
            acc[0][c] = __builtin_amdgcn_mfma_f32_16x16x32_f16(ah0, bh, acc[0][c], 0, 0, 0);
            acc[1][c] = __builtin_amdgcn_mfma_f32_16x16x32_f16(ah1, bh, acc[1][c], 0, 0, 0);
            acc[0][c] = __builtin_amdgcn_mfma_f32_16x16x32_f16(ah0, bl, acc[0][c], 0, 0, 0);
            acc[1][c] = __builtin_amdgcn_mfma_f32_16x16x32_f16(ah1, bl, acc[1][c], 0, 0, 0);
            acc[0][c] = __builtin_amdgcn_mfma_f32_16x16x32_f16(al0, bh, acc[0][c], 0, 0, 0);
            acc[1][c] = __builtin_amdgcn_mfma_f32_16x16x32_f16(al1, bh, acc[1][c], 0, 0, 0);
        }
    }

    float asv[8], adv[8];
#pragma unroll
    for (int c = 0; c < 8; c++) {
        asv[c] = a_src[colBase + c * 16 + m16];
        adv[c] = a_dst[colBase + c * 16 + m16];
    }
    int hb = colBase >> 6;
#pragma unroll
    for (int t = 0; t < 2; t++) {
#pragma unroll
        for (int i = 0; i < 4; i++) {
            int r = row0 + t * 16 + quad * 4 + i;
            float s0 = 0.f, d0 = 0.f, s1 = 0.f, d1 = 0.f;
#pragma unroll
            for (int c = 0; c < 8; c++) {
                float v = acc[t][c][i];
                if (c < 4) { s0 += v * asv[c]; d0 += v * adv[c]; }
                else       { s1 += v * asv[c]; d1 += v * adv[c]; }
            }
#pragma unroll
            for (int off = 1; off < 16; off <<= 1) {
                s0 += __shfl_xor(s0, off);
                d0 += __shfl_xor(d0, off);
                s1 += __shfl_xor(s1, off);
                d1 += __shfl_xor(d1, off);
            }
            if (m16 == 0 && r < M) {
                aS[r * 4 + hb] = s0;     aD[r * 4 + hb] = d0;
                aS[r * 4 + hb + 1] = s1; aD[r * 4 + hb + 1] = d1;
            }
        }
    }

#pragma unroll
    for (int t = 0; t < 2; t++) {
#pragma unroll
        for (int c = 0; c < 8; c++)
#pragma unroll
            for (int i = 0; i < 4; i++)
                st[wv][quad * 4 + i][c * 16 + m16] = (_Float16)acc[t][c][i];
        __syncthreads();
        int rowChunk = row0 + t * 16;
#pragma unroll
        for (int it = 0; it < 4; it++) {
            int lid = it * 64 + lane;
            int rloc = lid >> 4, u = lid & 15;
            h8_t v = *reinterpret_cast<const h8_t*>(&st[wv][rloc][u * 8]);
            *reinterpret_cast<h8_t*>(hOut + (size_t)(rowChunk + rloc) * 256 + colBase + u * 8) = v;
        }
        __syncthreads();
    }
}

// ---------------- GAT GEMM layer1 (K=256, per-kt B stage) + fused alphas ----------------
__global__ __launch_bounds__(256) void gemm_gat1_kernel(
        const _Float16* __restrict__ Ah, const _Float16* __restrict__ Al,
        const _Float16* __restrict__ Bh, const _Float16* __restrict__ Bl,
        const float* __restrict__ a_src, const float* __restrict__ a_dst,
        _Float16* __restrict__ hOut, float* __restrict__ aS, float* __restrict__ aD,
        int Mpad, int M, int K) {
    const int Nn = 256;
    __shared__ _Float16 Bs[2][4][128][8];
    __shared__ _Float16 st[4][16][136];
    int tid = threadIdx.x;
    int wv = tid >> 6, lane = tid & 63;
    int m16 = lane & 15, quad = lane >> 4;
    int row0 = blockIdx.x * 128 + wv * 32;
    int colBase = blockIdx.y * 128;

    floatx4 acc[2][8];
#pragma unroll
    for (int t = 0; t < 2; t++)
#pragma unroll
        for (int c = 0; c < 8; c++)
#pragma unroll
            for (int i = 0; i < 4; i++) acc[t][c][i] = 0.f;

    size_t aoff = ((size_t)quad * Mpad + row0 + m16) * 8;
    size_t kqbase = (size_t)colBase * 8;
    const size_t aStep = (size_t)Mpad * 32;
    const size_t bStep = (size_t)Nn * 32;

    for (int kt = 0; kt < K; kt += 32) {
        h8_t ah0 = *reinterpret_cast<const h8_t*>(Ah + aoff);
        h8_t ah1 = *reinterpret_cast<const h8_t*>(Ah + aoff + 128);
        h8_t al0 = *reinterpret_cast<const h8_t*>(Al + aoff);
        h8_t al1 = *reinterpret_cast<const h8_t*>(Al + aoff + 128);
#pragma unroll
        for (int cc = 0; cc < 4; cc++) {
            int c = tid + cc * 256;
            int plane = c >> 9, rem = c & 511, q = rem >> 7, col = rem & 127;
            const _Float16* srcp = (plane ? Bl : Bh) + kqbase + ((size_t)q * Nn + col) * 8;
            *reinterpret_cast<h8_t*>(&Bs[plane][q][col][0]) = *reinterpret_cast<const h8_t*>(srcp);
        }
        __syncthreads();
#pragma unroll
        for (int c = 0; c < 8; c++) {
            h8_t bh = *reinterpret_cast<const h8_t*>(&Bs[0][quad][c * 16 + m16][0]);
            h8_t bl = *reinterpret_cast<const h8_t*>(&Bs[1][quad][c * 16 + m16][0]);
            acc[0][c] = __builtin_amdgcn_mfma_f32_16x16x32_f16(ah0, bh, acc[0][c], 0, 0, 0);
            acc[1][c] = __builtin_amdgcn_mfma_f32_16x16x32_f16(ah1, bh, acc[1][c], 0, 0, 0);
            acc[0][c] = __builtin_amdgcn_mfma_f32_16x16x32_f16(ah0, bl, acc[0][c], 0, 0, 0);
            acc[1][c] = __builtin_amdgcn_mfma_f32_16x16x32_f16(ah1, bl, acc[1][c], 0, 0, 0);
            acc[0][c] = __builtin_amdgcn_mfma_f32_16x16x32_f16(al0, bh, acc[0][c], 0, 0, 0);
            acc[1][c] = __builtin_amdgcn_mfma_f32_16x16x32_f16(al1, bh, acc[1][c], 0, 0, 0);
        }
        __syncthreads();
        aoff += aStep; kqbase += bStep;
    }

    float asv[8], adv[8];
#pragma unroll
    for (int c = 0; c < 8; c++) {
        asv[c] = a_src[colBase + c * 16 + m16];
        adv[c] = a_dst[colBase + c * 16 + m16];
    }
    int hb = colBase >> 6;
#pragma unroll
    for (int t = 0; t < 2; t++) {
#pragma unroll
        for (int i = 0; i < 4; i++) {
            int r = row0 + t * 16 + quad * 4 + i;
            float s0 = 0.f, d0 = 0.f, s1 = 0.f, d1 = 0.f;
#pragma unroll
            for (int c = 0; c < 8; c++) {
                float v = acc[t][c][i];
                if (c < 4) { s0 += v * asv[c]; d0 += v * adv[c]; }
                else       { s1 += v * asv[c]; d1 += v * adv[c]; }
            }
#pragma unroll
            for (int off = 1; off < 16; off <<= 1) {
                s0 += __shfl_xor(s0, off);
                d0 += __shfl_xor(d0, off);
                s1 += __shfl_xor(s1, off);
                d1 += __shfl_xor(d1, off);
            }
            if (m16 == 0 && r < M) {
                aS[r * 4 + hb] = s0;     aD[r * 4 + hb] = d0;
                aS[r * 4 + hb + 1] = s1; aD[r * 4 + hb + 1] = d1;
            }
        }
    }

#pragma unroll
    for (int t = 0; t < 2; t++) {
#pragma unroll
        for (int c = 0; c < 8; c++)
#pragma unroll
            for (int i = 0; i < 4; i++)
                st[wv][quad * 4 + i][c * 16 + m16] = (_Float16)acc[t][c][i];
        __syncthreads();
        int rowChunk = row0 + t * 16;
#pragma unroll
        for (int it = 0; it < 4; it++) {
            int lid = it * 64 + lane;
            int rloc = lid >> 4, u = lid & 15;
            h8_t v = *reinterpret_cast<const h8_t*>(&st[wv][rloc][u * 8]);
            *reinterpret_cast<h8_t*>(hOut + (size_t)(rowChunk + rloc) * 256 + colBase + u * 8) = v;
        }
        __syncthreads();
    }
}

// ---------------- layer-2 GEMM (Nn=64, K=256) + fused alphas ----------------
__global__ __launch_bounds__(256) void gemm_l2_kernel(
        const _Float16* __restrict__ Ah, const _Float16* __restrict__ Al,
        const _Float16* __restrict__ Bh, const _Float16* __restrict__ Bl,
        const float* __restrict__ a_src, const float* __restrict__ a_dst,
        _Float16* __restrict__ hOut, float* __restrict__ aS, float* __restrict__ aD,
        int Mpad, int M, int K) {
    const int Nn = 64;
    __shared__ _Float16 Bs[2][4][64][8];
    __shared__ _Float16 st[4][16][72];
    int tid = threadIdx.x;
    int wv = tid >> 6, lane = tid & 63;
    int m16 = lane & 15, quad = lane >> 4;
    int row0 = blockIdx.x * 128 + wv * 32;

    floatx4 acc[2][4];
#pragma unroll
    for (int t = 0; t < 2; t++)
#pragma unroll
        for (int c = 0; c < 4; c++)
#pragma unroll
            for (int i = 0; i < 4; i++) acc[t][c][i] = 0.f;

    size_t aoff = ((size_t)quad * Mpad + row0 + m16) * 8;
    size_t kqbase = 0;
    const size_t aStep = (size_t)Mpad * 32;
    const size_t bStep = (size_t)Nn * 32;

    for (int kt = 0; kt < K; kt += 32) {
        h8_t ah0 = *reinterpret_cast<const h8_t*>(Ah + aoff);
        h8_t ah1 = *reinterpret_cast<const h8_t*>(Ah + aoff + 128);
        h8_t al0 = *reinterpret_cast<const h8_t*>(Al + aoff);
        h8_t al1 = *reinterpret_cast<const h8_t*>(Al + aoff + 128);
#pragma unroll
        for (int cc = 0; cc < 2; cc++) {
            int c = tid + cc * 256;
            int plane = c >> 8, rem = c & 255, q = rem >> 6, col = rem & 63;
            const _Float16* srcp = (plane ? Bl : Bh) + kqbase + ((size_t)q * Nn + col) * 8;
            *reinterpret_cast<h8_t*>(&Bs[plane][q][col][0]) = *reinterpret_cast<const h8_t*>(srcp);
        }
        __syncthreads();
#pragma unroll
        for (int c = 0; c < 4; c++) {
            h8_t bh = *reinterpret_cast<const h8_t*>(&Bs[0][quad][c * 16 + m16][0]);
            h8_t bl = *reinterpret_cast<const h8_t*>(&Bs[1][quad][c * 16 + m16][0]);
            acc[0][c] = __builtin_amdgcn_mfma_f32_16x16x32_f16(ah0, bh, acc[0][c], 0, 0, 0);
            acc[1][c] = __builtin_amdgcn_mfma_f32_16x16x32_f16(ah1, bh, acc[1][c], 0, 0, 0);
            acc[0][c] = __builtin_amdgcn_mfma_f32_16x16x32_f16(ah0, bl, acc[0][c], 0, 0, 0);
            acc[1][c] = __builtin_amdgcn_mfma_f32_16x16x32_f16(ah1, bl, acc[1][c], 0, 0, 0);
            acc[0][c] = __builtin_amdgcn_mfma_f32_16x16x32_f16(al0, bh, acc[0][c], 0, 0, 0);
            acc[1][c] = __builtin_amdgcn_mfma_f32_16x16x32_f16(al1, bh, acc[1][c], 0, 0, 0);
        }
        __syncthreads();
        aoff += aStep; kqbase += bStep;
    }

    float asv[4], adv[4];
#pragma unroll
    for (int c = 0; c < 4; c++) {
        asv[c] = a_src[c * 16 + m16];
        adv[c] = a_dst[c * 16 + m16];
    }
#pragma unroll
    for (int t = 0; t < 2; t++) {
#pragma unroll
        for (int i = 0; i < 4; i++) {
            int r = row0 + t * 16 + quad * 4 + i;
            float s0 = 0.f, d0 = 0.f;
#pragma unroll
            for (int c = 0; c < 4; c++) {
                float v = acc[t][c][i];
                s0 += v * asv[c]; d0 += v * adv[c];
            }
#pragma unroll
            for (int off = 1; off < 16; off <<= 1) {
                s0 += __shfl_xor(s0, off);
                d0 += __shfl_xor(d0, off);
            }
            if (m16 == 0 && r < M) { aS[r] = s0; aD[r] = d0; }
        }
    }

#pragma unroll
    for (int t = 0; t < 2; t++) {
#pragma unroll
        for (int c = 0; c < 4; c++)
#pragma unroll
            for (int i = 0; i < 4; i++)
                st[wv][quad * 4 + i][c * 16 + m16] = (_Float16)acc[t][c][i];
        __syncthreads();
        int rowChunk = row0 + t * 16;
#pragma unroll
        for (int it = 0; it < 2; it++) {
            int lid = it * 64 + lane;
            int rloc = lid >> 3, u = lid & 7;
            h8_t v = *reinterpret_cast<const h8_t*>(&st[wv][rloc][u * 8]);
            *reinterpret_cast<h8_t*>(hOut + (size_t)(rowChunk + rloc) * 64 + u * 8) = v;
        }
        __syncthreads();
    }
}

// ---------------- aggregation H=4 (unchanged from round 13) ----------------
template <int TAG>
__global__ __launch_bounds__(256) void aggregate4_kernel(const _Float16* __restrict__ hsrc,
                                                         const float* __restrict__ alpha_s,
                                                         const float* __restrict__ alpha_d,
                                                         const int* __restrict__ row_ptr,
                                                         const int* __restrict__ csr_src,
                                                         const float* __restrict__ bias,
                                                         _Float16* __restrict__ outH,
                                                         _Float16* __restrict__ outL,
                                                         int N, int Mpad) {
    __shared__ float wlds[4][64][4];
    __shared__ int   slds[4][64];
    int wv = threadIdx.x >> 6, lane = threadIdx.x & 63;
    int node = blockIdx.x * 4 + wv;
    if (node >= N) return;
    int rs = row_ptr[node], re = row_ptr[node + 1];
    int slot = lane >> 5, lp = lane & 31;
    int ghead = lp >> 3;
    int gbyte = lp * 16;
    float4 ad4 = *(const float4*)(alpha_d + (size_t)node * 4);

    float den0 = 0.f, den1 = 0.f, den2 = 0.f, den3 = 0.f;
    float acc8[8] = {0.f, 0.f, 0.f, 0.f, 0.f, 0.f, 0.f, 0.f};
    float* wp = &wlds[wv][0][0];
    int*   sp = &slds[wv][0];
    const char* hbase = (const char*)hsrc;
    for (int base = rs; base < re; base += 64) {
        int i = base + lane;
        float w0 = 0.f, w1 = 0.f, w2 = 0.f, w3 = 0.f;
        int off = 0;
        if (i < re) {
            int s = csr_src[i];
            float4 as = *(const float4*)(alpha_s + (size_t)s * 4);
            w0 = __expf(fminf(leaky(as.x + ad4.x), 60.f));
            w1 = __expf(fminf(leaky(as.y + ad4.y), 60.f));
            w2 = __expf(fminf(leaky(as.z + ad4.z), 60.f));
            w3 = __expf(fminf(leaky(as.w + ad4.w), 60.f));
            off = s * 512;
        }
        den0 += w0; den1 += w1; den2 += w2; den3 += w3;
        sp[lane] = off;
        *(float4*)(wp + lane * 4) = make_float4(w0, w1, w2, w3);
        int cnt = min(64, re - base);
#pragma unroll 2
        for (int j = slot; j < cnt; j += 2) {
            int o2 = sp[j];
            float w = wp[j * 4 + ghead];
            h8_t hv = *reinterpret_cast<const h8_t*>(hbase + o2 + gbyte);
#pragma unroll
            for (int k = 0; k < 8; k++) acc8[k] += w * (float)hv[k];
        }
    }
#pragma unroll
    for (int k = 0; k < 8; k++) acc8[k] += __shfl_xor(acc8[k], 32);
#pragma unroll
    for (int off = 32; off >= 1; off >>= 1) {
        den0 += __shfl_xor(den0, off);
        den1 += __shfl_xor(den1, off);
        den2 += __shfl_xor(den2, off);
        den3 += __shfl_xor(den3, off);
    }
    if (slot == 0) {
        float den = (ghead & 2) ? ((ghead & 1) ? den3 : den2) : ((ghead & 1) ? den1 : den0);
        float inv = 1.f / (den + 1e-16f);
        int cbase = lp * 8;
        float4 b0 = *(const float4*)(bias + cbase);
        float4 b1 = *(const float4*)(bias + cbase + 4);
        float bv[8] = {b0.x, b0.y, b0.z, b0.w, b1.x, b1.y, b1.z, b1.w};
        h8_t hv, lv;
#pragma unroll
        for (int k = 0; k < 8; k++) {
            float v = fmaxf(acc8[k] * inv + bv[k], 0.f);
            _Float16 hi = (_Float16)v;
            hv[k] = hi;
            lv[k] = (_Float16)(v - (float)hi);
        }
        size_t o = ((size_t)lp * Mpad + node) * 8;
        *reinterpret_cast<h8_t*>(outH + o) = hv;
        *reinterpret_cast<h8_t*>(outL + o) = lv;
    }
}

// ---------------- fused aggregation H=1 + head MLP ----------------
__global__ __launch_bounds__(256) void agg1_mlp_kernel(const _Float16* __restrict__ hsrc,
                                                       const float* __restrict__ alpha_s,
                                                       const float* __restrict__ alpha_d,
                                                       const int* __restrict__ row_ptr,
                                                       const int* __restrict__ csr_src,
                                                       const float* __restrict__ bias,
                                                       const float* __restrict__ Wo1,
                                                       const float* __restrict__ bo1,
                                                       const float* __restrict__ Wo2,
                                                       const float* __restrict__ bo2,
                                                       float* __restrict__ out, int N) {
    __shared__ float wlds[4][64];
    __shared__ int   slds[4][64];
    __shared__ float hrow[4][64];
    __shared__ float w1s[64 * 32];
    __shared__ float w2s[32];
    __shared__ float b1s[32];
    int tid = threadIdx.x;
#pragma unroll
    for (int i = 0; i < 8; i++) w1s[tid + i * 256] = Wo1[tid + i * 256];
    if (tid < 32) { w2s[tid] = Wo2[tid]; b1s[tid] = bo1[tid]; }
    __syncthreads();

    int wv = tid >> 6, lane = tid & 63;
    int node = blockIdx.x * 4 + wv;
    if (node >= N) return;
    int rs = row_ptr[node], re = row_ptr[node + 1];
    float ad = alpha_d[node];
    int slot = lane >> 3, lp = lane & 7;
    int gbyte = lp * 16;

    float den = 0.f;
    float acc8[8] = {0.f, 0.f, 0.f, 0.f, 0.f, 0.f, 0.f, 0.f};
    const char* hbase = (const char*)hsrc;
    float* wp = &wlds[wv][0];
    int*   sp = &slds[wv][0];
    for (int base = rs; base < re; base += 64) {
        int i = base + lane;
        float w = 0.f;
        int off = 0;
        if (i < re) {
            int s = csr_src[i];
            w = __expf(fminf(leaky(alpha_s[s] + ad), 60.f));
            off = s * 128;
        }
        den += w;
        sp[lane] = off;
        wp[lane] = w;
        int cnt = min(64, re - base);
#pragma unroll 2
        for (int j = slot; j < cnt; j += 8) {
            float wj = wp[j];
            h8_t hv = *reinterpret_cast<const h8_t*>(hbase + sp[j] + gbyte);
#pragma unroll
            for (int k = 0; k < 8; k++) acc8[k] += wj * (float)hv[k];
        }
    }
#pragma unroll
    for (int k = 0; k < 8; k++) {
        acc8[k] += __shfl_xor(acc8[k], 8);
        acc8[k] += __shfl_xor(acc8[k], 16);
        acc8[k] += __shfl_xor(acc8[k], 32);
    }
#pragma unroll
    for (int off = 32; off >= 1; off >>= 1) den += __shfl_xor(den, off);
    if (slot == 0) {
        float inv = 1.f / (den + 1e-16f);
        int cbase = lp * 8;
#pragma unroll
        for (int k = 0; k < 8; k++)
            hrow[wv][cbase + k] = acc8[k] * inv + bias[cbase + k];
    }
    // wave-local LDS handoff (no barrier needed within a wave)
    int j = lane & 31;
    float a = b1s[j];
#pragma unroll 4
    for (int k = 0; k < 64; k++) a += hrow[wv][k] * w1s[k * 32 + j];
    a = fmaxf(a, 0.f);
    float p = a * w2s[j];
#pragma unroll
    for (int off = 16; off >= 1; off >>= 1) p += __shfl_xor(p, off);
    if (lane == 0) out[node] = p + bo2[0];
}

// ---------------- launch ----------------
extern "C" void kernel_launch(void* const* d_in, const int* in_sizes, int n_in,
                              void* d_out, int out_size, void* d_ws, size_t ws_size,
                              hipStream_t stream) {
    const float* x     = (const float*)d_in[0];
    const float* W_emb = (const float*)d_in[1];
    const float* b_emb = (const float*)d_in[2];
    const float* W0    = (const float*)d_in[3];
    const float* as0   = (const float*)d_in[4];
    const float* ad0   = (const float*)d_in[5];
    const float* b0    = (const float*)d_in[6];
    const float* W1    = (const float*)d_in[7];
    const float* as1   = (const float*)d_in[8];
    const float* ad1   = (const float*)d_in[9];
    const float* b1    = (const float*)d_in[10];
    const float* W2    = (const float*)d_in[11];
    const float* as2   = (const float*)d_in[12];
    const float* ad2   = (const float*)d_in[13];
    const float* b2    = (const float*)d_in[14];
    const float* Wo1   = (const float*)d_in[15];
    const float* bo1   = (const float*)d_in[16];
    const float* Wo2   = (const float*)d_in[17];
    const float* bo2   = (const float*)d_in[18];
    const int* eidx    = (const int*)d_in[19];

    const int N = in_sizes[0] / 128;
    const int E = in_sizes[19] / 2;
    const int* esrc = eidx;
    const int* edst = eidx + E;
    const int gmB  = (N + 127) / 128;
    const int Mpad = gmB * 128;
    const int nb   = (N + 255) / 256;

    char* w = (char*)d_ws;
    auto alloc = [&](size_t bytes) {
        char* p = w;
        w += (bytes + 255) & ~(size_t)255;
        return (void*)p;
    };
    _Float16* hOut = (_Float16*)alloc((size_t)Mpad * 256 * 2);
    _Float16* PHh  = (_Float16*)alloc((size_t)Mpad * 256 * 2);
    _Float16* PHl  = (_Float16*)alloc((size_t)Mpad * 256 * 2);
    float* aS      = (float*)alloc((size_t)N * 4 * 4);
    float* aD      = (float*)alloc((size_t)N * 4 * 4);
    int*   row_ptr = (int*)alloc((size_t)(N + 1) * 4);
    int*   cursor  = (int*)alloc((size_t)N * 4);
    int*   cnt     = (int*)alloc((size_t)N * 4);
    int*   bsum    = (int*)alloc((size_t)nb * 4);
    int*   csr     = (int*)alloc((size_t)(E + N) * 4);
    _Float16* WeH  = (_Float16*)alloc(128 * 64 * 2);
    _Float16* WeL  = (_Float16*)alloc(128 * 64 * 2);
    _Float16* W0H  = (_Float16*)alloc(64 * 256 * 2);
    _Float16* W0L  = (_Float16*)alloc(64 * 256 * 2);
    _Float16* W1H  = (_Float16*)alloc(256 * 256 * 2);
    _Float16* W1L  = (_Float16*)alloc(256 * 256 * 2);
    _Float16* W2H  = (_Float16*)alloc(256 * 64 * 2);
    _Float16* W2L  = (_Float16*)alloc(256 * 64 * 2);

    // CSR build (multi-block scan)
    hipMemsetAsync(cnt, 0, (size_t)N * 4, stream);
    hist_kernel<<<(E + 255) / 256, 256, 0, stream>>>(edst, E, cnt);
    blocksum_kernel<<<nb, 256, 0, stream>>>(cnt, N, bsum);
    scanbsum_kernel<<<1, 256, 0, stream>>>(bsum, nb, row_ptr + N);
    rowptr_kernel<<<nb, 256, 0, stream>>>(cnt, bsum, N, row_ptr, cursor);
    scatter_kernel<<<(E + N + 255) / 256, 256, 0, stream>>>(esrc, edst, E, N, cursor, csr);

    // weight planes (fused single launch)
    prep_weights_all<<<dim3(256, 4), 256, 0, stream>>>(W_emb, W0, W1, W2,
                                                       WeH, WeL, W0H, W0L, W1H, W1L, W2H, W2L);

    int gn4 = (N + 3) / 4;

    // embedding: x (fp32) -> relu(x@W_emb+b) as hi/lo planes, direct-A conversion
    gemm_emb_kernel<<<dim3(gmB, 1), 256, 0, stream>>>(x, WeH, WeL, b_emb, PHh, PHl, Mpad, N);

    // GAT layer 0 (K=64, full-B stage)
    gemm_gat0_kernel<<<dim3(gmB, 2), 256, 0, stream>>>(PHh, PHl, W0H, W0L, as0, ad0, hOut, aS, aD, Mpad, N);
    aggregate4_kernel<0><<<gn4, 256, 0, stream>>>(hOut, aS, aD, row_ptr, csr, b0, PHh, PHl, N, Mpad);

    // GAT layer 1 (K=256)
    gemm_gat1_kernel<<<dim3(gmB, 2), 256, 0, stream>>>(PHh, PHl, W1H, W1L, as1, ad1, hOut, aS, aD, Mpad, N, 256);
    aggregate4_kernel<1><<<gn4, 256, 0, stream>>>(hOut, aS, aD, row_ptr, csr, b1, PHh, PHl, N, Mpad);

    // GAT layer 2 (1 head) + fused head MLP
    gemm_l2_kernel<<<dim3(gmB, 1), 256, 0, stream>>>(PHh, PHl, W2H, W2L, as2, ad2, hOut, aS, aD, Mpad, N, 256);
    agg1_mlp_kernel<<<gn4, 256, 0, stream>>>(hOut, aS, aD, row_ptr, csr, b2,
                                             Wo1, bo1, Wo2, bo2, (float*)d_out, N);
}

// Round 15
// 474.876 us; speedup vs baseline: 1.6817x; 1.0203x over previous
//
#include <hip/hip_runtime.h>

typedef _Float16 h8_t __attribute__((ext_vector_type(8)));
typedef _Float16 h4_t __attribute__((ext_vector_type(4)));
typedef float floatx4 __attribute__((ext_vector_type(4)));

__device__ __forceinline__ float leaky(float v) { return v >= 0.f ? v : 0.2f * v; }

// ---------------- CSR build ----------------
__global__ void hist_kernel(const int* __restrict__ dst, int E, int* __restrict__ cnt) {
    int e = blockIdx.x * blockDim.x + threadIdx.x;
    if (e < E) atomicAdd(&cnt[dst[e]], 1);
}

__global__ __launch_bounds__(256) void blocksum_kernel(const int* __restrict__ cnt, int N,
                                                       int* __restrict__ bsum) {
    __shared__ int red[256];
    int tid = threadIdx.x;
    int idx = blockIdx.x * 256 + tid;
    red[tid] = idx < N ? cnt[idx] + 1 : 0;
    __syncthreads();
#pragma unroll
    for (int off = 128; off >= 1; off >>= 1) {
        if (tid < off) red[tid] += red[tid + off];
        __syncthreads();
    }
    if (tid == 0) bsum[blockIdx.x] = red[0];
}

__global__ __launch_bounds__(256) void scanbsum_kernel(int* __restrict__ bsum, int nb,
                                                       int* __restrict__ total) {
    __shared__ int part[256];
    int tid = threadIdx.x;
    int per = (nb + 255) / 256;
    int s0 = tid * per, s1 = min(s0 + per, nb);
    int s = 0;
    for (int i = s0; i < s1; i++) s += bsum[i];
    part[tid] = s;
    __syncthreads();
    for (int off = 1; off < 256; off <<= 1) {
        int v = (tid >= off) ? part[tid - off] : 0;
        __syncthreads();
        part[tid] += v;
        __syncthreads();
    }
    int base = (tid == 0) ? 0 : part[tid - 1];
    for (int i = s0; i < s1; i++) {
        int v = bsum[i];
        bsum[i] = base;
        base += v;
    }
    if (tid == 255) *total = part[255];
}

__global__ __launch_bounds__(256) void rowptr_kernel(const int* __restrict__ cnt,
                                                     const int* __restrict__ bsum, int N,
                                                     int* __restrict__ row_ptr,
                                                     int* __restrict__ cursor) {
    __shared__ int lds[256];
    int tid = threadIdx.x;
    int idx = blockIdx.x * 256 + tid;
    int v = idx < N ? cnt[idx] + 1 : 0;
    lds[tid] = v;
    __syncthreads();
    for (int off = 1; off < 256; off <<= 1) {
        int t = (tid >= off) ? lds[tid - off] : 0;
        __syncthreads();
        lds[tid] += t;
        __syncthreads();
    }
    if (idx < N) {
        int p = bsum[blockIdx.x] + lds[tid] - v;
        row_ptr[idx] = p;
        cursor[idx] = p;
    }
}

__global__ void scatter_kernel(const int* __restrict__ src, const int* __restrict__ dst,
                               int E, int N, int* __restrict__ cursor, int* __restrict__ csr_src) {
    int e = blockIdx.x * blockDim.x + threadIdx.x;
    if (e >= E + N) return;
    int s, d;
    if (e < E) { s = src[e]; d = dst[e]; }
    else       { s = e - E;  d = s; }
    int pos = atomicAdd(&cursor[d], 1);
    csr_src[pos] = s;
}

// ---------------- fused weight prep ----------------
__global__ void prep_weights_all(const float* __restrict__ W_emb, const float* __restrict__ W0,
                                 const float* __restrict__ W1, const float* __restrict__ W2,
                                 _Float16* __restrict__ WeH, _Float16* __restrict__ WeL,
                                 _Float16* __restrict__ W0H, _Float16* __restrict__ W0L,
                                 _Float16* __restrict__ W1H, _Float16* __restrict__ W1L,
                                 _Float16* __restrict__ W2H, _Float16* __restrict__ W2L) {
    int which = blockIdx.y;
    const float* W;
    _Float16 *Wh, *Wl;
    int K, N;
    if (which == 0)      { W = W_emb; Wh = WeH; Wl = WeL; K = 128; N = 64; }
    else if (which == 1) { W = W0;    Wh = W0H; Wl = W0L; K = 64;  N = 256; }
    else if (which == 2) { W = W1;    Wh = W1H; Wl = W1L; K = 256; N = 256; }
    else                 { W = W2;    Wh = W2H; Wl = W2L; K = 256; N = 64; }
    int idx = blockIdx.x * blockDim.x + threadIdx.x;
    if (idx >= K * N) return;
    int k = idx / N, n = idx % N;
    float v = W[idx];
    _Float16 hi = (_Float16)v;
    _Float16 lo = (_Float16)(v - (float)hi);
    size_t o = ((size_t)(k >> 3) * N + n) * 8 + (k & 7);
    Wh[o] = hi; Wl[o] = lo;
}

// ---------------- embedding GEMM: direct-x A, full-B LDS stage, -> hi/lo planes ----------------
__global__ __launch_bounds__(256) void gemm_emb_kernel(
        const float* __restrict__ X,
        const _Float16* __restrict__ Bh, const _Float16* __restrict__ Bl,
        const float* __restrict__ bias,
        _Float16* __restrict__ Ph, _Float16* __restrict__ Pl,
        int Mpad, int M) {
    const int Nn = 64, K = 128;
    __shared__ _Float16 Bs[2][16][64][8];
    __shared__ _Float16 stH[4][16][72];
    __shared__ _Float16 stL[4][16][72];
    int tid = threadIdx.x;
    int wv = tid >> 6, lane = tid & 63;
    int m16 = lane & 15, quad = lane >> 4;
    int row0 = blockIdx.x * 128 + wv * 32;

#pragma unroll
    for (int cc = 0; cc < 8; cc++) {
        int c = tid + cc * 256;
        int plane = c >> 10, rem = c & 1023, q = rem >> 6, col = rem & 63;
        const _Float16* srcp = (plane ? Bl : Bh) + ((size_t)q * Nn + col) * 8;
        *reinterpret_cast<h8_t*>(&Bs[plane][q][col][0]) = *reinterpret_cast<const h8_t*>(srcp);
    }
    __syncthreads();

    floatx4 acc[2][4];
#pragma unroll
    for (int t = 0; t < 2; t++)
#pragma unroll
        for (int c = 0; c < 4; c++)
#pragma unroll
            for (int i = 0; i < 4; i++) acc[t][c][i] = 0.f;

    int r0 = row0 + m16, r1 = row0 + 16 + m16;
#pragma unroll
    for (int kt4 = 0; kt4 < 4; kt4++) {
        int kcol = kt4 * 32 + quad * 8;
        float vs0[8] = {0,0,0,0,0,0,0,0}, vs1[8] = {0,0,0,0,0,0,0,0};
        if (r0 < M) {
            const float4* p = (const float4*)(X + (size_t)r0 * K + kcol);
            float4 a = p[0], b = p[1];
            vs0[0]=a.x; vs0[1]=a.y; vs0[2]=a.z; vs0[3]=a.w;
            vs0[4]=b.x; vs0[5]=b.y; vs0[6]=b.z; vs0[7]=b.w;
        }
        if (r1 < M) {
            const float4* p = (const float4*)(X + (size_t)r1 * K + kcol);
            float4 a = p[0], b = p[1];
            vs1[0]=a.x; vs1[1]=a.y; vs1[2]=a.z; vs1[3]=a.w;
            vs1[4]=b.x; vs1[5]=b.y; vs1[6]=b.z; vs1[7]=b.w;
        }
        h8_t ah0, al0, ah1, al1;
#pragma unroll
        for (int j = 0; j < 8; j++) {
            _Float16 hi0 = (_Float16)vs0[j];
            ah0[j] = hi0; al0[j] = (_Float16)(vs0[j] - (float)hi0);
            _Float16 hi1 = (_Float16)vs1[j];
            ah1[j] = hi1; al1[j] = (_Float16)(vs1[j] - (float)hi1);
        }
        int kq = kt4 * 4 + quad;
#pragma unroll
        for (int c = 0; c < 4; c++) {
            h8_t bh = *reinterpret_cast<const h8_t*>(&Bs[0][kq][c * 16 + m16][0]);
            h8_t bl = *reinterpret_cast<const h8_t*>(&Bs[1][kq][c * 16 + m16][0]);
            acc[0][c] = __builtin_amdgcn_mfma_f32_16x16x32_f16(ah0, bh, acc[0][c], 0, 0, 0);
            acc[1][c] = __builtin_amdgcn_mfma_f32_16x16x32_f16(ah1, bh, acc[1][c], 0, 0, 0);
            acc[0][c] = __builtin_amdgcn_mfma_f32_16x16x32_f16(ah0, bl, acc[0][c], 0, 0, 0);
            acc[1][c] = __builtin_amdgcn_mfma_f32_16x16x32_f16(ah1, bl, acc[1][c], 0, 0, 0);
            acc[0][c] = __builtin_amdgcn_mfma_f32_16x16x32_f16(al0, bh, acc[0][c], 0, 0, 0);
            acc[1][c] = __builtin_amdgcn_mfma_f32_16x16x32_f16(al1, bh, acc[1][c], 0, 0, 0);
        }
    }

    // epilogue: st buffers are wave-local -> no barriers needed
#pragma unroll
    for (int t = 0; t < 2; t++) {
#pragma unroll
        for (int c = 0; c < 4; c++) {
            float bv = bias[c * 16 + m16];
#pragma unroll
            for (int i = 0; i < 4; i++) {
                float v = fmaxf(acc[t][c][i] + bv, 0.f);
                _Float16 hi = (_Float16)v;
                stH[wv][quad * 4 + i][c * 16 + m16] = hi;
                stL[wv][quad * 4 + i][c * 16 + m16] = (_Float16)(v - (float)hi);
            }
        }
        int rowChunk = row0 + t * 16;
#pragma unroll
        for (int it = 0; it < 2; it++) {
            int lid = it * 64 + lane;
            int kg = lid >> 4, rloc = lid & 15;
            h8_t vh = *reinterpret_cast<const h8_t*>(&stH[wv][rloc][kg * 8]);
            h8_t vl = *reinterpret_cast<const h8_t*>(&stL[wv][rloc][kg * 8]);
            size_t o = ((size_t)kg * Mpad + rowChunk + rloc) * 8;
            *reinterpret_cast<h8_t*>(Ph + o) = vh;
            *reinterpret_cast<h8_t*>(Pl + o) = vl;
        }
    }
}

// ---------------- GAT GEMM layer0 (K=64, full-B stage) + fused alphas ----------------
__global__ __launch_bounds__(256) void gemm_gat0_kernel(
        const _Float16* __restrict__ Ah, const _Float16* __restrict__ Al,
        const _Float16* __restrict__ Bh, const _Float16* __restrict__ Bl,
        const float* __restrict__ a_src, const float* __restrict__ a_dst,
        _Float16* __restrict__ hOut, float* __restrict__ aS, float* __restrict__ aD,
        int Mpad, int M) {
    const int Nn = 256;
    __shared__ _Float16 Bs[2][8][128][8];
    __shared__ _Float16 st[4][16][136];
    int tid = threadIdx.x;
    int wv = tid >> 6, lane = tid & 63;
    int m16 = lane & 15, quad = lane >> 4;
    int row0 = blockIdx.x * 128 + wv * 32;
    int colBase = blockIdx.y * 128;
    size_t kqbase = (size_t)colBase * 8;

#pragma unroll
    for (int cc = 0; cc < 8; cc++) {
        int c = tid + cc * 256;
        int plane = c >> 10, rem = c & 1023, q = rem >> 7, col = rem & 127;
        const _Float16* srcp = (plane ? Bl : Bh) + kqbase + ((size_t)q * Nn + col) * 8;
        *reinterpret_cast<h8_t*>(&Bs[plane][q][col][0]) = *reinterpret_cast<const h8_t*>(srcp);
    }
    __syncthreads();

    floatx4 acc[2][8];
#pragma unroll
    for (int t = 0; t < 2; t++)
#pragma unroll
        for (int c = 0; c < 8; c++)
#pragma unroll
            for (int i = 0; i < 4; i++) acc[t][c][i] = 0.f;

#pragma unroll
    for (int kt = 0; kt < 2; kt++) {
        int kq = kt * 4 + quad;
        size_t aoff = ((size_t)kq * Mpad + row0 + m16) * 8;
        h8_t ah0 = *reinterpret_cast<const h8_t*>(Ah + aoff);
        h8_t ah1 = *reinterpret_cast<const h8_t*>(Ah + aoff + 128);
        h8_t al0 = *reinterpret_cast<const h8_t*>(Al + aoff);
        h8_t al1 = *reinterpret_cast<const h8_t*>(Al + aoff + 128);
#pragma unroll
        for (int c = 0; c < 8; c++) {
            h8_t bh = *reinterpret_cast<const h8_t*>(&Bs[0][kq][c * 16 + m16][0]);
            h8_t bl = *reinterpret_cast<const h8_t*>(&Bs[1][kq][c * 16 + m16][0]);
            acc[0][c] = __builtin_amdgcn_mfma_f32_16x16x32_f16(ah0, bh, acc[0][c], 0, 0, 0);
            acc[1][c] = __builtin_amdgcn_mfma_f32_16x16x32_f16(ah1, bh, acc[1][c], 0, 0, 0);
            acc[0][c] = __builtin_amdgcn_mfma_f32_16x16x32_f16(ah0, bl, acc[0][c], 0, 0, 0);
            acc[1][c] = __builtin_amdgcn_mfma_f32_16x16x32_f16(ah1, bl, acc[1][c], 0, 0, 0);
            acc[0][c] = __builtin_amdgcn_mfma_f32_16x16x32_f16(al0, bh, acc[0][c], 0, 0, 0);
            acc[1][c] = __builtin_amdgcn_mfma_f32_16x16x32_f16(al1, bh, acc[1][c], 0, 0, 0);
        }
    }

    float asv[8], adv[8];
#pragma unroll
    for (int c = 0; c < 8; c++) {
        asv[c] = a_src[colBase + c * 16 + m16];
        adv[c] = a_dst[colBase + c * 16 + m16];
    }
    int hb = colBase >> 6;
#pragma unroll
    for (int t = 0; t < 2; t++) {
#pragma unroll
        for (int i = 0; i < 4; i++) {
            int r = row0 + t * 16 + quad * 4 + i;
            float s0 = 0.f, d0 = 0.f, s1 = 0.f, d1 = 0.f;
#pragma unroll
            for (int c = 0; c < 8; c++) {
                float v = acc[t][c][i];
                if (c < 4) { s0 += v * asv[c]; d0 += v * adv[c]; }
                else       { s1 += v * asv[c]; d1 += v * adv[c]; }
            }
#pragma unroll
            for (int off = 1; off < 16; off <<= 1) {
                s0 += __shfl_xor(s0, off);
                d0 += __shfl_xor(d0, off);
                s1 += __shfl_xor(s1, off);
                d1 += __shfl_xor(d1, off);
            }
            if (m16 == 0 && r < M) {
                aS[r * 4 + hb] = s0;     aD[r * 4 + hb] = d0;
                aS[r * 4 + hb + 1] = s1; aD[r * 4 + hb + 1] = d1;
            }
        }
    }

    // wave-local epilogue (no barriers)
#pragma unroll
    for (int t = 0; t < 2; t++) {
#pragma unroll
        for (int c = 0; c < 8; c++)
#pragma unroll
            for (int i = 0; i < 4; i++)
                st[wv][quad * 4 + i][c * 16 + m16] = (_Float16)acc[t][c][i];
        int rowChunk = row0 + t * 16;
#pragma unroll
        for (int it = 0; it < 4; it++) {
            int lid = it * 64 + lane;
            int rloc = lid >> 4, u = lid & 15;
            h8_t v = *reinterpret_cast<const h8_t*>(&st[wv][rloc][u * 8]);
            *reinterpret_cast<h8_t*>(hOut + (size_t)(rowChunk + rloc) * 256 + colBase + u * 8) = v;
        }
    }
}

// ---------------- GAT GEMM layer1 (K=256, double-buffered) + fused alphas ----------------
__global__ __launch_bounds__(256) void gemm_gat1_kernel(
        const _Float16* __restrict__ Ah, const _Float16* __restrict__ Al,
        const _Float16* __restrict__ Bh, const _Float16* __restrict__ Bl,
        const float* __restrict__ a_src, const float* __restrict__ a_dst,
        _Float16* __restrict__ hOut, float* __restrict__ aS, float* __restrict__ aD,
        int Mpad, int M, int K) {
    const int Nn = 256;
    __shared__ _Float16 Bs[2][4][128][8];
    __shared__ _Float16 st[4][16][136];
    int tid = threadIdx.x;
    int wv = tid >> 6, lane = tid & 63;
    int m16 = lane & 15, quad = lane >> 4;
    int row0 = blockIdx.x * 128 + wv * 32;
    int colBase = blockIdx.y * 128;

    floatx4 acc[2][8];
#pragma unroll
    for (int t = 0; t < 2; t++)
#pragma unroll
        for (int c = 0; c < 8; c++)
#pragma unroll
            for (int i = 0; i < 4; i++) acc[t][c][i] = 0.f;

    // loop-invariant staging decode
    int sPlane[4], sQ[4], sCol[4];
    const _Float16* sBase[4];
#pragma unroll
    for (int cc = 0; cc < 4; cc++) {
        int c = tid + cc * 256;
        sPlane[cc] = c >> 9;
        int rem = c & 511;
        sQ[cc] = rem >> 7;
        sCol[cc] = rem & 127;
        sBase[cc] = (sPlane[cc] ? Bl : Bh) + ((size_t)sQ[cc] * Nn + sCol[cc]) * 8;
    }

    size_t aoff = ((size_t)quad * Mpad + row0 + m16) * 8;
    size_t kqbase = (size_t)colBase * 8;
    const size_t aStep = (size_t)Mpad * 32;
    const size_t bStep = (size_t)Nn * 32;

    // prologue: load first A + B tiles into registers
    h8_t aR[4], bR[4];
    aR[0] = *reinterpret_cast<const h8_t*>(Ah + aoff);
    aR[1] = *reinterpret_cast<const h8_t*>(Ah + aoff + 128);
    aR[2] = *reinterpret_cast<const h8_t*>(Al + aoff);
    aR[3] = *reinterpret_cast<const h8_t*>(Al + aoff + 128);
#pragma unroll
    for (int cc = 0; cc < 4; cc++)
        bR[cc] = *reinterpret_cast<const h8_t*>(sBase[cc] + kqbase);

    for (int kt = 0; kt < K; kt += 32) {
        // write staged B regs -> LDS
#pragma unroll
        for (int cc = 0; cc < 4; cc++)
            *reinterpret_cast<h8_t*>(&Bs[sPlane[cc]][sQ[cc]][sCol[cc]][0]) = bR[cc];
        __syncthreads();
        // prefetch next iteration (flies during MFMA below)
        h8_t aN[4], bN[4];
        bool more = (kt + 32) < K;
        if (more) {
            aoff += aStep; kqbase += bStep;
            aN[0] = *reinterpret_cast<const h8_t*>(Ah + aoff);
            aN[1] = *reinterpret_cast<const h8_t*>(Ah + aoff + 128);
            aN[2] = *reinterpret_cast<const h8_t*>(Al + aoff);
            aN[3] = *reinterpret_cast<const h8_t*>(Al + aoff + 128);
#pragma unroll
            for (int cc = 0; cc < 4; cc++)
                bN[cc] = *reinterpret_cast<const h8_t*>(sBase[cc] + kqbase);
        }
#pragma unroll
        for (int c = 0; c < 8; c++) {
            h8_t bh = *reinterpret_cast<const h8_t*>(&Bs[0][quad][c * 16 + m16][0]);
            h8_t bl = *reinterpret_cast<const h8_t*>(&Bs[1][quad][c * 16 + m16][0]);
            acc[0][c] = __builtin_amdgcn_mfma_f32_16x16x32_f16(aR[0], bh, acc[0][c], 0, 0, 0);
            acc[1][c] = __builtin_amdgcn_mfma_f32_16x16x32_f16(aR[1], bh, acc[1][c], 0, 0, 0);
            acc[0][c] = __builtin_amdgcn_mfma_f32_16x16x32_f16(aR[0], bl, acc[0][c], 0, 0, 0);
            acc[1][c] = __builtin_amdgcn_mfma_f32_16x16x32_f16(aR[1], bl, acc[1][c], 0, 0, 0);
            acc[0][c] = __builtin_amdgcn_mfma_f32_16x16x32_f16(aR[2], bh, acc[0][c], 0, 0, 0);
            acc[1][c] = __builtin_amdgcn_mfma_f32_16x16x32_f16(aR[3], bh, acc[1][c], 0, 0, 0);
        }
        __syncthreads();
        if (more) {
#pragma unroll
            for (int j = 0; j < 4; j++) { aR[j] = aN[j]; bR[j] = bN[j]; }
        }
    }

    float asv[8], adv[8];
#pragma unroll
    for (int c = 0; c < 8; c++) {
        asv[c] = a_src[colBase + c * 16 + m16];
        adv[c] = a_dst[colBase + c * 16 + m16];
    }
    int hb = colBase >> 6;
#pragma unroll
    for (int t = 0; t < 2; t++) {
#pragma unroll
        for (int i = 0; i < 4; i++) {
            int r = row0 + t * 16 + quad * 4 + i;
            float s0 = 0.f, d0 = 0.f, s1 = 0.f, d1 = 0.f;
#pragma unroll
            for (int c = 0; c < 8; c++) {
                float v = acc[t][c][i];
                if (c < 4) { s0 += v * asv[c]; d0 += v * adv[c]; }
                else       { s1 += v * asv[c]; d1 += v * adv[c]; }
            }
#pragma unroll
            for (int off = 1; off < 16; off <<= 1) {
                s0 += __shfl_xor(s0, off);
                d0 += __shfl_xor(d0, off);
                s1 += __shfl_xor(s1, off);
                d1 += __shfl_xor(d1, off);
            }
            if (m16 == 0 && r < M) {
                aS[r * 4 + hb] = s0;     aD[r * 4 + hb] = d0;
                aS[r * 4 + hb + 1] = s1; aD[r * 4 + hb + 1] = d1;
            }
        }
    }

    // wave-local epilogue (no barriers)
#pragma unroll
    for (int t = 0; t < 2; t++) {
#pragma unroll
        for (int c = 0; c < 8; c++)
#pragma unroll
            for (int i = 0; i < 4; i++)
                st[wv][quad * 4 + i][c * 16 + m16] = (_Float16)acc[t][c][i];
        int rowChunk = row0 + t * 16;
#pragma unroll
        for (int it = 0; it < 4; it++) {
            int lid = it * 64 + lane;
            int rloc = lid >> 4, u = lid & 15;
            h8_t v = *reinterpret_cast<const h8_t*>(&st[wv][rloc][u * 8]);
            *reinterpret_cast<h8_t*>(hOut + (size_t)(rowChunk + rloc) * 256 + colBase + u * 8) = v;
        }
    }
}

// ---------------- layer-2 GEMM (Nn=64, K=256, double-buffered) + fused alphas ----------------
__global__ __launch_bounds__(256) void gemm_l2_kernel(
        const _Float16* __restrict__ Ah, const _Float16* __restrict__ Al,
        const _Float16* __restrict__ Bh, const _Float16* __restrict__ Bl,
        const float* __restrict__ a_src, const float* __restrict__ a_dst,
        _Float16* __restrict__ hOut, float* __restrict__ aS, float* __restrict__ aD,
        int Mpad, int M, int K) {
    const int Nn = 64;
    __shared__ _Float16 Bs[2][4][64][8];
    __shared__ _Float16 st[4][16][72];
    int tid = threadIdx.x;
    int wv = tid >> 6, lane = tid & 63;
    int m16 = lane & 15, quad = lane >> 4;
    int row0 = blockIdx.x * 128 + wv * 32;

    floatx4 acc[2][4];
#pragma unroll
    for (int t = 0; t < 2; t++)
#pragma unroll
        for (int c = 0; c < 4; c++)
#pragma unroll
            for (int i = 0; i < 4; i++) acc[t][c][i] = 0.f;

    int sPlane[2], sQ[2], sCol[2];
    const _Float16* sBase[2];
#pragma unroll
    for (int cc = 0; cc < 2; cc++) {
        int c = tid + cc * 256;
        sPlane[cc] = c >> 8;
        int rem = c & 255;
        sQ[cc] = rem >> 6;
        sCol[cc] = rem & 63;
        sBase[cc] = (sPlane[cc] ? Bl : Bh) + ((size_t)sQ[cc] * Nn + sCol[cc]) * 8;
    }

    size_t aoff = ((size_t)quad * Mpad + row0 + m16) * 8;
    size_t kqbase = 0;
    const size_t aStep = (size_t)Mpad * 32;
    const size_t bStep = (size_t)Nn * 32;

    h8_t aR[4], bR[2];
    aR[0] = *reinterpret_cast<const h8_t*>(Ah + aoff);
    aR[1] = *reinterpret_cast<const h8_t*>(Ah + aoff + 128);
    aR[2] = *reinterpret_cast<const h8_t*>(Al + aoff);
    aR[3] = *reinterpret_cast<const h8_t*>(Al + aoff + 128);
#pragma unroll
    for (int cc = 0; cc < 2; cc++)
        bR[cc] = *reinterpret_cast<const h8_t*>(sBase[cc] + kqbase);

    for (int kt = 0; kt < K; kt += 32) {
#pragma unroll
        for (int cc = 0; cc < 2; cc++)
            *reinterpret_cast<h8_t*>(&Bs[sPlane[cc]][sQ[cc]][sCol[cc]][0]) = bR[cc];
        __syncthreads();
        h8_t aN[4], bN[2];
        bool more = (kt + 32) < K;
        if (more) {
            aoff += aStep; kqbase += bStep;
            aN[0] = *reinterpret_cast<const h8_t*>(Ah + aoff);
            aN[1] = *reinterpret_cast<const h8_t*>(Ah + aoff + 128);
            aN[2] = *reinterpret_cast<const h8_t*>(Al + aoff);
            aN[3] = *reinterpret_cast<const h8_t*>(Al + aoff + 128);
#pragma unroll
            for (int cc = 0; cc < 2; cc++)
                bN[cc] = *reinterpret_cast<const h8_t*>(sBase[cc] + kqbase);
        }
#pragma unroll
        for (int c = 0; c < 4; c++) {
            h8_t bh = *reinterpret_cast<const h8_t*>(&Bs[0][quad][c * 16 + m16][0]);
            h8_t bl = *reinterpret_cast<const h8_t*>(&Bs[1][quad][c * 16 + m16][0]);
            acc[0][c] = __builtin_amdgcn_mfma_f32_16x16x32_f16(aR[0], bh, acc[0][c], 0, 0, 0);
            acc[1][c] = __builtin_amdgcn_mfma_f32_16x16x32_f16(aR[1], bh, acc[1][c], 0, 0, 0);
            acc[0][c] = __builtin_amdgcn_mfma_f32_16x16x32_f16(aR[0], bl, acc[0][c], 0, 0, 0);
            acc[1][c] = __builtin_amdgcn_mfma_f32_16x16x32_f16(aR[1], bl, acc[1][c], 0, 0, 0);
            acc[0][c] = __builtin_amdgcn_mfma_f32_16x16x32_f16(aR[2], bh, acc[0][c], 0, 0, 0);
            acc[1][c] = __builtin_amdgcn_mfma_f32_16x16x32_f16(aR[3], bh, acc[1][c], 0, 0, 0);
        }
        __syncthreads();
        if (more) {
            aR[0] = aN[0]; aR[1] = aN[1]; aR[2] = aN[2]; aR[3] = aN[3];
            bR[0] = bN[0]; bR[1] = bN[1];
        }
    }

    float asv[4], adv[4];
#pragma unroll
    for (int c = 0; c < 4; c++) {
        asv[c] = a_src[c * 16 + m16];
        adv[c] = a_dst[c * 16 + m16];
    }
#pragma unroll
    for (int t = 0; t < 2; t++) {
#pragma unroll
        for (int i = 0; i < 4; i++) {
            int r = row0 + t * 16 + quad * 4 + i;
            float s0 = 0.f, d0 = 0.f;
#pragma unroll
            for (int c = 0; c < 4; c++) {
                float v = acc[t][c][i];
                s0 += v * asv[c]; d0 += v * adv[c];
            }
#pragma unroll
            for (int off = 1; off < 16; off <<= 1) {
                s0 += __shfl_xor(s0, off);
                d0 += __shfl_xor(d0, off);
            }
            if (m16 == 0 && r < M) { aS[r] = s0; aD[r] = d0; }
        }
    }

    // wave-local epilogue (no barriers)
#pragma unroll
    for (int t = 0; t < 2; t++) {
#pragma unroll
        for (int c = 0; c < 4; c++)
#pragma unroll
            for (int i = 0; i < 4; i++)
                st[wv][quad * 4 + i][c * 16 + m16] = (_Float16)acc[t][c][i];
        int rowChunk = row0 + t * 16;
#pragma unroll
        for (int it = 0; it < 2; it++) {
            int lid = it * 64 + lane;
            int rloc = lid >> 3, u = lid & 7;
            h8_t v = *reinterpret_cast<const h8_t*>(&st[wv][rloc][u * 8]);
            *reinterpret_cast<h8_t*>(hOut + (size_t)(rowChunk + rloc) * 64 + u * 8) = v;
        }
    }
}

// ---------------- aggregation H=4 (unchanged) ----------------
template <int TAG>
__global__ __launch_bounds__(256) void aggregate4_kernel(const _Float16* __restrict__ hsrc,
                                                         const float* __restrict__ alpha_s,
                                                         const float* __restrict__ alpha_d,
                                                         const int* __restrict__ row_ptr,
                                                         const int* __restrict__ csr_src,
                                                         const float* __restrict__ bias,
                                                         _Float16* __restrict__ outH,
                                                         _Float16* __restrict__ outL,
                                                         int N, int Mpad) {
    __shared__ float wlds[4][64][4];
    __shared__ int   slds[4][64];
    int wv = threadIdx.x >> 6, lane = threadIdx.x & 63;
    int node = blockIdx.x * 4 + wv;
    if (node >= N) return;
    int rs = row_ptr[node], re = row_ptr[node + 1];
    int slot = lane >> 5, lp = lane & 31;
    int ghead = lp >> 3;
    int gbyte = lp * 16;
    float4 ad4 = *(const float4*)(alpha_d + (size_t)node * 4);

    float den0 = 0.f, den1 = 0.f, den2 = 0.f, den3 = 0.f;
    float acc8[8] = {0.f, 0.f, 0.f, 0.f, 0.f, 0.f, 0.f, 0.f};
    float* wp = &wlds[wv][0][0];
    int*   sp = &slds[wv][0];
    const char* hbase = (const char*)hsrc;
    for (int base = rs; base < re; base += 64) {
        int i = base + lane;
        float w0 = 0.f, w1 = 0.f, w2 = 0.f, w3 = 0.f;
        int off = 0;
        if (i < re) {
            int s = csr_src[i];
            float4 as = *(const float4*)(alpha_s + (size_t)s * 4);
            w0 = __expf(fminf(leaky(as.x + ad4.x), 60.f));
            w1 = __expf(fminf(leaky(as.y + ad4.y), 60.f));
            w2 = __expf(fminf(leaky(as.z + ad4.z), 60.f));
            w3 = __expf(fminf(leaky(as.w + ad4.w), 60.f));
            off = s * 512;
        }
        den0 += w0; den1 += w1; den2 += w2; den3 += w3;
        sp[lane] = off;
        *(float4*)(wp + lane * 4) = make_float4(w0, w1, w2, w3);
        int cnt = min(64, re - base);
#pragma unroll 2
        for (int j = slot; j < cnt; j += 2) {
            int o2 = sp[j];
            float w = wp[j * 4 + ghead];
            h8_t hv = *reinterpret_cast<const h8_t*>(hbase + o2 + gbyte);
#pragma unroll
            for (int k = 0; k < 8; k++) acc8[k] += w * (float)hv[k];
        }
    }
#pragma unroll
    for (int k = 0; k < 8; k++) acc8[k] += __shfl_xor(acc8[k], 32);
#pragma unroll
    for (int off = 32; off >= 1; off >>= 1) {
        den0 += __shfl_xor(den0, off);
        den1 += __shfl_xor(den1, off);
        den2 += __shfl_xor(den2, off);
        den3 += __shfl_xor(den3, off);
    }
    if (slot == 0) {
        float den = (ghead & 2) ? ((ghead & 1) ? den3 : den2) : ((ghead & 1) ? den1 : den0);
        float inv = 1.f / (den + 1e-16f);
        int cbase = lp * 8;
        float4 b0 = *(const float4*)(bias + cbase);
        float4 b1 = *(const float4*)(bias + cbase + 4);
        float bv[8] = {b0.x, b0.y, b0.z, b0.w, b1.x, b1.y, b1.z, b1.w};
        h8_t hv, lv;
#pragma unroll
        for (int k = 0; k < 8; k++) {
            float v = fmaxf(acc8[k] * inv + bv[k], 0.f);
            _Float16 hi = (_Float16)v;
            hv[k] = hi;
            lv[k] = (_Float16)(v - (float)hi);
        }
        size_t o = ((size_t)lp * Mpad + node) * 8;
        *reinterpret_cast<h8_t*>(outH + o) = hv;
        *reinterpret_cast<h8_t*>(outL + o) = lv;
    }
}

// ---------------- fused aggregation H=1 + head MLP ----------------
__global__ __launch_bounds__(256) void agg1_mlp_kernel(const _Float16* __restrict__ hsrc,
                                                       const float* __restrict__ alpha_s,
                                                       const float* __restrict__ alpha_d,
                                                       const int* __restrict__ row_ptr,
                                                       const int* __restrict__ csr_src,
                                                       const float* __restrict__ bias,
                                                       const float* __restrict__ Wo1,
                                                       const float* __restrict__ bo1,
                                                       const float* __restrict__ Wo2,
                                                       const float* __restrict__ bo2,
                                                       float* __restrict__ out, int N) {
    __shared__ float wlds[4][64];
    __shared__ int   slds[4][64];
    __shared__ float hrow[4][64];
    __shared__ float w1s[64 * 32];
    __shared__ float w2s[32];
    __shared__ float b1s[32];
    int tid = threadIdx.x;
#pragma unroll
    for (int i = 0; i < 8; i++) w1s[tid + i * 256] = Wo1[tid + i * 256];
    if (tid < 32) { w2s[tid] = Wo2[tid]; b1s[tid] = bo1[tid]; }
    __syncthreads();

    int wv = tid >> 6, lane = tid & 63;
    int node = blockIdx.x * 4 + wv;
    if (node >= N) return;
    int rs = row_ptr[node], re = row_ptr[node + 1];
    float ad = alpha_d[node];
    int slot = lane >> 3, lp = lane & 7;
    int gbyte = lp * 16;

    float den = 0.f;
    float acc8[8] = {0.f, 0.f, 0.f, 0.f, 0.f, 0.f, 0.f, 0.f};
    const char* hbase = (const char*)hsrc;
    float* wp = &wlds[wv][0];
    int*   sp = &slds[wv][0];
    for (int base = rs; base < re; base += 64) {
        int i = base + lane;
        float w = 0.f;
        int off = 0;
        if (i < re) {
            int s = csr_src[i];
            w = __expf(fminf(leaky(alpha_s[s] + ad), 60.f));
            off = s * 128;
        }
        den += w;
        sp[lane] = off;
        wp[lane] = w;
        int cnt = min(64, re - base);
#pragma unroll 2
        for (int j = slot; j < cnt; j += 8) {
            float wj = wp[j];
            h8_t hv = *reinterpret_cast<const h8_t*>(hbase + sp[j] + gbyte);
#pragma unroll
            for (int k = 0; k < 8; k++) acc8[k] += wj * (float)hv[k];
        }
    }
#pragma unroll
    for (int k = 0; k < 8; k++) {
        acc8[k] += __shfl_xor(acc8[k], 8);
        acc8[k] += __shfl_xor(acc8[k], 16);
        acc8[k] += __shfl_xor(acc8[k], 32);
    }
#pragma unroll
    for (int off = 32; off >= 1; off >>= 1) den += __shfl_xor(den, off);
    if (slot == 0) {
        float inv = 1.f / (den + 1e-16f);
        int cbase = lp * 8;
#pragma unroll
        for (int k = 0; k < 8; k++)
            hrow[wv][cbase + k] = acc8[k] * inv + bias[cbase + k];
    }
    int j = lane & 31;
    float a = b1s[j];
#pragma unroll 4
    for (int k = 0; k < 64; k++) a += hrow[wv][k] * w1s[k * 32 + j];
    a = fmaxf(a, 0.f);
    float p = a * w2s[j];
#pragma unroll
    for (int off = 16; off >= 1; off >>= 1) p += __shfl_xor(p, off);
    if (lane == 0) out[node] = p + bo2[0];
}

// ---------------- launch ----------------
extern "C" void kernel_launch(void* const* d_in, const int* in_sizes, int n_in,
                              void* d_out, int out_size, void* d_ws, size_t ws_size,
                              hipStream_t stream) {
    const float* x     = (const float*)d_in[0];
    const float* W_emb = (const float*)d_in[1];
    const float* b_emb = (const float*)d_in[2];
    const float* W0    = (const float*)d_in[3];
    const float* as0   = (const float*)d_in[4];
    const float* ad0   = (const float*)d_in[5];
    const float* b0    = (const float*)d_in[6];
    const float* W1    = (const float*)d_in[7];
    const float* as1   = (const float*)d_in[8];
    const float* ad1   = (const float*)d_in[9];
    const float* b1    = (const float*)d_in[10];
    const float* W2    = (const float*)d_in[11];
    const float* as2   = (const float*)d_in[12];
    const float* ad2   = (const float*)d_in[13];
    const float* b2    = (const float*)d_in[14];
    const float* Wo1   = (const float*)d_in[15];
    const float* bo1   = (const float*)d_in[16];
    const float* Wo2   = (const float*)d_in[17];
    const float* bo2   = (const float*)d_in[18];
    const int* eidx    = (const int*)d_in[19];

    const int N = in_sizes[0] / 128;
    const int E = in_sizes[19] / 2;
    const int* esrc = eidx;
    const int* edst = eidx + E;
    const int gmB  = (N + 127) / 128;
    const int Mpad = gmB * 128;
    const int nb   = (N + 255) / 256;

    char* w = (char*)d_ws;
    auto alloc = [&](size_t bytes) {
        char* p = w;
        w += (bytes + 255) & ~(size_t)255;
        return (void*)p;
    };
    _Float16* hOut = (_Float16*)alloc((size_t)Mpad * 256 * 2);
    _Float16* PHh  = (_Float16*)alloc((size_t)Mpad * 256 * 2);
    _Float16* PHl  = (_Float16*)alloc((size_t)Mpad * 256 * 2);
    float* aS      = (float*)alloc((size_t)N * 4 * 4);
    float* aD      = (float*)alloc((size_t)N * 4 * 4);
    int*   row_ptr = (int*)alloc((size_t)(N + 1) * 4);
    int*   cursor  = (int*)alloc((size_t)N * 4);
    int*   cnt     = (int*)alloc((size_t)N * 4);
    int*   bsum    = (int*)alloc((size_t)nb * 4);
    int*   csr     = (int*)alloc((size_t)(E + N) * 4);
    _Float16* WeH  = (_Float16*)alloc(128 * 64 * 2);
    _Float16* WeL  = (_Float16*)alloc(128 * 64 * 2);
    _Float16* W0H  = (_Float16*)alloc(64 * 256 * 2);
    _Float16* W0L  = (_Float16*)alloc(64 * 256 * 2);
    _Float16* W1H  = (_Float16*)alloc(256 * 256 * 2);
    _Float16* W1L  = (_Float16*)alloc(256 * 256 * 2);
    _Float16* W2H  = (_Float16*)alloc(256 * 64 * 2);
    _Float16* W2L  = (_Float16*)alloc(256 * 64 * 2);

    // CSR build (multi-block scan)
    hipMemsetAsync(cnt, 0, (size_t)N * 4, stream);
    hist_kernel<<<(E + 255) / 256, 256, 0, stream>>>(edst, E, cnt);
    blocksum_kernel<<<nb, 256, 0, stream>>>(cnt, N, bsum);
    scanbsum_kernel<<<1, 256, 0, stream>>>(bsum, nb, row_ptr + N);
    rowptr_kernel<<<nb, 256, 0, stream>>>(cnt, bsum, N, row_ptr, cursor);
    scatter_kernel<<<(E + N + 255) / 256, 256, 0, stream>>>(esrc, edst, E, N, cursor, csr);

    // weight planes (fused single launch)
    prep_weights_all<<<dim3(256, 4), 256, 0, stream>>>(W_emb, W0, W1, W2,
                                                       WeH, WeL, W0H, W0L, W1H, W1L, W2H, W2L);

    int gn4 = (N + 3) / 4;

    // embedding
    gemm_emb_kernel<<<dim3(gmB, 1), 256, 0, stream>>>(x, WeH, WeL, b_emb, PHh, PHl, Mpad, N);

    // GAT layer 0
    gemm_gat0_kernel<<<dim3(gmB, 2), 256, 0, stream>>>(PHh, PHl, W0H, W0L, as0, ad0, hOut, aS, aD, Mpad, N);
    aggregate4_kernel<0><<<gn4, 256, 0, stream>>>(hOut, aS, aD, row_ptr, csr, b0, PHh, PHl, N, Mpad);

    // GAT layer 1
    gemm_gat1_kernel<<<dim3(gmB, 2), 256, 0, stream>>>(PHh, PHl, W1H, W1L, as1, ad1, hOut, aS, aD, Mpad, N, 256);
    aggregate4_kernel<1><<<gn4, 256, 0, stream>>>(hOut, aS, aD, row_ptr, csr, b1, PHh, PHl, N, Mpad);

    // GAT layer 2 + fused head MLP
    gemm_l2_kernel<<<dim3(gmB, 1), 256, 0, stream>>>(PHh, PHl, W2H, W2L, as2, ad2, hOut, aS, aD, Mpad, N, 256);
    agg1_mlp_kernel<<<gn4, 256, 0, stream>>>(hOut, aS, aD, row_ptr, csr, b2,
                                             Wo1, bo1, Wo2, bo2, (float*)d_out, N);
}